// Round 5
// baseline (302.857 us; speedup 1.0000x reference)
//
#include <hip/hip_runtime.h>
#include <hip/hip_bf16.h>

// Problem constants
#define B_   256
#define L_   64
#define DT_  768
#define DH_  128
#define AL_  48
#define DTE_ 64
#define H_   8
#define NL_  3
#define DFF_ 512

typedef __attribute__((ext_vector_type(4))) float f32x4;
typedef __attribute__((ext_vector_type(4))) unsigned int u32x4;
typedef __attribute__((ext_vector_type(2))) unsigned int u32x2;
typedef __attribute__((ext_vector_type(8))) short short8;

__device__ inline unsigned short f2bf(float f) {
    union { float f; unsigned u; } v; v.f = f;
    unsigned r = (v.u + 0x7FFFu + ((v.u >> 16) & 1u)) >> 16;
    return (unsigned short)r;
}
__device__ inline unsigned f2bf2(float a, float b) {
    return (unsigned)f2bf(a) | ((unsigned)f2bf(b) << 16);
}
__device__ inline float bf2f(unsigned short u) {
    union { unsigned u; float f; } v; v.u = ((unsigned)u) << 16; return v.f;
}
// 8 consecutive fp32 (16B-aligned) -> short8 bf16
__device__ inline short8 cvt8(const float* p) {
    f32x4 a = *(const f32x4*)p;
    f32x4 b = *(const f32x4*)(p + 4);
    union { short8 s; unsigned u[4]; } r;
    r.u[0] = f2bf2(a[0], a[1]);
    r.u[1] = f2bf2(a[2], a[3]);
    r.u[2] = f2bf2(b[0], b[1]);
    r.u[3] = f2bf2(b[2], b[3]);
    return r.s;
}
__device__ inline short8 ldg8(const unsigned short* p) {
    union { short8 s; u32x4 v; } r;
    r.v = *(const u32x4*)p;
    return r.s;
}

// ================= Weight prep: fp32 [K][N] -> bf16 Wt [N][K] =================
struct TEnt { const float* src; int dstOff; int K; int N; int tile0; };
struct TTab { TEnt e[19]; };

__global__ __launch_bounds__(256) void prep_weights_kernel(TTab tab, unsigned short* __restrict__ wt)
{
    __shared__ unsigned short lds[64][72];
    int ei = 0;
    #pragma unroll
    for (int j = 1; j < 19; ++j) if ((int)blockIdx.x >= tab.e[j].tile0) ei = j;
    TEnt e = tab.e[ei];
    int t = blockIdx.x - e.tile0;
    int tilesK = e.K >> 6;
    int tk = t % tilesK, tn = t / tilesK;
    int tid = threadIdx.x;
    #pragma unroll
    for (int p = 0; p < 16; ++p) {
        int kk = p * 4 + (tid >> 6);
        int n = tid & 63;
        float v = e.src[(size_t)(tk * 64 + kk) * e.N + tn * 64 + n];
        lds[n][kk] = f2bf(v);
    }
    __syncthreads();
    #pragma unroll
    for (int p = 0; p < 2; ++p) {
        int c = p * 256 + tid;
        int n = c >> 3, q = c & 7;
        u32x4 v = *(const u32x4*)(&lds[n][q * 8]);
        *(u32x4*)(&wt[(size_t)e.dstOff + (size_t)(tn * 64 + n) * e.K + tk * 64 + q * 8]) = v;
    }
}

// ================= bf16 MFMA GEMM (proj): C = A(fp32 MxK) @ Wt^T -> bf16 ======
__global__ __launch_bounds__(256) void gemm_proj_kernel(
    const float* __restrict__ A, const unsigned short* __restrict__ Wt,
    const float* __restrict__ bias, unsigned short* __restrict__ C,
    int M, int N, int K)
{
    __shared__ unsigned short As[32 * 64];
    __shared__ unsigned short Bs[128 * 64];
    int tid = threadIdx.x;
    int bm = blockIdx.x * 32;
    int wave = tid >> 6, lane = tid & 63;
    int wm = wave >> 1, wn = wave & 1;
    int g = lane >> 4, r16 = lane & 15;

    f32x4 acc[4] = {};

    for (int k0 = 0; k0 < K; k0 += 64) {
        #pragma unroll
        for (int p = 0; p < 2; ++p) {
            int row = p * 16 + (tid >> 4);
            int c4 = tid & 15;
            f32x4 v = *(const f32x4*)(&A[(size_t)(bm + row) * K + k0 + c4 * 4]);
            u32x2 w;
            w[0] = f2bf2(v[0], v[1]);
            w[1] = f2bf2(v[2], v[3]);
            *(u32x2*)(&As[row * 64 + ((c4 * 4) ^ ((row & 7) << 3))]) = w;
        }
        #pragma unroll
        for (int p = 0; p < 4; ++p) {
            int c = p * 256 + tid;
            int n = c >> 3, q = c & 7;
            u32x4 v = *(const u32x4*)(&Wt[(size_t)n * K + k0 + q * 8]);
            *(u32x4*)(&Bs[n * 64 + ((q * 8) ^ ((n & 7) << 3))]) = v;
        }
        __syncthreads();
        #pragma unroll
        for (int kk = 0; kk < 2; ++kk) {
            short8 af, bf[4];
            int co = kk * 32 + g * 8;
            {
                int row = wm * 16 + r16;
                af = *(const short8*)(&As[row * 64 + (co ^ ((row & 7) << 3))]);
            }
            #pragma unroll
            for (int ni = 0; ni < 4; ++ni) {
                int row = wn * 64 + ni * 16 + r16;
                bf[ni] = *(const short8*)(&Bs[row * 64 + (co ^ ((row & 7) << 3))]);
            }
            #pragma unroll
            for (int ni = 0; ni < 4; ++ni)
                acc[ni] = __builtin_amdgcn_mfma_f32_16x16x32_bf16(af, bf[ni], acc[ni], 0, 0, 0);
        }
        __syncthreads();
    }
    #pragma unroll
    for (int ni = 0; ni < 4; ++ni) {
        int col = wn * 64 + ni * 16 + r16;
        float bv = bias[col];
        #pragma unroll
        for (int r = 0; r < 4; ++r) {
            int row = bm + wm * 16 + g * 4 + r;
            C[(size_t)row * N + col] = f2bf(acc[ni][r] + bv);
        }
    }
}

// ================= MEGA: first-attn + 3 transformer layers + head =============
// One block per batch element, 1024 threads (16 waves). x lives in LDS.
__global__ __launch_bounds__(1024) void mega_kernel(
    const float* __restrict__ note_times, const int* __restrict__ note_counts,
    const float* __restrict__ te_w, const float* __restrict__ te_b,
    const float* __restrict__ wq, const float* __restrict__ wk,
    const unsigned short* __restrict__ note_emb, const unsigned short* __restrict__ wtL,
    const float* __restrict__ tf_b1, const float* __restrict__ tf_b2,
    const float* __restrict__ ln1_g, const float* __restrict__ ln1_b,
    const float* __restrict__ ln2_g, const float* __restrict__ ln2_b,
    const float* __restrict__ cls_w1, const float* __restrict__ cls_b1,
    const float* __restrict__ cls_w2, const float* __restrict__ cls_b2,
    float* __restrict__ out)
{
    __shared__ union R1U {
        float wqk[64 * 64];                                              // 16,384 B
        struct { unsigned short As[64 * 64]; unsigned short Bs[128 * 64]; } fa; // 24,576 B
        float x[48 * 132];                                               // 25,344 B
    } r1;
    __shared__ union R2U {
        struct { unsigned short qs[48 * 64]; float kkR[64 * 65]; } fa;   // 22,784 B
        struct { unsigned short qkv[3][48 * 38]; float sbuf[16][96];
                 unsigned short obf[48 * 128]; } at;                     // 29,376 B
        struct { unsigned short hidden[48 * 256]; } ff;                  // 24,576 B
        struct { float Cs[48 * 132]; } ep;                               // 25,344 B
    } r2;

    const int b = blockIdx.x;
    const int tid = threadIdx.x, wave = tid >> 6, lane = tid & 63;
    const int g = lane >> 4, r16 = lane & 15;
    const int nc = note_counts[b];

    // ---------- FA-0: stage wq; q_all -> qs (bf16) ----------
    for (int i = tid; i < 4096; i += 1024) r1.wqk[i] = wq[i];
    __syncthreads();
    #pragma unroll
    for (int ai = 0; ai < 3; ++ai) {
        int a = wave * 3 + ai;
        float lin = fmaf((float)a, te_w[lane], te_b[lane]);
        float te = (lane == 0) ? lin : __sinf(lin);
        float s0 = 0.f, s1 = 0.f, s2 = 0.f, s3 = 0.f;
        #pragma unroll
        for (int j = 0; j < 64; j += 4) {
            s0 = fmaf(__shfl(te, j + 0), r1.wqk[(j + 0) * 64 + lane], s0);
            s1 = fmaf(__shfl(te, j + 1), r1.wqk[(j + 1) * 64 + lane], s1);
            s2 = fmaf(__shfl(te, j + 2), r1.wqk[(j + 2) * 64 + lane], s2);
            s3 = fmaf(__shfl(te, j + 3), r1.wqk[(j + 3) * 64 + lane], s3);
        }
        r2.fa.qs[a * 64 + lane] = f2bf((s0 + s1) + (s2 + s3));
    }
    __syncthreads();
    // ---------- FA-1: stage wk; kk -> kkR (fp32, stride 65) ----------
    for (int i = tid; i < 4096; i += 1024) r1.wqk[i] = wk[i];
    __syncthreads();
    #pragma unroll
    for (int li = 0; li < 4; ++li) {
        int l = wave * 4 + li;
        float t = note_times[b * 64 + l];
        float lin = fmaf(t, te_w[lane], te_b[lane]);
        float te = (lane == 0) ? lin : __sinf(lin);
        float s0 = 0.f, s1 = 0.f, s2 = 0.f, s3 = 0.f;
        #pragma unroll
        for (int j = 0; j < 64; j += 4) {
            s0 = fmaf(__shfl(te, j + 0), r1.wqk[(j + 0) * 64 + lane], s0);
            s1 = fmaf(__shfl(te, j + 1), r1.wqk[(j + 1) * 64 + lane], s1);
            s2 = fmaf(__shfl(te, j + 2), r1.wqk[(j + 2) * 64 + lane], s2);
            s3 = fmaf(__shfl(te, j + 3), r1.wqk[(j + 3) * 64 + lane], s3);
        }
        r2.fa.kkR[l * 65 + lane] = (s0 + s1) + (s2 + s3);
    }
    __syncthreads();   // qs + kkR ready; r1 becomes As/Bs

    // ---------- FA-2: stage Bs = note_emb^T; scores -> abar -> As ----------
    {
        int l = tid & 63, c = tid >> 6;   // c 0..15
        u32x4 v = *(const u32x4*)(&note_emb[((size_t)b * 64 + l) * 128 + c * 8]);
        #pragma unroll
        for (int j = 0; j < 8; ++j) {
            unsigned short h16 = (unsigned short)((j & 1) ? (v[j >> 1] >> 16) : (v[j >> 1] & 0xffff));
            int f = c * 8 + j;
            r1.fa.Bs[f * 64 + (l ^ ((f & 7) << 3))] = h16;
        }
    }
    {
        const float scale = 0.35355339059327373f; // 1/sqrt(8)
        #pragma unroll
        for (int ai = 0; ai < 3; ++ai) {
            int a = wave * 3 + ai;
            float s[8], m[8], e[8], sm[8];
            #pragma unroll
            for (int h = 0; h < 8; ++h) {
                union { u32x4 v; unsigned short q[8]; } qv;
                qv.v = *(const u32x4*)(&r2.fa.qs[a * 64 + h * 8]);
                float t0 = 0.f;
                #pragma unroll
                for (int e2 = 0; e2 < 8; ++e2)
                    t0 = fmaf(bf2f(qv.q[e2]), r2.fa.kkR[lane * 65 + h * 8 + e2], t0);
                s[h] = (lane < nc) ? t0 * scale : -1e9f;
            }
            #pragma unroll
            for (int h = 0; h < 8; ++h) m[h] = s[h];
            #pragma unroll
            for (int o2 = 32; o2 >= 1; o2 >>= 1) {
                #pragma unroll
                for (int h = 0; h < 8; ++h) m[h] = fmaxf(m[h], __shfl_xor(m[h], o2));
            }
            #pragma unroll
            for (int h = 0; h < 8; ++h) { e[h] = __expf(s[h] - m[h]); sm[h] = e[h]; }
            #pragma unroll
            for (int o2 = 32; o2 >= 1; o2 >>= 1) {
                #pragma unroll
                for (int h = 0; h < 8; ++h) sm[h] += __shfl_xor(sm[h], o2);
            }
            float acc = 0.f;
            #pragma unroll
            for (int h = 0; h < 8; ++h) acc = fmaf(e[h], __fdividef(0.125f, sm[h]), acc);
            r1.fa.As[a * 64 + (lane ^ ((a & 7) << 3))] = f2bf(acc);
        }
    }
    __syncthreads();

    // ---------- FA-3: PV via MFMA -> x (fp32 LDS, stride 132) ----------
    {
        f32x4 accA = {0.f, 0.f, 0.f, 0.f}, accB = {0.f, 0.f, 0.f, 0.f};
        const bool hasB = (wave < 8);
        {
            int f = wave, mi = f >> 3, ni = f & 7;
            #pragma unroll
            for (int kk = 0; kk < 2; ++kk) {
                int co = kk * 32 + g * 8;
                int ra = mi * 16 + r16, rb = ni * 16 + r16;
                short8 af = *(const short8*)(&r1.fa.As[ra * 64 + (co ^ ((ra & 7) << 3))]);
                short8 bf = *(const short8*)(&r1.fa.Bs[rb * 64 + (co ^ ((rb & 7) << 3))]);
                accA = __builtin_amdgcn_mfma_f32_16x16x32_bf16(af, bf, accA, 0, 0, 0);
            }
        }
        if (hasB) {
            int f = wave + 16, mi = f >> 3, ni = f & 7;
            #pragma unroll
            for (int kk = 0; kk < 2; ++kk) {
                int co = kk * 32 + g * 8;
                int ra = mi * 16 + r16, rb = ni * 16 + r16;
                short8 af = *(const short8*)(&r1.fa.As[ra * 64 + (co ^ ((ra & 7) << 3))]);
                short8 bf = *(const short8*)(&r1.fa.Bs[rb * 64 + (co ^ ((rb & 7) << 3))]);
                accB = __builtin_amdgcn_mfma_f32_16x16x32_bf16(af, bf, accB, 0, 0, 0);
            }
        }
        __syncthreads();   // As/Bs reads done -> x may overwrite
        {
            int f = wave, mi = f >> 3, ni = f & 7;
            #pragma unroll
            for (int r = 0; r < 4; ++r)
                r1.x[(mi * 16 + g * 4 + r) * 132 + ni * 16 + r16] = (nc > 0) ? accA[r] : 0.f;
        }
        if (hasB) {
            int f = wave + 16, mi = f >> 3, ni = f & 7;
            #pragma unroll
            for (int r = 0; r < 4; ++r)
                r1.x[(mi * 16 + g * 4 + r) * 132 + ni * 16 + r16] = (nc > 0) ? accB[r] : 0.f;
        }
    }
    __syncthreads();

    // ================= 3 transformer layers =================
    for (int il = 0; il < NL_; ++il) {
        const unsigned short* Wl = wtL + (size_t)il * 196608;

        // ---- attention: 4 passes of 2 heads
        for (int hp = 0; hp < 4; ++hp) {
            // qkv mini-GEMM: 18 frags (mat 0..2 x nt 0..1 x mi 0..2)
            auto qkvfrag = [&](int f) -> f32x4 {
                int mi = f % 3, c2 = f / 3;
                int mat = c2 >> 1, nt = c2 & 1;
                f32x4 acc = {0.f, 0.f, 0.f, 0.f};
                const unsigned short* Wm = Wl + mat * 16384 + (size_t)(hp * 32 + nt * 16 + r16) * 128;
                #pragma unroll
                for (int kq = 0; kq < 4; ++kq) {
                    int co = kq * 32 + g * 8;
                    short8 af = cvt8(&r1.x[(mi * 16 + r16) * 132 + co]);
                    short8 bf = ldg8(Wm + co);
                    acc = __builtin_amdgcn_mfma_f32_16x16x32_bf16(af, bf, acc, 0, 0, 0);
                }
                return acc;
            };
            f32x4 qa = qkvfrag(wave);
            f32x4 qb = {0.f, 0.f, 0.f, 0.f};
            if (wave < 2) qb = qkvfrag(wave + 16);
            auto qkvwrite = [&](int f, f32x4 acc) {
                int mi = f % 3, c2 = f / 3;
                int mat = c2 >> 1, nt = c2 & 1;
                #pragma unroll
                for (int r = 0; r < 4; ++r)
                    r2.at.qkv[mat][(mi * 16 + g * 4 + r) * 38 + nt * 16 + r16] = f2bf(acc[r]);
            };
            qkvwrite(wave, qa);
            if (wave < 2) qkvwrite(wave + 16, qb);
            __syncthreads();

            // scores + softmax + PV (wave -> head hl = wave&1, a-range 6)
            int hl = wave & 1, aw = wave >> 1;
            int h = hp * 2 + hl;
            // preload this head's k row for this lane (lane = kx)
            float kreg[16];
            #pragma unroll
            for (int d = 0; d < 16; ++d)
                kreg[d] = bf2f(r2.at.qkv[1][lane * 38 + hl * 16 + d]);
            #pragma unroll
            for (int batch = 0; batch < 3; ++batch) {
                int a0 = aw * 6 + batch * 2, a1 = a0 + 1;
                float sA = 0.f, sB = 0.f;
                #pragma unroll
                for (int d = 0; d < 16; ++d) {
                    sA = fmaf(bf2f(r2.at.qkv[0][a0 * 38 + hl * 16 + d]), kreg[d], sA);
                    sB = fmaf(bf2f(r2.at.qkv[0][a1 * 38 + hl * 16 + d]), kreg[d], sB);
                }
                sA = (lane < 48) ? sA * 0.25f : -3.0e38f;
                sB = (lane < 48) ? sB * 0.25f : -3.0e38f;
                float mA = sA, mB = sB;
                #pragma unroll
                for (int o2 = 32; o2 >= 1; o2 >>= 1) {
                    mA = fmaxf(mA, __shfl_xor(mA, o2));
                    mB = fmaxf(mB, __shfl_xor(mB, o2));
                }
                float eA = __expf(sA - mA), eB = __expf(sB - mB);
                float uA = eA, uB = eB;
                #pragma unroll
                for (int o2 = 32; o2 >= 1; o2 >>= 1) {
                    uA += __shfl_xor(uA, o2);
                    uB += __shfl_xor(uB, o2);
                }
                if (lane < 48) {
                    r2.at.sbuf[wave][lane]      = eA * __fdividef(1.f, uA);
                    r2.at.sbuf[wave][48 + lane] = eB * __fdividef(1.f, uB);
                }
                // PV: lanes with g<2: a = a0+g, output col d = r16
                if (g < 2) {
                    int a = a0 + g;
                    float o = 0.f;
                    #pragma unroll 4
                    for (int j = 0; j < 48; ++j)
                        o = fmaf(r2.at.sbuf[wave][g * 48 + j],
                                 bf2f(r2.at.qkv[2][j * 38 + hl * 16 + r16]), o);
                    int c = h * 16 + r16;
                    r2.at.obf[a * 128 + (c & 64) + ((c & 63) ^ ((a & 7) << 3))] = f2bf(o);
                }
            }
            __syncthreads();
        }

        // ---- wo GEMM (M=48, N=128, K=128), A from obf
        f32x4 woA = {0.f, 0.f, 0.f, 0.f}, woB = {0.f, 0.f, 0.f, 0.f};
        auto wofrag = [&](int f) -> f32x4 {
            int mi = f >> 3, ni = f & 7;
            f32x4 acc = {0.f, 0.f, 0.f, 0.f};
            const unsigned short* Wm = Wl + 3 * 16384 + (size_t)(ni * 16 + r16) * 128;
            #pragma unroll
            for (int kq = 0; kq < 4; ++kq) {
                int co = kq * 32 + g * 8;
                int ra = mi * 16 + r16;
                short8 af = *(const short8*)(&r2.at.obf[ra * 128 + (co & 64) + ((co & 63) ^ ((ra & 7) << 3))]);
                short8 bf = ldg8(Wm + co);
                acc = __builtin_amdgcn_mfma_f32_16x16x32_bf16(af, bf, acc, 0, 0, 0);
            }
            return acc;
        };
        woA = wofrag(wave);
        if (wave < 8) woB = wofrag(wave + 16);
        __syncthreads();   // obf reads done -> Cs overlay
        {
            int mi = wave >> 3, ni = wave & 7;
            #pragma unroll
            for (int r = 0; r < 4; ++r)
                r2.ep.Cs[(mi * 16 + g * 4 + r) * 132 + ni * 16 + r16] = woA[r];
            if (wave < 8) {
                int f = wave + 16; mi = f >> 3; ni = f & 7;
                #pragma unroll
                for (int r = 0; r < 4; ++r)
                    r2.ep.Cs[(mi * 16 + g * 4 + r) * 132 + ni * 16 + r16] = woB[r];
            }
        }
        __syncthreads();
        // ---- LN1 (+residual): 3 rows per wave
        #pragma unroll
        for (int rr = 0; rr < 3; ++rr) {
            int row = wave * 3 + rr;
            float v0 = r2.ep.Cs[row * 132 + lane] + r1.x[row * 132 + lane];
            float v1 = r2.ep.Cs[row * 132 + 64 + lane] + r1.x[row * 132 + 64 + lane];
            float sum = v0 + v1, sq = v0 * v0 + v1 * v1;
            #pragma unroll
            for (int o2 = 32; o2 >= 1; o2 >>= 1) {
                sum += __shfl_xor(sum, o2);
                sq  += __shfl_xor(sq, o2);
            }
            float mu = sum * (1.f / 128.f);
            float var = sq * (1.f / 128.f) - mu * mu;
            float rs = rsqrtf(var + 1e-5f);
            r1.x[row * 132 + lane]      = (v0 - mu) * rs * ln1_g[il * 128 + lane] + ln1_b[il * 128 + lane];
            r1.x[row * 132 + 64 + lane] = (v1 - mu) * rs * ln1_g[il * 128 + 64 + lane] + ln1_b[il * 128 + 64 + lane];
        }
        __syncthreads();

        // ---- FFN: hidden in 2 passes of 256 cols; y accumulates across passes
        f32x4 y0 = {0.f, 0.f, 0.f, 0.f}, y1 = {0.f, 0.f, 0.f, 0.f};
        for (int pass = 0; pass < 2; ++pass) {
            // hidden = relu(x @ w1_pass + b1): 48 frags = (mi=t 0..2, nt=wave)
            auto h1frag = [&](int mi) -> f32x4 {
                f32x4 acc = {0.f, 0.f, 0.f, 0.f};
                const unsigned short* Wm = Wl + 65536 + (size_t)(pass * 256 + wave * 16 + r16) * 128;
                #pragma unroll
                for (int kq = 0; kq < 4; ++kq) {
                    int co = kq * 32 + g * 8;
                    short8 af = cvt8(&r1.x[(mi * 16 + r16) * 132 + co]);
                    short8 bf = ldg8(Wm + co);
                    acc = __builtin_amdgcn_mfma_f32_16x16x32_bf16(af, bf, acc, 0, 0, 0);
                }
                return acc;
            };
            f32x4 hA = h1frag(0), hB = h1frag(1), hC = h1frag(2);
            __syncthreads();   // prior-pass hidden reads (or Cs/LN1) complete
            {
                float b1v = tf_b1[il * 512 + pass * 256 + wave * 16 + r16];
                int col = wave * 16 + r16;
                #pragma unroll
                for (int r = 0; r < 4; ++r) {
                    int a0r = 0 * 16 + g * 4 + r;
                    r2.ff.hidden[a0r * 256 + (col & 192) + ((col & 63) ^ ((a0r & 7) << 3))] = f2bf(fmaxf(hA[r] + b1v, 0.f));
                    int a1r = 1 * 16 + g * 4 + r;
                    r2.ff.hidden[a1r * 256 + (col & 192) + ((col & 63) ^ ((a1r & 7) << 3))] = f2bf(fmaxf(hB[r] + b1v, 0.f));
                    int a2r = 2 * 16 + g * 4 + r;
                    r2.ff.hidden[a2r * 256 + (col & 192) + ((col & 63) ^ ((a2r & 7) << 3))] = f2bf(fmaxf(hC[r] + b1v, 0.f));
                }
            }
            __syncthreads();
            // y += hidden @ w2_pass : 24 frags
            auto y2frag = [&](int f, f32x4 acc) -> f32x4 {
                int mi = f >> 3, ni = f & 7;
                const unsigned short* Wm = Wl + 131072 + (size_t)(ni * 16 + r16) * 512 + pass * 256;
                #pragma unroll
                for (int kq = 0; kq < 8; ++kq) {
                    int co = kq * 32 + g * 8;
                    int ra = mi * 16 + r16;
                    short8 af = *(const short8*)(&r2.ff.hidden[ra * 256 + (co & 192) + ((co & 63) ^ ((ra & 7) << 3))]);
                    short8 bf = ldg8(Wm + co);
                    acc = __builtin_amdgcn_mfma_f32_16x16x32_bf16(af, bf, acc, 0, 0, 0);
                }
                return acc;
            };
            y0 = y2frag(wave, y0);
            if (wave < 8) y1 = y2frag(wave + 16, y1);
        }
        __syncthreads();   // hidden reads done -> Cs overlay
        {
            int mi = wave >> 3, ni = wave & 7;
            float b2v = tf_b2[il * 128 + ni * 16 + r16];
            #pragma unroll
            for (int r = 0; r < 4; ++r)
                r2.ep.Cs[(mi * 16 + g * 4 + r) * 132 + ni * 16 + r16] = y0[r] + b2v;
            if (wave < 8) {
                int f = wave + 16; mi = f >> 3; ni = f & 7;
                b2v = tf_b2[il * 128 + ni * 16 + r16];
                #pragma unroll
                for (int r = 0; r < 4; ++r)
                    r2.ep.Cs[(mi * 16 + g * 4 + r) * 132 + ni * 16 + r16] = y1[r] + b2v;
            }
        }
        __syncthreads();
        // ---- LN2 (+residual)
        #pragma unroll
        for (int rr = 0; rr < 3; ++rr) {
            int row = wave * 3 + rr;
            float v0 = r2.ep.Cs[row * 132 + lane] + r1.x[row * 132 + lane];
            float v1 = r2.ep.Cs[row * 132 + 64 + lane] + r1.x[row * 132 + 64 + lane];
            float sum = v0 + v1, sq = v0 * v0 + v1 * v1;
            #pragma unroll
            for (int o2 = 32; o2 >= 1; o2 >>= 1) {
                sum += __shfl_xor(sum, o2);
                sq  += __shfl_xor(sq, o2);
            }
            float mu = sum * (1.f / 128.f);
            float var = sq * (1.f / 128.f) - mu * mu;
            float rs = rsqrtf(var + 1e-5f);
            r1.x[row * 132 + lane]      = (v0 - mu) * rs * ln2_g[il * 128 + lane] + ln2_b[il * 128 + lane];
            r1.x[row * 132 + 64 + lane] = (v1 - mu) * rs * ln2_g[il * 128 + 64 + lane] + ln2_b[il * 128 + 64 + lane];
        }
        __syncthreads();
    }

    // ---------- classifier head (wave 0) ----------
    if (wave == 0) {
        float hj = cls_b1[lane];
        #pragma unroll 8
        for (int d = 0; d < 128; ++d)
            hj = fmaf(r1.x[47 * 132 + d], cls_w1[d * 64 + lane], hj);
        hj = fmaxf(hj, 0.f);
        float acc = hj * cls_w2[lane];
        #pragma unroll
        for (int o2 = 32; o2 >= 1; o2 >>= 1) acc += __shfl_xor(acc, o2);
        if (lane == 0) out[b] = acc + cls_b2[0];
    }
}

// ================= Launch =====================================================
extern "C" void kernel_launch(void* const* d_in, const int* in_sizes, int n_in,
                              void* d_out, int out_size, void* d_ws, size_t ws_size,
                              hipStream_t stream) {
    (void)in_sizes; (void)n_in; (void)out_size; (void)ws_size;
    const float* cls_emb    = (const float*)d_in[0];
    const float* note_times = (const float*)d_in[1];
    const int*   note_counts= (const int*)d_in[2];
    const float* proj_w     = (const float*)d_in[3];
    const float* proj_b     = (const float*)d_in[4];
    const float* te_w       = (const float*)d_in[5];
    const float* te_b       = (const float*)d_in[6];
    const float* wq         = (const float*)d_in[7];
    const float* wk         = (const float*)d_in[8];
    const float* tf_wq      = (const float*)d_in[9];
    const float* tf_wk      = (const float*)d_in[10];
    const float* tf_wv      = (const float*)d_in[11];
    const float* tf_wo      = (const float*)d_in[12];
    const float* tf_ln1_g   = (const float*)d_in[13];
    const float* tf_ln1_b   = (const float*)d_in[14];
    const float* tf_w1      = (const float*)d_in[15];
    const float* tf_b1      = (const float*)d_in[16];
    const float* tf_w2      = (const float*)d_in[17];
    const float* tf_b2      = (const float*)d_in[18];
    const float* tf_ln2_g   = (const float*)d_in[19];
    const float* tf_ln2_b   = (const float*)d_in[20];
    const float* cls_w1     = (const float*)d_in[21];
    const float* cls_b1     = (const float*)d_in[22];
    const float* cls_w2     = (const float*)d_in[23];
    const float* cls_b2     = (const float*)d_in[24];
    float* out = (float*)d_out;
    float* ws = (float*)d_ws;

    // workspace layout (float units)
    unsigned short* note_emb16 = (unsigned short*)(ws + 0);       // 2,097,152 u16
    unsigned short* wt         = (unsigned short*)(ws + 1048576); // 688,128 u16

    // ---- weight prep table
    TTab tab;
    int tile = 0, idx = 0;
    auto add = [&](const float* src, int dstOff, int K, int N) {
        tab.e[idx].src = src; tab.e[idx].dstOff = dstOff;
        tab.e[idx].K = K; tab.e[idx].N = N; tab.e[idx].tile0 = tile;
        tile += (K / 64) * (N / 64); ++idx;
    };
    add(proj_w, 0, DT_, DH_);
    for (int i = 0; i < NL_; ++i) {
        int base = 98304 + i * 196608;
        add(tf_wq + (size_t)i * DH_ * DH_, base,           DH_, DH_);
        add(tf_wk + (size_t)i * DH_ * DH_, base + 16384,   DH_, DH_);
        add(tf_wv + (size_t)i * DH_ * DH_, base + 32768,   DH_, DH_);
        add(tf_wo + (size_t)i * DH_ * DH_, base + 49152,   DH_, DH_);
        add(tf_w1 + (size_t)i * DH_ * DFF_, base + 65536,  DH_, DFF_);
        add(tf_w2 + (size_t)i * DFF_ * DH_, base + 131072, DFF_, DH_);
    }
    prep_weights_kernel<<<tile, 256, 0, stream>>>(tab, wt);

    // note_emb = bf16(cls_emb @ proj_w + proj_b)
    gemm_proj_kernel<<<(B_ * L_) / 32, 256, 0, stream>>>(
        cls_emb, wt, proj_b, note_emb16, B_ * L_, DH_, DT_);

    // mega: first attention + 3 layers + head
    mega_kernel<<<B_, 1024, 0, stream>>>(
        note_times, note_counts, te_w, te_b, wq, wk,
        note_emb16, wt + 98304,
        tf_b1, tf_b2, tf_ln1_g, tf_ln1_b, tf_ln2_g, tf_ln2_b,
        cls_w1, cls_b1, cls_w2, cls_b2, out);
}

// Round 6
// 261.843 us; speedup vs baseline: 1.1566x; 1.1566x over previous
//
#include <hip/hip_runtime.h>
#include <hip/hip_bf16.h>

// Problem constants
#define B_   256
#define L_   64
#define DT_  768
#define DH_  128
#define AL_  48
#define DTE_ 64
#define H_   8
#define NL_  3
#define DFF_ 512

typedef __attribute__((ext_vector_type(4))) float f32x4;
typedef __attribute__((ext_vector_type(4))) unsigned int u32x4;
typedef __attribute__((ext_vector_type(2))) unsigned int u32x2;
typedef __attribute__((ext_vector_type(8))) short short8;

__device__ inline unsigned short f2bf(float f) {
    union { float f; unsigned u; } v; v.f = f;
    unsigned r = (v.u + 0x7FFFu + ((v.u >> 16) & 1u)) >> 16;
    return (unsigned short)r;
}
__device__ inline unsigned f2bf2(float a, float b) {
    return (unsigned)f2bf(a) | ((unsigned)f2bf(b) << 16);
}
__device__ inline float bf2f(unsigned short u) {
    union { unsigned u; float f; } v; v.u = ((unsigned)u) << 16; return v.f;
}
__device__ inline short8 ldg8(const unsigned short* p) {
    union { short8 s; u32x4 v; } r;
    r.v = *(const u32x4*)p;
    return r.s;
}

// ================= Weight prep: fp32 [K][N] -> bf16 Wt [N][K] =================
struct TEnt { const float* src; int dstOff; int K; int N; int tile0; };
struct TTab { TEnt e[19]; };

__global__ __launch_bounds__(256) void prep_weights_kernel(TTab tab, unsigned short* __restrict__ wt)
{
    __shared__ unsigned short lds[64][72];
    int ei = 0;
    #pragma unroll
    for (int j = 1; j < 19; ++j) if ((int)blockIdx.x >= tab.e[j].tile0) ei = j;
    TEnt e = tab.e[ei];
    int t = blockIdx.x - e.tile0;
    int tilesK = e.K >> 6;
    int tk = t % tilesK, tn = t / tilesK;
    int tid = threadIdx.x;
    #pragma unroll
    for (int p = 0; p < 16; ++p) {
        int kk = p * 4 + (tid >> 6);
        int n = tid & 63;
        float v = e.src[(size_t)(tk * 64 + kk) * e.N + tn * 64 + n];
        lds[n][kk] = f2bf(v);
    }
    __syncthreads();
    #pragma unroll
    for (int p = 0; p < 2; ++p) {
        int c = p * 256 + tid;
        int n = c >> 3, q = c & 7;
        u32x4 v = *(const u32x4*)(&lds[n][q * 8]);
        *(u32x4*)(&wt[(size_t)e.dstOff + (size_t)(tn * 64 + n) * e.K + tk * 64 + q * 8]) = v;
    }
}

// ================= bf16 MFMA GEMM (proj): C = A(fp32 MxK) @ Wt^T -> bf16 ======
__global__ __launch_bounds__(256) void gemm_proj_kernel(
    const float* __restrict__ A, const unsigned short* __restrict__ Wt,
    const float* __restrict__ bias, unsigned short* __restrict__ C,
    int M, int N, int K)
{
    __shared__ unsigned short As[32 * 64];
    __shared__ unsigned short Bs[128 * 64];
    int tid = threadIdx.x;
    int bm = blockIdx.x * 32;
    int wave = tid >> 6, lane = tid & 63;
    int wm = wave >> 1, wn = wave & 1;
    int g = lane >> 4, r16 = lane & 15;

    f32x4 acc[4] = {};

    for (int k0 = 0; k0 < K; k0 += 64) {
        #pragma unroll
        for (int p = 0; p < 2; ++p) {
            int row = p * 16 + (tid >> 4);
            int c4 = tid & 15;
            f32x4 v = *(const f32x4*)(&A[(size_t)(bm + row) * K + k0 + c4 * 4]);
            u32x2 w;
            w[0] = f2bf2(v[0], v[1]);
            w[1] = f2bf2(v[2], v[3]);
            *(u32x2*)(&As[row * 64 + ((c4 * 4) ^ ((row & 7) << 3))]) = w;
        }
        #pragma unroll
        for (int p = 0; p < 4; ++p) {
            int c = p * 256 + tid;
            int n = c >> 3, q = c & 7;
            u32x4 v = *(const u32x4*)(&Wt[(size_t)n * K + k0 + q * 8]);
            *(u32x4*)(&Bs[n * 64 + ((q * 8) ^ ((n & 7) << 3))]) = v;
        }
        __syncthreads();
        #pragma unroll
        for (int kk = 0; kk < 2; ++kk) {
            short8 af, bf[4];
            int co = kk * 32 + g * 8;
            {
                int row = wm * 16 + r16;
                af = *(const short8*)(&As[row * 64 + (co ^ ((row & 7) << 3))]);
            }
            #pragma unroll
            for (int ni = 0; ni < 4; ++ni) {
                int row = wn * 64 + ni * 16 + r16;
                bf[ni] = *(const short8*)(&Bs[row * 64 + (co ^ ((row & 7) << 3))]);
            }
            #pragma unroll
            for (int ni = 0; ni < 4; ++ni)
                acc[ni] = __builtin_amdgcn_mfma_f32_16x16x32_bf16(af, bf[ni], acc[ni], 0, 0, 0);
        }
        __syncthreads();
    }
    #pragma unroll
    for (int ni = 0; ni < 4; ++ni) {
        int col = wn * 64 + ni * 16 + r16;
        float bv = bias[col];
        #pragma unroll
        for (int r = 0; r < 4; ++r) {
            int row = bm + wm * 16 + g * 4 + r;
            C[(size_t)row * N + col] = f2bf(acc[ni][r] + bv);
        }
    }
}

// ================= First attention, split-alpha: block = (b, half of 48 rows) =
__global__ __launch_bounds__(256) void first_attn_kernel(
    const float* __restrict__ note_times, const int* __restrict__ note_counts,
    const float* __restrict__ te_w, const float* __restrict__ te_b,
    const float* __restrict__ wq, const float* __restrict__ wk,
    const unsigned short* __restrict__ note_emb,
    float* __restrict__ x_out, unsigned short* __restrict__ xbf_out)
{
    __shared__ union RA {
        float wmat[64 * 64];                                              // phase 0
        float kte[64 * 68];                                               // phase 1-2
        struct { unsigned short As[32 * 64]; unsigned short Bs[128 * 64]; } mm; // 3-4
    } ra;
    __shared__ float kkR[64 * 68];
    __shared__ float qs[24 * 64];
    const int bx = blockIdx.x;
    const int b = bx >> 1, a0 = (bx & 1) * 24;
    const int tid = threadIdx.x, wave = tid >> 6, lane = tid & 63;
    const int g = lane >> 4, r16 = lane & 15;
    const int nc = note_counts[b];

    // preload wk column into regs (lane = output dim d)
    float wkc[64];
    #pragma unroll
    for (int j = 0; j < 64; ++j) wkc[j] = wk[j * 64 + lane];

    // ---- phase 0: stage wq; compute q rows a0..a0+23 via shfl-GEMV
    for (int i = tid; i < 4096; i += 256) ra.wmat[i] = wq[i];
    __syncthreads();
    #pragma unroll
    for (int qi = 0; qi < 6; ++qi) {
        int al = wave * 6 + qi;
        float lin = fmaf((float)(a0 + al), te_w[lane], te_b[lane]);
        float te = (lane == 0) ? lin : __sinf(lin);
        float s0 = 0.f, s1 = 0.f, s2 = 0.f, s3 = 0.f;
        #pragma unroll
        for (int j = 0; j < 64; j += 4) {
            s0 = fmaf(__shfl(te, j + 0), ra.wmat[(j + 0) * 64 + lane], s0);
            s1 = fmaf(__shfl(te, j + 1), ra.wmat[(j + 1) * 64 + lane], s1);
            s2 = fmaf(__shfl(te, j + 2), ra.wmat[(j + 2) * 64 + lane], s2);
            s3 = fmaf(__shfl(te, j + 3), ra.wmat[(j + 3) * 64 + lane], s3);
        }
        qs[al * 64 + lane] = (s0 + s1) + (s2 + s3);
    }
    __syncthreads();

    // ---- phase 1: kte (padded 68) -- overwrites wq region
    for (int i = tid; i < 4096; i += 256) {
        int l = i >> 6, j = i & 63;
        float t = note_times[b * 64 + l];
        float lin = fmaf(t, te_w[j], te_b[j]);
        ra.kte[l * 68 + j] = (j == 0) ? lin : __sinf(lin);
    }
    __syncthreads();

    // ---- phase 2: kk[l][d], lane = d, 4-way partial sums
    for (int it = 0; it < 16; ++it) {
        int l = it * 4 + wave;
        float s0 = 0.f, s1 = 0.f, s2 = 0.f, s3 = 0.f;
        #pragma unroll
        for (int j4 = 0; j4 < 16; ++j4) {
            f32x4 kt = *(const f32x4*)(&ra.kte[l * 68 + j4 * 4]);
            s0 = fmaf(kt[0], wkc[j4 * 4 + 0], s0);
            s1 = fmaf(kt[1], wkc[j4 * 4 + 1], s1);
            s2 = fmaf(kt[2], wkc[j4 * 4 + 2], s2);
            s3 = fmaf(kt[3], wkc[j4 * 4 + 3], s3);
        }
        kkR[l * 68 + lane] = (s0 + s1) + (s2 + s3);
    }
    __syncthreads();   // kte dead -> As/Bs

    // ---- phase 3a: stage Bs = note_emb^T (swizzled); zero As rows 24..31
    {
        int l = tid & 63;
        #pragma unroll
        for (int p = 0; p < 4; ++p) {
            int c = p * 4 + (tid >> 6);  // 0..15
            u32x4 v = *(const u32x4*)(&note_emb[((size_t)b * 64 + l) * 128 + c * 8]);
            #pragma unroll
            for (int j = 0; j < 8; ++j) {
                unsigned short h16 = (unsigned short)((j & 1) ? (v[j >> 1] >> 16) : (v[j >> 1] & 0xffff));
                int f = c * 8 + j;
                ra.mm.Bs[f * 64 + (l ^ ((f & 7) << 3))] = h16;
            }
        }
    }
    for (int i = tid; i < 8 * 64; i += 256)
        ra.mm.As[(24 + (i >> 6)) * 64 + (i & 63)] = 0;

    // ---- phase 3b: scores + 8-head ILP softmax -> As (bf16, swizzled)
    f32x4 kv[16];
    #pragma unroll
    for (int q = 0; q < 16; ++q) kv[q] = *(const f32x4*)(&kkR[lane * 68 + q * 4]);
    const float scale = 0.35355339059327373f; // 1/sqrt(8)
    #pragma unroll
    for (int ai = 0; ai < 6; ++ai) {
        int al = wave * 6 + ai;
        float s[8], m[8], e[8], sm[8];
        #pragma unroll
        for (int h = 0; h < 8; ++h) {
            f32x4 q0 = *(const f32x4*)(&qs[al * 64 + h * 8]);
            f32x4 q1 = *(const f32x4*)(&qs[al * 64 + h * 8 + 4]);
            f32x4 k0 = kv[h * 2], k1 = kv[h * 2 + 1];
            float t0 = q0[0] * k0[0];
            t0 = fmaf(q0[1], k0[1], t0);
            t0 = fmaf(q0[2], k0[2], t0);
            t0 = fmaf(q0[3], k0[3], t0);
            float t1 = q1[0] * k1[0];
            t1 = fmaf(q1[1], k1[1], t1);
            t1 = fmaf(q1[2], k1[2], t1);
            t1 = fmaf(q1[3], k1[3], t1);
            s[h] = (lane < nc) ? (t0 + t1) * scale : -1e9f;
        }
        #pragma unroll
        for (int h = 0; h < 8; ++h) m[h] = s[h];
        #pragma unroll
        for (int o2 = 32; o2 >= 1; o2 >>= 1) {
            #pragma unroll
            for (int h = 0; h < 8; ++h) m[h] = fmaxf(m[h], __shfl_xor(m[h], o2));
        }
        #pragma unroll
        for (int h = 0; h < 8; ++h) { e[h] = __expf(s[h] - m[h]); sm[h] = e[h]; }
        #pragma unroll
        for (int o2 = 32; o2 >= 1; o2 >>= 1) {
            #pragma unroll
            for (int h = 0; h < 8; ++h) sm[h] += __shfl_xor(sm[h], o2);
        }
        float acc = 0.f;
        #pragma unroll
        for (int h = 0; h < 8; ++h) acc = fmaf(e[h], __fdividef(0.125f, sm[h]), acc);
        ra.mm.As[al * 64 + (lane ^ ((al & 7) << 3))] = f2bf(acc);
    }
    __syncthreads();

    // ---- phase 4: PV via MFMA, 16 frags over 4 waves
    f32x4 acc4[4] = {};
    #pragma unroll
    for (int q = 0; q < 4; ++q) {
        int f = wave * 4 + q, mi = f >> 3, ni = f & 7;
        #pragma unroll
        for (int kk = 0; kk < 2; ++kk) {
            int co = kk * 32 + g * 8;
            int raR = mi * 16 + r16, rb = ni * 16 + r16;
            short8 af = *(const short8*)(&ra.mm.As[raR * 64 + (co ^ ((raR & 7) << 3))]);
            short8 bf = *(const short8*)(&ra.mm.Bs[rb * 64 + (co ^ ((rb & 7) << 3))]);
            acc4[q] = __builtin_amdgcn_mfma_f32_16x16x32_bf16(af, bf, acc4[q], 0, 0, 0);
        }
    }
    #pragma unroll
    for (int q = 0; q < 4; ++q) {
        int f = wave * 4 + q, mi = f >> 3, ni = f & 7;
        #pragma unroll
        for (int r = 0; r < 4; ++r) {
            int row = mi * 16 + g * 4 + r;
            if (row < 24) {
                float v = (nc > 0) ? acc4[q][r] : 0.f;
                size_t o = ((size_t)b * AL_ + a0 + row) * 128 + ni * 16 + r16;
                x_out[o] = v;
                xbf_out[o] = f2bf(v);
            }
        }
    }
}

// ====== Transformer self-attention per (b,h): fused qkv-proj (MFMA) + attn ====
__global__ __launch_bounds__(256) void attn2_kernel(
    const unsigned short* __restrict__ xbf, const unsigned short* __restrict__ WtL,
    unsigned short* __restrict__ o)
{
    __shared__ unsigned short Xs[AL_ * 128];
    __shared__ float qh[AL_ * 20], kh[AL_ * 20], vh[AL_ * 20];
    __shared__ float s[AL_ * 49];
    int bid = blockIdx.x;
    int b = bid >> 3, h = bid & 7;
    int tid = threadIdx.x, wave = tid >> 6, lane = tid & 63;
    int g = lane >> 4, r16 = lane & 15;

    #pragma unroll
    for (int p = 0; p < 3; ++p) {
        int i = p * 256 + tid;           // 0..767
        int a = i >> 4, c = (i & 15) * 8;
        u32x4 v = *(const u32x4*)(&xbf[((size_t)b * AL_ + a) * 128 + c]);
        *(u32x4*)(&Xs[a * 128 + (c & 64) + ((c & 63) ^ ((a & 7) << 3))]) = v;
    }
    __syncthreads();

    if (wave < 3) {
        f32x4 acc[3] = {};
        const unsigned short* Wm = WtL + wave * 16384 + (size_t)(h * 16) * 128;
        #pragma unroll
        for (int kq = 0; kq < 4; ++kq) {
            short8 bf = *(const short8*)(&Wm[(size_t)r16 * 128 + kq * 32 + g * 8]);
            #pragma unroll
            for (int mi = 0; mi < 3; ++mi) {
                int row = mi * 16 + r16;
                int c = kq * 32 + g * 8;
                short8 af = *(const short8*)(&Xs[row * 128 + (c & 64) + ((c & 63) ^ ((row & 7) << 3))]);
                acc[mi] = __builtin_amdgcn_mfma_f32_16x16x32_bf16(af, bf, acc[mi], 0, 0, 0);
            }
        }
        float* dst = (wave == 0) ? qh : (wave == 1) ? kh : vh;
        #pragma unroll
        for (int mi = 0; mi < 3; ++mi)
            #pragma unroll
            for (int r = 0; r < 4; ++r)
                dst[(mi * 16 + g * 4 + r) * 20 + r16] = acc[mi][r];
    }
    __syncthreads();

    for (int i = tid; i < AL_ * AL_; i += 256) {
        int a = i / 48, kx = i - a * 48;
        f32x4 a4 = {0.f, 0.f, 0.f, 0.f};
        #pragma unroll
        for (int c = 0; c < 4; ++c) {
            f32x4 qv = *(const f32x4*)(&qh[a * 20 + c * 4]);
            f32x4 kk = *(const f32x4*)(&kh[kx * 20 + c * 4]);
            a4[0] = fmaf(qv[0], kk[0], a4[0]);
            a4[1] = fmaf(qv[1], kk[1], a4[1]);
            a4[2] = fmaf(qv[2], kk[2], a4[2]);
            a4[3] = fmaf(qv[3], kk[3], a4[3]);
        }
        s[a * 49 + kx] = (a4[0] + a4[1] + a4[2] + a4[3]) * 0.25f;
    }
    __syncthreads();
    for (int ai = 0; ai < 12; ++ai) {
        int a = wave * 12 + ai;
        float v = (lane < 48) ? s[a * 49 + lane] : -3.0e38f;
        float m = v;
        #pragma unroll
        for (int o2 = 32; o2 >= 1; o2 >>= 1) m = fmaxf(m, __shfl_xor(m, o2));
        float e = (lane < 48) ? __expf(v - m) : 0.f;
        float sum = e;
        #pragma unroll
        for (int o2 = 32; o2 >= 1; o2 >>= 1) sum += __shfl_xor(sum, o2);
        if (lane < 48) s[a * 49 + lane] = e * __fdividef(1.f, sum);
    }
    __syncthreads();
    if (tid < 192) {
        int a = tid >> 2, dq = tid & 3;
        f32x4 a4 = {0.f, 0.f, 0.f, 0.f};
        for (int j = 0; j < 48; ++j) {
            float w = s[a * 49 + j];
            f32x4 vv = *(const f32x4*)(&vh[j * 20 + dq * 4]);
            a4[0] = fmaf(w, vv[0], a4[0]);
            a4[1] = fmaf(w, vv[1], a4[1]);
            a4[2] = fmaf(w, vv[2], a4[2]);
            a4[3] = fmaf(w, vv[3], a4[3]);
        }
        u32x2 pb;
        pb[0] = f2bf2(a4[0], a4[1]);
        pb[1] = f2bf2(a4[2], a4[3]);
        *(u32x2*)(&o[((size_t)b * AL_ + a) * 128 + h * 16 + dq * 4]) = pb;
    }
}

// ====== Layer tail: wo-GEMM + LN1 + FFN(2 GEMMs) + LN2, all row-local =========
__global__ __launch_bounds__(256) void layer_tail_kernel(
    const unsigned short* __restrict__ obuf, const unsigned short* __restrict__ Wl,
    const float* __restrict__ b1, const float* __restrict__ b2,
    const float* __restrict__ g1, const float* __restrict__ be1,
    const float* __restrict__ g2, const float* __restrict__ be2,
    float* __restrict__ x, unsigned short* __restrict__ xbf)
{
    __shared__ unsigned short OX[32 * 128];                              // Os then Xs
    __shared__ union { unsigned short hid[32 * 512]; float Cs[32 * 132]; } u2;
    __shared__ float xr[32 * 132];
    const int tid = threadIdx.x, wave = tid >> 6, lane = tid & 63;
    const int g = lane >> 4, r16 = lane & 15;
    const int row0 = blockIdx.x * 32;

    // stage Os (attn output rows, swizzled)
    #pragma unroll
    for (int p = 0; p < 2; ++p) {
        int i = p * 256 + tid;
        int a = i >> 4, c = (i & 15) * 8;
        u32x4 v = *(const u32x4*)(&obuf[(size_t)(row0 + a) * 128 + c]);
        *(u32x4*)(&OX[a * 128 + (c & 64) + ((c & 63) ^ ((a & 7) << 3))]) = v;
    }
    __syncthreads();

    // wo GEMM: 16 frags, f = wave*4+q
    {
        f32x4 wacc[4] = {};
        #pragma unroll
        for (int q = 0; q < 4; ++q) {
            int f = wave * 4 + q, mi = f >> 3, ni = f & 7;
            const unsigned short* Wm = Wl + 49152 + (size_t)(ni * 16 + r16) * 128;
            #pragma unroll
            for (int kq = 0; kq < 4; ++kq) {
                int co = kq * 32 + g * 8;
                int ra = mi * 16 + r16;
                short8 af = *(const short8*)(&OX[ra * 128 + (co & 64) + ((co & 63) ^ ((ra & 7) << 3))]);
                short8 bf = ldg8(Wm + co);
                wacc[q] = __builtin_amdgcn_mfma_f32_16x16x32_bf16(af, bf, wacc[q], 0, 0, 0);
            }
        }
        #pragma unroll
        for (int q = 0; q < 4; ++q) {
            int f = wave * 4 + q, mi = f >> 3, ni = f & 7;
            #pragma unroll
            for (int r = 0; r < 4; ++r)
                u2.Cs[(mi * 16 + g * 4 + r) * 132 + ni * 16 + r16] = wacc[q][r];
        }
    }
    __syncthreads();

    // LN1 (+residual from global x) -> xr (fp32) + Xs (bf16, swizzled)
    #pragma unroll
    for (int rr = 0; rr < 8; ++rr) {
        int row = wave * 8 + rr;
        size_t go = (size_t)(row0 + row) * 128;
        float v0 = u2.Cs[row * 132 + lane] + x[go + lane];
        float v1 = u2.Cs[row * 132 + 64 + lane] + x[go + 64 + lane];
        float sum = v0 + v1, sq = v0 * v0 + v1 * v1;
        #pragma unroll
        for (int o2 = 32; o2 >= 1; o2 >>= 1) {
            sum += __shfl_xor(sum, o2);
            sq  += __shfl_xor(sq, o2);
        }
        float mu = sum * (1.f / 128.f);
        float var = sq * (1.f / 128.f) - mu * mu;
        float rs = rsqrtf(var + 1e-5f);
        float o0 = (v0 - mu) * rs * g1[lane] + be1[lane];
        float o1 = (v1 - mu) * rs * g1[lane + 64] + be1[lane + 64];
        xr[row * 132 + lane] = o0;
        xr[row * 132 + 64 + lane] = o1;
        OX[row * 128 + (lane ^ ((row & 7) << 3))] = f2bf(o0);
        OX[row * 128 + 64 + (lane ^ ((row & 7) << 3))] = f2bf(o1);
    }
    __syncthreads();

    // hidden = relu(Xs @ w1 + b1): wave owns cols [wave*128, +128)
    {
        f32x4 hacc[2][8] = {};
        #pragma unroll
        for (int nf = 0; nf < 8; ++nf) {
            int col = wave * 128 + nf * 16 + r16;
            const unsigned short* Wm = Wl + 65536 + (size_t)col * 128;
            #pragma unroll
            for (int kq = 0; kq < 4; ++kq) {
                int co = kq * 32 + g * 8;
                short8 bf = ldg8(Wm + co);
                #pragma unroll
                for (int mi = 0; mi < 2; ++mi) {
                    int ra = mi * 16 + r16;
                    short8 af = *(const short8*)(&OX[ra * 128 + (co & 64) + ((co & 63) ^ ((ra & 7) << 3))]);
                    hacc[mi][nf] = __builtin_amdgcn_mfma_f32_16x16x32_bf16(af, bf, hacc[mi][nf], 0, 0, 0);
                }
            }
        }
        #pragma unroll
        for (int nf = 0; nf < 8; ++nf) {
            int col = wave * 128 + nf * 16 + r16;
            float bv = b1[col];
            #pragma unroll
            for (int mi = 0; mi < 2; ++mi)
                #pragma unroll
                for (int r = 0; r < 4; ++r) {
                    int rowa = mi * 16 + g * 4 + r;
                    u2.hid[rowa * 512 + (col & 448) + ((col & 63) ^ ((rowa & 7) << 3))] =
                        f2bf(fmaxf(hacc[mi][nf][r] + bv, 0.f));
                }
        }
    }
    __syncthreads();

    // y = hid @ w2: 16 frags, K=512
    f32x4 yacc[4] = {};
    #pragma unroll
    for (int q = 0; q < 4; ++q) {
        int f = wave * 4 + q, mi = f >> 3, ni = f & 7;
        const unsigned short* Wm = Wl + 131072 + (size_t)(ni * 16 + r16) * 512;
        #pragma unroll
        for (int kq = 0; kq < 16; ++kq) {
            int co = kq * 32 + g * 8;
            int ra = mi * 16 + r16;
            short8 af = *(const short8*)(&u2.hid[ra * 512 + (co & 448) + ((co & 63) ^ ((ra & 7) << 3))]);
            short8 bf = ldg8(Wm + co);
            yacc[q] = __builtin_amdgcn_mfma_f32_16x16x32_bf16(af, bf, yacc[q], 0, 0, 0);
        }
    }
    __syncthreads();  // hid dead
    #pragma unroll
    for (int q = 0; q < 4; ++q) {
        int f = wave * 4 + q, mi = f >> 3, ni = f & 7;
        float bv = b2[ni * 16 + r16];
        #pragma unroll
        for (int r = 0; r < 4; ++r)
            u2.Cs[(mi * 16 + g * 4 + r) * 132 + ni * 16 + r16] = yacc[q][r] + bv;
    }
    __syncthreads();

    // LN2 (+residual xr) -> global x + xbf
    #pragma unroll
    for (int rr = 0; rr < 8; ++rr) {
        int row = wave * 8 + rr;
        size_t go = (size_t)(row0 + row) * 128;
        float v0 = u2.Cs[row * 132 + lane] + xr[row * 132 + lane];
        float v1 = u2.Cs[row * 132 + 64 + lane] + xr[row * 132 + 64 + lane];
        float sum = v0 + v1, sq = v0 * v0 + v1 * v1;
        #pragma unroll
        for (int o2 = 32; o2 >= 1; o2 >>= 1) {
            sum += __shfl_xor(sum, o2);
            sq  += __shfl_xor(sq, o2);
        }
        float mu = sum * (1.f / 128.f);
        float var = sq * (1.f / 128.f) - mu * mu;
        float rs = rsqrtf(var + 1e-5f);
        float o0 = (v0 - mu) * rs * g2[lane] + be2[lane];
        float o1 = (v1 - mu) * rs * g2[lane + 64] + be2[lane + 64];
        x[go + lane] = o0;
        x[go + 64 + lane] = o1;
        xbf[go + lane] = f2bf(o0);
        xbf[go + 64 + lane] = f2bf(o1);
    }
}

// ================= Classifier head ============================================
__global__ __launch_bounds__(64) void head_kernel(
    const float* __restrict__ x, const float* __restrict__ w1,
    const float* __restrict__ b1, const float* __restrict__ w2,
    const float* __restrict__ b2, float* __restrict__ out)
{
    int b = blockIdx.x;
    int j = threadIdx.x;
    const float* xr = x + ((size_t)b * AL_ + (AL_ - 1)) * DH_;
    float hj = b1[j];
    for (int d = 0; d < DH_; ++d) hj = fmaf(xr[d], w1[d * 64 + j], hj);
    hj = fmaxf(hj, 0.f);
    float acc = hj * w2[j];
    #pragma unroll
    for (int d = 32; d >= 1; d >>= 1) acc += __shfl_xor(acc, d);
    if (j == 0) out[b] = acc + b2[0];
}

// ================= Launch =====================================================
extern "C" void kernel_launch(void* const* d_in, const int* in_sizes, int n_in,
                              void* d_out, int out_size, void* d_ws, size_t ws_size,
                              hipStream_t stream) {
    (void)in_sizes; (void)n_in; (void)out_size; (void)ws_size;
    const float* cls_emb    = (const float*)d_in[0];
    const float* note_times = (const float*)d_in[1];
    const int*   note_counts= (const int*)d_in[2];
    const float* proj_w     = (const float*)d_in[3];
    const float* proj_b     = (const float*)d_in[4];
    const float* te_w       = (const float*)d_in[5];
    const float* te_b       = (const float*)d_in[6];
    const float* wq         = (const float*)d_in[7];
    const float* wk         = (const float*)d_in[8];
    const float* tf_wq      = (const float*)d_in[9];
    const float* tf_wk      = (const float*)d_in[10];
    const float* tf_wv      = (const float*)d_in[11];
    const float* tf_wo      = (const float*)d_in[12];
    const float* tf_ln1_g   = (const float*)d_in[13];
    const float* tf_ln1_b   = (const float*)d_in[14];
    const float* tf_w1      = (const float*)d_in[15];
    const float* tf_b1      = (const float*)d_in[16];
    const float* tf_w2      = (const float*)d_in[17];
    const float* tf_b2      = (const float*)d_in[18];
    const float* tf_ln2_g   = (const float*)d_in[19];
    const float* tf_ln2_b   = (const float*)d_in[20];
    const float* cls_w1     = (const float*)d_in[21];
    const float* cls_b1     = (const float*)d_in[22];
    const float* cls_w2     = (const float*)d_in[23];
    const float* cls_b2     = (const float*)d_in[24];
    float* out = (float*)d_out;
    float* ws = (float*)d_ws;

    // workspace layout (float units)
    unsigned short* note_emb16 = (unsigned short*)(ws + 0);       // 1,048,576 f
    float* x        = ws + 1048576;                                // 1,572,864 f
    unsigned short* obuf16 = (unsigned short*)(ws + 2621440);      // 786,432 f
    unsigned short* xbf    = (unsigned short*)(ws + 3407872);      // 786,432 f
    unsigned short* wt     = (unsigned short*)(ws + 4194304);      // 344,064 f

    // ---- weight prep table
    TTab tab;
    int tile = 0, idx = 0;
    auto add = [&](const float* src, int dstOff, int K, int N) {
        tab.e[idx].src = src; tab.e[idx].dstOff = dstOff;
        tab.e[idx].K = K; tab.e[idx].N = N; tab.e[idx].tile0 = tile;
        tile += (K / 64) * (N / 64); ++idx;
    };
    add(proj_w, 0, DT_, DH_);
    int layerBase[NL_];
    for (int i = 0; i < NL_; ++i) {
        int base = 98304 + i * 196608;
        layerBase[i] = base;
        add(tf_wq + (size_t)i * DH_ * DH_, base,           DH_, DH_);
        add(tf_wk + (size_t)i * DH_ * DH_, base + 16384,   DH_, DH_);
        add(tf_wv + (size_t)i * DH_ * DH_, base + 32768,   DH_, DH_);
        add(tf_wo + (size_t)i * DH_ * DH_, base + 49152,   DH_, DH_);
        add(tf_w1 + (size_t)i * DH_ * DFF_, base + 65536,  DH_, DFF_);
        add(tf_w2 + (size_t)i * DFF_ * DH_, base + 131072, DFF_, DH_);
    }
    prep_weights_kernel<<<tile, 256, 0, stream>>>(tab, wt);

    const int Mx = B_ * AL_; // 12288

    // note_emb = bf16(cls_emb @ proj_w + proj_b)
    gemm_proj_kernel<<<(B_ * L_) / 32, 256, 0, stream>>>(
        cls_emb, wt, proj_b, note_emb16, B_ * L_, DH_, DT_);

    // first attention (q-proj folded in), 2 blocks per batch
    first_attn_kernel<<<B_ * 2, 256, 0, stream>>>(
        note_times, note_counts, te_w, te_b, wq, wk, note_emb16, x, xbf);

    for (int i = 0; i < NL_; ++i) {
        int base = layerBase[i];
        attn2_kernel<<<B_ * H_, 256, 0, stream>>>(xbf, wt + base, obuf16);
        layer_tail_kernel<<<Mx / 32, 256, 0, stream>>>(
            obuf16, wt + base,
            tf_b1 + i * DFF_, tf_b2 + i * DH_,
            tf_ln1_g + i * DH_, tf_ln1_b + i * DH_,
            tf_ln2_g + i * DH_, tf_ln2_b + i * DH_,
            x, xbf);
    }

    head_kernel<<<B_, 64, 0, stream>>>(x, cls_w1, cls_b1, cls_w2, cls_b2, out);
}

// Round 7
// 204.064 us; speedup vs baseline: 1.4841x; 1.2831x over previous
//
#include <hip/hip_runtime.h>
#include <hip/hip_bf16.h>

// Problem constants
#define B_   256
#define L_   64
#define DT_  768
#define DH_  128
#define AL_  48
#define DTE_ 64
#define H_   8
#define NL_  3
#define DFF_ 512

typedef __attribute__((ext_vector_type(4))) float f32x4;
typedef __attribute__((ext_vector_type(4))) unsigned int u32x4;
typedef __attribute__((ext_vector_type(2))) unsigned int u32x2;
typedef __attribute__((ext_vector_type(8))) short short8;

__device__ inline unsigned short f2bf(float f) {
    union { float f; unsigned u; } v; v.f = f;
    unsigned r = (v.u + 0x7FFFu + ((v.u >> 16) & 1u)) >> 16;
    return (unsigned short)r;
}
__device__ inline unsigned f2bf2(float a, float b) {
    return (unsigned)f2bf(a) | ((unsigned)f2bf(b) << 16);
}
__device__ inline float bf2f(unsigned short u) {
    union { unsigned u; float f; } v; v.u = ((unsigned)u) << 16; return v.f;
}
__device__ inline short8 ldg8(const unsigned short* p) {
    union { short8 s; u32x4 v; } r;
    r.v = *(const u32x4*)p;
    return r.s;
}
// packed f16 helpers (inline asm: guaranteed on gfx950)
__device__ inline unsigned pk_f16(float a, float b) {
    unsigned r;
    asm("v_cvt_pkrtz_f16_f32 %0, %1, %2" : "=v"(r) : "v"(a), "v"(b));
    return r;
}
__device__ inline unsigned pk_max(unsigned a, unsigned b) {
    unsigned r;
    asm("v_pk_max_f16 %0, %1, %2" : "=v"(r) : "v"(a), "v"(b));
    return r;
}
__device__ inline float f16_lo(unsigned h) {
    float f; asm("v_cvt_f32_f16 %0, %1" : "=v"(f) : "v"(h)); return f;
}
__device__ inline float f16_hi(unsigned h) {
    float f; unsigned t = h >> 16;
    asm("v_cvt_f32_f16 %0, %1" : "=v"(f) : "v"(t)); return f;
}

// ================= Weight prep: fp32 [K][N] -> bf16 Wt [N][K] =================
struct TEnt { const float* src; int dstOff; int K; int N; int tile0; };
struct TTab { TEnt e[19]; };

__global__ __launch_bounds__(256) void prep_weights_kernel(TTab tab, unsigned short* __restrict__ wt)
{
    __shared__ unsigned short lds[64][72];
    int ei = 0;
    #pragma unroll
    for (int j = 1; j < 19; ++j) if ((int)blockIdx.x >= tab.e[j].tile0) ei = j;
    TEnt e = tab.e[ei];
    int t = blockIdx.x - e.tile0;
    int tilesK = e.K >> 6;
    int tk = t % tilesK, tn = t / tilesK;
    int tid = threadIdx.x;
    #pragma unroll
    for (int p = 0; p < 16; ++p) {
        int kk = p * 4 + (tid >> 6);
        int n = tid & 63;
        float v = e.src[(size_t)(tk * 64 + kk) * e.N + tn * 64 + n];
        lds[n][kk] = f2bf(v);
    }
    __syncthreads();
    #pragma unroll
    for (int p = 0; p < 2; ++p) {
        int c = p * 256 + tid;
        int n = c >> 3, q = c & 7;
        u32x4 v = *(const u32x4*)(&lds[n][q * 8]);
        *(u32x4*)(&wt[(size_t)e.dstOff + (size_t)(tn * 64 + n) * e.K + tk * 64 + q * 8]) = v;
    }
}

// ================= q_all (48x64 fp32): time_embed(arange(48)) @ wq ============
__global__ __launch_bounds__(256) void qk_prep_kernel(
    const float* __restrict__ te_w, const float* __restrict__ te_b,
    const float* __restrict__ wq, float* __restrict__ q_allG)
{
    __shared__ float qte[AL_ * 68];
    int tid = threadIdx.x;
    for (int i = tid; i < AL_ * 64; i += 256) {
        int a = i >> 6, j = i & 63;
        float lin = fmaf((float)a, te_w[j], te_b[j]);
        qte[a * 68 + j] = (j == 0) ? lin : __sinf(lin);
    }
    __syncthreads();
    for (int i = tid; i < AL_ * 64; i += 256) {
        int a = i >> 6, d = i & 63;
        float s0 = 0.f, s1 = 0.f, s2 = 0.f, s3 = 0.f;
        for (int j = 0; j < 64; j += 4) {
            s0 = fmaf(qte[a * 68 + j],     wq[j * 64 + d],       s0);
            s1 = fmaf(qte[a * 68 + j + 1], wq[(j + 1) * 64 + d], s1);
            s2 = fmaf(qte[a * 68 + j + 2], wq[(j + 2) * 64 + d], s2);
            s3 = fmaf(qte[a * 68 + j + 3], wq[(j + 3) * 64 + d], s3);
        }
        q_allG[i] = (s0 + s1) + (s2 + s3);
    }
}

// ================= bf16 MFMA GEMM (proj): C = A(fp32 MxK) @ Wt^T -> bf16 ======
__global__ __launch_bounds__(256) void gemm_proj_kernel(
    const float* __restrict__ A, const unsigned short* __restrict__ Wt,
    const float* __restrict__ bias, unsigned short* __restrict__ C,
    int M, int N, int K)
{
    __shared__ unsigned short As[32 * 64];
    __shared__ unsigned short Bs[128 * 64];
    int tid = threadIdx.x;
    int bm = blockIdx.x * 32;
    int wave = tid >> 6, lane = tid & 63;
    int wm = wave >> 1, wn = wave & 1;
    int g = lane >> 4, r16 = lane & 15;

    f32x4 acc[4] = {};

    for (int k0 = 0; k0 < K; k0 += 64) {
        #pragma unroll
        for (int p = 0; p < 2; ++p) {
            int row = p * 16 + (tid >> 4);
            int c4 = tid & 15;
            f32x4 v = *(const f32x4*)(&A[(size_t)(bm + row) * K + k0 + c4 * 4]);
            u32x2 w;
            w[0] = f2bf2(v[0], v[1]);
            w[1] = f2bf2(v[2], v[3]);
            *(u32x2*)(&As[row * 64 + ((c4 * 4) ^ ((row & 7) << 3))]) = w;
        }
        #pragma unroll
        for (int p = 0; p < 4; ++p) {
            int c = p * 256 + tid;
            int n = c >> 3, q = c & 7;
            u32x4 v = *(const u32x4*)(&Wt[(size_t)n * K + k0 + q * 8]);
            *(u32x4*)(&Bs[n * 64 + ((q * 8) ^ ((n & 7) << 3))]) = v;
        }
        __syncthreads();
        #pragma unroll
        for (int kk = 0; kk < 2; ++kk) {
            short8 af, bf[4];
            int co = kk * 32 + g * 8;
            {
                int row = wm * 16 + r16;
                af = *(const short8*)(&As[row * 64 + (co ^ ((row & 7) << 3))]);
            }
            #pragma unroll
            for (int ni = 0; ni < 4; ++ni) {
                int row = wn * 64 + ni * 16 + r16;
                bf[ni] = *(const short8*)(&Bs[row * 64 + (co ^ ((row & 7) << 3))]);
            }
            #pragma unroll
            for (int ni = 0; ni < 4; ++ni)
                acc[ni] = __builtin_amdgcn_mfma_f32_16x16x32_bf16(af, bf[ni], acc[ni], 0, 0, 0);
        }
        __syncthreads();
    }
    #pragma unroll
    for (int ni = 0; ni < 4; ++ni) {
        int col = wn * 64 + ni * 16 + r16;
        float bv = bias[col];
        #pragma unroll
        for (int r = 0; r < 4; ++r) {
            int row = bm + wm * 16 + g * 4 + r;
            C[(size_t)row * N + col] = f2bf(acc[ni][r] + bv);
        }
    }
}

// ================= First attention: block = (b, half of 48 alpha rows) ========
// kte in regs (lane=l), kk via scalar-load GEMV, packed-f16 max, sums via MFMA.
__global__ __launch_bounds__(256) void first_attn_kernel(
    const float* __restrict__ note_times, const int* __restrict__ note_counts,
    const float* __restrict__ te_w, const float* __restrict__ te_b,
    const float* __restrict__ wk, const float* __restrict__ q_all,
    const unsigned short* __restrict__ note_emb,
    float* __restrict__ x_out, unsigned short* __restrict__ xbf_out)
{
    __shared__ union RU {
        float kkL[64 * 68];                                               // 17,408 B
        unsigned short E[32 * 256];                                       // 16,384 B
        struct { unsigned short As[32 * 64]; unsigned short Bs[128 * 64]; } mm; // 20,480 B
    } ru;
    __shared__ float rsL[32][8];

    const int bx = blockIdx.x;
    const int b = bx >> 1, a0 = (bx & 1) * 24;
    const int tid = threadIdx.x, lane = tid & 63;
    const int wv = __builtin_amdgcn_readfirstlane(tid >> 6);
    const int g = lane >> 4, r16 = lane & 15;
    const int nc = note_counts[b];

    // ---- phase A: per-lane kte (l = lane), 64 regs
    float kte[64];
    {
        float t = note_times[b * 64 + lane];
        #pragma unroll
        for (int j = 0; j < 64; ++j) {
            float lin = fmaf(t, te_w[j], te_b[j]);
            kte[j] = (j == 0) ? lin : __sinf(lin);
        }
    }
    // ---- phase B: kk columns d in [wv*16, +16); wk via scalar loads (uniform)
    {
        float kvp[16] = {};
        #pragma unroll
        for (int j = 0; j < 64; ++j) {
            #pragma unroll
            for (int dd = 0; dd < 16; ++dd)
                kvp[dd] = fmaf(kte[j], wk[j * 64 + wv * 16 + dd], kvp[dd]);
        }
        #pragma unroll
        for (int q4 = 0; q4 < 4; ++q4)
            *(f32x4*)(&ru.kkL[lane * 68 + wv * 16 + q4 * 4]) = *(const f32x4*)(&kvp[q4 * 4]);
    }
    __syncthreads();
    // ---- read full kv row (lane = l)
    float kv[64];
    #pragma unroll
    for (int q4 = 0; q4 < 16; ++q4)
        *(f32x4*)(&kv[q4 * 4]) = *(const f32x4*)(&ru.kkL[lane * 68 + q4 * 4]);
    __syncthreads();   // kkL dead -> E region

    float abar[6] = {};
    const float scale = 0.35355339059327373f; // 1/sqrt(8)
    #pragma unroll
    for (int p = 0; p < 2; ++p) {
        float e_reg[6][4];
        #pragma unroll
        for (int i = 0; i < 6; ++i) {
            int a = wv * 6 + i;
            float s[4];
            #pragma unroll
            for (int h = 0; h < 4; ++h) {
                float acc = 0.f;
                #pragma unroll
                for (int d = 0; d < 8; ++d)
                    acc = fmaf(q_all[(a0 + a) * 64 + p * 32 + h * 8 + d],
                               kv[p * 32 + h * 8 + d], acc);
                s[h] = (lane < nc) ? acc * scale : -1e9f;
            }
            // per-head max via packed-f16 butterfly (tolerance +-87 on softmax max)
            unsigned m0 = pk_f16(s[0], s[1]);
            unsigned m1 = pk_f16(s[2], s[3]);
            #pragma unroll
            for (int st = 32; st >= 1; st >>= 1) {
                m0 = pk_max(m0, (unsigned)__shfl_xor((int)m0, st));
                m1 = pk_max(m1, (unsigned)__shfl_xor((int)m1, st));
            }
            float mm[4] = { f16_lo(m0), f16_hi(m0), f16_lo(m1), f16_hi(m1) };
            #pragma unroll
            for (int h = 0; h < 4; ++h) {
                float e = __expf(s[h] - mm[h]);
                e_reg[i][h] = e;
                int k = h * 64 + lane;
                ru.E[a * 256 + (k ^ ((a & 7) << 3))] = f2bf(e);
            }
        }
        __syncthreads();
        // sums via MFMA: S[a][h] = sum_l E, ones-B built in regs (waves 0,1)
        if (wv < 2) {
            f32x4 acc = {0.f, 0.f, 0.f, 0.f};
            #pragma unroll
            for (int ks = 0; ks < 8; ++ks) {
                int row = wv * 16 + r16;
                short8 af = *(const short8*)(&ru.E[row * 256 + ((ks * 32 + g * 8) ^ ((row & 7) << 3))]);
                short bb = (r16 == (ks >> 1)) ? (short)0x3F80 : (short)0;
                short8 bf = { bb, bb, bb, bb, bb, bb, bb, bb };
                acc = __builtin_amdgcn_mfma_f32_16x16x32_bf16(af, bf, acc, 0, 0, 0);
            }
            if (r16 < 4) {
                #pragma unroll
                for (int r = 0; r < 4; ++r)
                    rsL[wv * 16 + g * 4 + r][p * 4 + r16] = 0.125f / fmaxf(acc[r], 1e-20f);
            }
        }
        __syncthreads();
        #pragma unroll
        for (int i = 0; i < 6; ++i) {
            int a = wv * 6 + i;
            f32x4 rv = *(const f32x4*)(&rsL[a][p * 4]);
            abar[i] = fmaf(e_reg[i][0], rv[0], abar[i]);
            abar[i] = fmaf(e_reg[i][1], rv[1], abar[i]);
            abar[i] = fmaf(e_reg[i][2], rv[2], abar[i]);
            abar[i] = fmaf(e_reg[i][3], rv[3], abar[i]);
        }
    }
    // ---- stage Bs = note_emb^T swizzled; write As = abar (E dead)
    {
        int l = tid & 63;
        #pragma unroll
        for (int pp = 0; pp < 4; ++pp) {
            int c = pp * 4 + (tid >> 6);
            u32x4 v = *(const u32x4*)(&note_emb[((size_t)b * 64 + l) * 128 + c * 8]);
            #pragma unroll
            for (int j = 0; j < 8; ++j) {
                unsigned short h16 = (unsigned short)((j & 1) ? (v[j >> 1] >> 16) : (v[j >> 1] & 0xffff));
                int f = c * 8 + j;
                ru.mm.Bs[f * 64 + (l ^ ((f & 7) << 3))] = h16;
            }
        }
    }
    #pragma unroll
    for (int i = 0; i < 6; ++i) {
        int a = wv * 6 + i;
        ru.mm.As[a * 64 + (lane ^ ((a & 7) << 3))] = f2bf(abar[i]);
    }
    __syncthreads();

    // ---- PV via MFMA: 16 frags (2m x 8n) over 4 waves; rows >= 24 discarded
    f32x4 pv[4] = {};
    #pragma unroll
    for (int q = 0; q < 4; ++q) {
        int f = wv * 4 + q, mi = f >> 3, ni = f & 7;
        #pragma unroll
        for (int ks = 0; ks < 2; ++ks) {
            int co = ks * 32 + g * 8;
            int raw = mi * 16 + r16, rb = ni * 16 + r16;
            short8 af = *(const short8*)(&ru.mm.As[raw * 64 + (co ^ ((raw & 7) << 3))]);
            short8 bf = *(const short8*)(&ru.mm.Bs[rb * 64 + (co ^ ((rb & 7) << 3))]);
            pv[q] = __builtin_amdgcn_mfma_f32_16x16x32_bf16(af, bf, pv[q], 0, 0, 0);
        }
    }
    #pragma unroll
    for (int q = 0; q < 4; ++q) {
        int f = wv * 4 + q, mi = f >> 3, ni = f & 7;
        #pragma unroll
        for (int r = 0; r < 4; ++r) {
            int row = mi * 16 + g * 4 + r;
            if (row < 24) {
                float v = (nc > 0) ? pv[q][r] : 0.f;
                size_t o = ((size_t)b * AL_ + a0 + row) * 128 + ni * 16 + r16;
                x_out[o] = v;
                xbf_out[o] = f2bf(v);
            }
        }
    }
}

// ====== Transformer self-attn per (b,h): qkv-MFMA + scores-MFMA + PV-MFMA =====
__global__ __launch_bounds__(256) void attn2_kernel(
    const unsigned short* __restrict__ xbf, const unsigned short* __restrict__ WtL,
    unsigned short* __restrict__ o)
{
    __shared__ unsigned short Xs[AL_ * 128];    // 12,288 B swizzled
    __shared__ unsigned short qM[AL_ * 40];     // [a][k]: 0..15 data, 16..31 zero
    __shared__ unsigned short kM[AL_ * 40];
    __shared__ unsigned short vT[16 * 72];      // [d][k=a']: 48..63 zero
    __shared__ float sL[AL_ * 52];
    __shared__ unsigned short P[AL_ * 64];      // swizzled bf16 probs
    int bid = blockIdx.x;
    int b = bid >> 3, h = bid & 7;
    int tid = threadIdx.x, lane = tid & 63;
    int wv = __builtin_amdgcn_readfirstlane(tid >> 6);
    int g = lane >> 4, r16 = lane & 15;

    #pragma unroll
    for (int p = 0; p < 3; ++p) {
        int i = p * 256 + tid;
        int a = i >> 4, c = (i & 15) * 8;
        u32x4 v = *(const u32x4*)(&xbf[((size_t)b * AL_ + a) * 128 + c]);
        *(u32x4*)(&Xs[a * 128 + (c & 64) + ((c & 63) ^ ((a & 7) << 3))]) = v;
    }
    // zero pads
    #pragma unroll
    for (int z = 0; z < 3; ++z) {
        int e = z * 256 + tid;
        int a = e >> 4, k2 = 16 + (e & 15);
        qM[a * 40 + k2] = 0;
        kM[a * 40 + k2] = 0;
    }
    { int d = tid >> 4, k2 = 48 + (tid & 15); vT[d * 72 + k2] = 0; }
    __syncthreads();

    // qkv: waves 0..2 (M=48, N=16, K=128)
    if (wv < 3) {
        f32x4 acc[3] = {};
        const unsigned short* Wm = WtL + wv * 16384 + (size_t)(h * 16) * 128;
        #pragma unroll
        for (int kq = 0; kq < 4; ++kq) {
            short8 bf = ldg8(&Wm[(size_t)r16 * 128 + kq * 32 + g * 8]);
            #pragma unroll
            for (int mi = 0; mi < 3; ++mi) {
                int row = mi * 16 + r16;
                int c = kq * 32 + g * 8;
                short8 af = *(const short8*)(&Xs[row * 128 + (c & 64) + ((c & 63) ^ ((row & 7) << 3))]);
                acc[mi] = __builtin_amdgcn_mfma_f32_16x16x32_bf16(af, bf, acc[mi], 0, 0, 0);
            }
        }
        #pragma unroll
        for (int mi = 0; mi < 3; ++mi) {
            #pragma unroll
            for (int r = 0; r < 4; ++r) {
                int a = mi * 16 + g * 4 + r;
                unsigned short hv = f2bf(acc[mi][r]);
                if (wv == 0) qM[a * 40 + r16] = hv;
                else if (wv == 1) kM[a * 40 + r16] = hv;
                else vT[r16 * 72 + a] = hv;
            }
        }
    }
    __syncthreads();

    // scores: 9 frags (3m x 3n) via MFMA K=32 (zero-padded)
    if (wv < 3) {
        #pragma unroll
        for (int ni = 0; ni < 3; ++ni) {
            f32x4 acc = {0.f, 0.f, 0.f, 0.f};
            short8 af = *(const short8*)(&qM[(wv * 16 + r16) * 40 + g * 8]);
            short8 bf = *(const short8*)(&kM[(ni * 16 + r16) * 40 + g * 8]);
            acc = __builtin_amdgcn_mfma_f32_16x16x32_bf16(af, bf, acc, 0, 0, 0);
            #pragma unroll
            for (int r = 0; r < 4; ++r)
                sL[(wv * 16 + g * 4 + r) * 52 + ni * 16 + r16] = acc[r] * 0.25f;
        }
    }
    __syncthreads();

    // softmax transposed: wave 0, lane = a row, all in registers
    if (wv == 0 && lane < 48) {
        float sv[48];
        #pragma unroll
        for (int c4 = 0; c4 < 12; ++c4)
            *(f32x4*)(&sv[c4 * 4]) = *(const f32x4*)(&sL[lane * 52 + c4 * 4]);
        float m = sv[0];
        #pragma unroll
        for (int j = 1; j < 48; ++j) m = fmaxf(m, sv[j]);
        float sum = 0.f;
        #pragma unroll
        for (int j = 0; j < 48; ++j) { sv[j] = __expf(sv[j] - m); sum += sv[j]; }
        float inv = __fdividef(1.f, sum);
        #pragma unroll
        for (int oc = 0; oc < 8; ++oc) {
            u32x4 w = {0u, 0u, 0u, 0u};
            if (oc < 6) {
                w[0] = f2bf2(sv[oc * 8 + 0] * inv, sv[oc * 8 + 1] * inv);
                w[1] = f2bf2(sv[oc * 8 + 2] * inv, sv[oc * 8 + 3] * inv);
                w[2] = f2bf2(sv[oc * 8 + 4] * inv, sv[oc * 8 + 5] * inv);
                w[3] = f2bf2(sv[oc * 8 + 6] * inv, sv[oc * 8 + 7] * inv);
            }
            *(u32x4*)(&P[lane * 64 + ((oc * 8) ^ ((lane & 7) << 3))]) = w;
        }
    }
    __syncthreads();

    // PV: out[a][d] = sum_a' P[a][a'] v[a'][d]; 3 m-frags, K=64 (padded)
    if (wv < 3) {
        f32x4 acc = {0.f, 0.f, 0.f, 0.f};
        #pragma unroll
        for (int ks = 0; ks < 2; ++ks) {
            int co = ks * 32 + g * 8;
            int rp = wv * 16 + r16;
            short8 af = *(const short8*)(&P[rp * 64 + (co ^ ((rp & 7) << 3))]);
            short8 bf = *(const short8*)(&vT[r16 * 72 + co]);
            acc = __builtin_amdgcn_mfma_f32_16x16x32_bf16(af, bf, acc, 0, 0, 0);
        }
        #pragma unroll
        for (int r = 0; r < 4; ++r) {
            int a = wv * 16 + g * 4 + r;
            o[((size_t)b * AL_ + a) * 128 + h * 16 + r16] = f2bf(acc[r]);
        }
    }
}

// ====== Layer tail (16 rows/block): wo-GEMM + LN1 + FFN + LN2 =================
__global__ __launch_bounds__(256) void layer_tail_kernel(
    const unsigned short* __restrict__ obuf, const unsigned short* __restrict__ Wl,
    const float* __restrict__ b1, const float* __restrict__ b2,
    const float* __restrict__ g1, const float* __restrict__ be1,
    const float* __restrict__ g2, const float* __restrict__ be2,
    float* __restrict__ x, unsigned short* __restrict__ xbf)
{
    __shared__ unsigned short OX[16 * 128];                              // 4 KB
    __shared__ union { unsigned short hid[16 * 512]; float Cs[16 * 132]; } u2;
    __shared__ float xr[16 * 132];
    const int tid = threadIdx.x, lane = tid & 63;
    const int wv = __builtin_amdgcn_readfirstlane(tid >> 6);
    const int g = lane >> 4, r16 = lane & 15;
    const int row0 = blockIdx.x * 16;

    {
        int a = tid >> 4, c = (tid & 15) * 8;
        u32x4 v = *(const u32x4*)(&obuf[(size_t)(row0 + a) * 128 + c]);
        *(u32x4*)(&OX[a * 128 + (c & 64) + ((c & 63) ^ ((a & 7) << 3))]) = v;
    }
    __syncthreads();

    // wo GEMM: 8 frags (1m x 8n): wave does ni = wv*2 + {0,1}
    {
        f32x4 wacc[2] = {};
        #pragma unroll
        for (int q = 0; q < 2; ++q) {
            int ni = wv * 2 + q;
            const unsigned short* Wm = Wl + 49152 + (size_t)(ni * 16 + r16) * 128;
            #pragma unroll
            for (int kq = 0; kq < 4; ++kq) {
                int co = kq * 32 + g * 8;
                short8 af = *(const short8*)(&OX[r16 * 128 + (co & 64) + ((co & 63) ^ ((r16 & 7) << 3))]);
                short8 bf = ldg8(Wm + co);
                wacc[q] = __builtin_amdgcn_mfma_f32_16x16x32_bf16(af, bf, wacc[q], 0, 0, 0);
            }
        }
        #pragma unroll
        for (int q = 0; q < 2; ++q) {
            int ni = wv * 2 + q;
            #pragma unroll
            for (int r = 0; r < 4; ++r)
                u2.Cs[(g * 4 + r) * 132 + ni * 16 + r16] = wacc[q][r];
        }
    }
    __syncthreads();

    // LN1 (+residual) -> xr + OX (bf16 swizzled)
    #pragma unroll
    for (int rr = 0; rr < 4; ++rr) {
        int row = wv * 4 + rr;
        size_t go = (size_t)(row0 + row) * 128;
        float v0 = u2.Cs[row * 132 + lane] + x[go + lane];
        float v1 = u2.Cs[row * 132 + 64 + lane] + x[go + 64 + lane];
        float sum = v0 + v1, sq = v0 * v0 + v1 * v1;
        #pragma unroll
        for (int o2 = 32; o2 >= 1; o2 >>= 1) {
            sum += __shfl_xor(sum, o2);
            sq  += __shfl_xor(sq, o2);
        }
        float mu = sum * (1.f / 128.f);
        float var = sq * (1.f / 128.f) - mu * mu;
        float rs = rsqrtf(var + 1e-5f);
        float o0 = (v0 - mu) * rs * g1[lane] + be1[lane];
        float o1 = (v1 - mu) * rs * g1[lane + 64] + be1[lane + 64];
        xr[row * 132 + lane] = o0;
        xr[row * 132 + 64 + lane] = o1;
        OX[row * 128 + (lane ^ ((row & 7) << 3))] = f2bf(o0);
        OX[row * 128 + 64 + (lane ^ ((row & 7) << 3))] = f2bf(o1);
    }
    __syncthreads();

    // hidden = relu(Xs @ w1 + b1): wave owns cols [wv*128, +128)
    {
        f32x4 hacc[8] = {};
        #pragma unroll
        for (int nf = 0; nf < 8; ++nf) {
            int col = wv * 128 + nf * 16 + r16;
            const unsigned short* Wm = Wl + 65536 + (size_t)col * 128;
            #pragma unroll
            for (int kq = 0; kq < 4; ++kq) {
                int co = kq * 32 + g * 8;
                short8 bf = ldg8(Wm + co);
                short8 af = *(const short8*)(&OX[r16 * 128 + (co & 64) + ((co & 63) ^ ((r16 & 7) << 3))]);
                hacc[nf] = __builtin_amdgcn_mfma_f32_16x16x32_bf16(af, bf, hacc[nf], 0, 0, 0);
            }
        }
        #pragma unroll
        for (int nf = 0; nf < 8; ++nf) {
            int col = wv * 128 + nf * 16 + r16;
            float bv = b1[col];
            #pragma unroll
            for (int r = 0; r < 4; ++r) {
                int rowa = g * 4 + r;
                u2.hid[rowa * 512 + (col & 448) + ((col & 63) ^ ((rowa & 7) << 3))] =
                    f2bf(fmaxf(hacc[nf][r] + bv, 0.f));
            }
        }
    }
    __syncthreads();

    // y = hid @ w2 (K=512): 8 frags: wave does ni = wv*2 + {0,1}
    f32x4 yacc[2] = {};
    #pragma unroll
    for (int q = 0; q < 2; ++q) {
        int ni = wv * 2 + q;
        const unsigned short* Wm = Wl + 131072 + (size_t)(ni * 16 + r16) * 512;
        #pragma unroll
        for (int kq = 0; kq < 16; ++kq) {
            int co = kq * 32 + g * 8;
            short8 af = *(const short8*)(&u2.hid[r16 * 512 + (co & 448) + ((co & 63) ^ ((r16 & 7) << 3))]);
            short8 bf = ldg8(Wm + co);
            yacc[q] = __builtin_amdgcn_mfma_f32_16x16x32_bf16(af, bf, yacc[q], 0, 0, 0);
        }
    }
    __syncthreads();  // hid dead
    #pragma unroll
    for (int q = 0; q < 2; ++q) {
        int ni = wv * 2 + q;
        float bv = b2[ni * 16 + r16];
        #pragma unroll
        for (int r = 0; r < 4; ++r)
            u2.Cs[(g * 4 + r) * 132 + ni * 16 + r16] = yacc[q][r] + bv;
    }
    __syncthreads();

    // LN2 (+residual xr) -> x + xbf
    #pragma unroll
    for (int rr = 0; rr < 4; ++rr) {
        int row = wv * 4 + rr;
        size_t go = (size_t)(row0 + row) * 128;
        float v0 = u2.Cs[row * 132 + lane] + xr[row * 132 + lane];
        float v1 = u2.Cs[row * 132 + 64 + lane] + xr[row * 132 + 64 + lane];
        float sum = v0 + v1, sq = v0 * v0 + v1 * v1;
        #pragma unroll
        for (int o2 = 32; o2 >= 1; o2 >>= 1) {
            sum += __shfl_xor(sum, o2);
            sq  += __shfl_xor(sq, o2);
        }
        float mu = sum * (1.f / 128.f);
        float var = sq * (1.f / 128.f) - mu * mu;
        float rs = rsqrtf(var + 1e-5f);
        float o0 = (v0 - mu) * rs * g2[lane] + be2[lane];
        float o1 = (v1 - mu) * rs * g2[lane + 64] + be2[lane + 64];
        x[go + lane] = o0;
        x[go + 64 + lane] = o1;
        xbf[go + lane] = f2bf(o0);
        xbf[go + 64 + lane] = f2bf(o1);
    }
}

// ================= Classifier head ============================================
__global__ __launch_bounds__(64) void head_kernel(
    const float* __restrict__ x, const float* __restrict__ w1,
    const float* __restrict__ b1, const float* __restrict__ w2,
    const float* __restrict__ b2, float* __restrict__ out)
{
    int b = blockIdx.x;
    int j = threadIdx.x;
    const float* xr = x + ((size_t)b * AL_ + (AL_ - 1)) * DH_;
    float hj = b1[j];
    for (int d = 0; d < DH_; ++d) hj = fmaf(xr[d], w1[d * 64 + j], hj);
    hj = fmaxf(hj, 0.f);
    float acc = hj * w2[j];
    #pragma unroll
    for (int d = 32; d >= 1; d >>= 1) acc += __shfl_xor(acc, d);
    if (j == 0) out[b] = acc + b2[0];
}

// ================= Launch =====================================================
extern "C" void kernel_launch(void* const* d_in, const int* in_sizes, int n_in,
                              void* d_out, int out_size, void* d_ws, size_t ws_size,
                              hipStream_t stream) {
    (void)in_sizes; (void)n_in; (void)out_size; (void)ws_size;
    const float* cls_emb    = (const float*)d_in[0];
    const float* note_times = (const float*)d_in[1];
    const int*   note_counts= (const int*)d_in[2];
    const float* proj_w     = (const float*)d_in[3];
    const float* proj_b     = (const float*)d_in[4];
    const float* te_w       = (const float*)d_in[5];
    const float* te_b       = (const float*)d_in[6];
    const float* wq         = (const float*)d_in[7];
    const float* wk         = (const float*)d_in[8];
    const float* tf_wq      = (const float*)d_in[9];
    const float* tf_wk      = (const float*)d_in[10];
    const float* tf_wv      = (const float*)d_in[11];
    const float* tf_wo      = (const float*)d_in[12];
    const float* tf_ln1_g   = (const float*)d_in[13];
    const float* tf_ln1_b   = (const float*)d_in[14];
    const float* tf_w1      = (const float*)d_in[15];
    const float* tf_b1      = (const float*)d_in[16];
    const float* tf_w2      = (const float*)d_in[17];
    const float* tf_b2      = (const float*)d_in[18];
    const float* tf_ln2_g   = (const float*)d_in[19];
    const float* tf_ln2_b   = (const float*)d_in[20];
    const float* cls_w1     = (const float*)d_in[21];
    const float* cls_b1     = (const float*)d_in[22];
    const float* cls_w2     = (const float*)d_in[23];
    const float* cls_b2     = (const float*)d_in[24];
    float* out = (float*)d_out;
    float* ws = (float*)d_ws;

    // workspace layout (float units)
    unsigned short* note_emb16 = (unsigned short*)(ws + 0);       // 1,048,576 f
    float* x        = ws + 1048576;                                // 1,572,864 f
    unsigned short* obuf16 = (unsigned short*)(ws + 2621440);      // 786,432 f
    unsigned short* xbf    = (unsigned short*)(ws + 3407872);      // 786,432 f
    float* q_all    = ws + 4194304;                                // 3,072 f
    unsigned short* wt     = (unsigned short*)(ws + 4197376);      // 344,064 f

    // ---- weight prep table
    TTab tab;
    int tile = 0, idx = 0;
    auto add = [&](const float* src, int dstOff, int K, int N) {
        tab.e[idx].src = src; tab.e[idx].dstOff = dstOff;
        tab.e[idx].K = K; tab.e[idx].N = N; tab.e[idx].tile0 = tile;
        tile += (K / 64) * (N / 64); ++idx;
    };
    add(proj_w, 0, DT_, DH_);
    int layerBase[NL_];
    for (int i = 0; i < NL_; ++i) {
        int base = 98304 + i * 196608;
        layerBase[i] = base;
        add(tf_wq + (size_t)i * DH_ * DH_, base,           DH_, DH_);
        add(tf_wk + (size_t)i * DH_ * DH_, base + 16384,   DH_, DH_);
        add(tf_wv + (size_t)i * DH_ * DH_, base + 32768,   DH_, DH_);
        add(tf_wo + (size_t)i * DH_ * DH_, base + 49152,   DH_, DH_);
        add(tf_w1 + (size_t)i * DH_ * DFF_, base + 65536,  DH_, DFF_);
        add(tf_w2 + (size_t)i * DFF_ * DH_, base + 131072, DFF_, DH_);
    }
    prep_weights_kernel<<<tile, 256, 0, stream>>>(tab, wt);
    qk_prep_kernel<<<1, 256, 0, stream>>>(te_w, te_b, wq, q_all);

    const int Mx = B_ * AL_; // 12288

    gemm_proj_kernel<<<(B_ * L_) / 32, 256, 0, stream>>>(
        cls_emb, wt, proj_b, note_emb16, B_ * L_, DH_, DT_);

    first_attn_kernel<<<B_ * 2, 256, 0, stream>>>(
        note_times, note_counts, te_w, te_b, wk, q_all, note_emb16, x, xbf);

    for (int i = 0; i < NL_; ++i) {
        int base = layerBase[i];
        attn2_kernel<<<B_ * H_, 256, 0, stream>>>(xbf, wt + base, obuf16);
        layer_tail_kernel<<<Mx / 16, 256, 0, stream>>>(
            obuf16, wt + base,
            tf_b1 + i * DFF_, tf_b2 + i * DH_,
            tf_ln1_g + i * DH_, tf_ln1_b + i * DH_,
            tf_ln2_g + i * DH_, tf_ln2_b + i * DH_,
            x, xbf);
    }

    head_kernel<<<B_, 64, 0, stream>>>(x, cls_w1, cls_b1, cls_w2, cls_b2, out);
}

// Round 8
// 187.535 us; speedup vs baseline: 1.6149x; 1.0881x over previous
//
#include <hip/hip_runtime.h>
#include <hip/hip_bf16.h>

// Problem constants
#define B_   256
#define L_   64
#define DT_  768
#define DH_  128
#define AL_  48
#define DTE_ 64
#define H_   8
#define NL_  3
#define DFF_ 512

typedef __attribute__((ext_vector_type(4))) float f32x4;
typedef __attribute__((ext_vector_type(4))) unsigned int u32x4;
typedef __attribute__((ext_vector_type(2))) unsigned int u32x2;
typedef __attribute__((ext_vector_type(8))) short short8;

__device__ inline unsigned short f2bf(float f) {
    union { float f; unsigned u; } v; v.f = f;
    unsigned r = (v.u + 0x7FFFu + ((v.u >> 16) & 1u)) >> 16;
    return (unsigned short)r;
}
__device__ inline unsigned f2bf2(float a, float b) {
    return (unsigned)f2bf(a) | ((unsigned)f2bf(b) << 16);
}
__device__ inline float bf2f(unsigned short u) {
    union { unsigned u; float f; } v; v.u = ((unsigned)u) << 16; return v.f;
}
__device__ inline short8 ldg8(const unsigned short* p) {
    union { short8 s; u32x4 v; } r;
    r.v = *(const u32x4*)p;
    return r.s;
}
// packed f16 helpers
__device__ inline unsigned pk_f16(float a, float b) {
    unsigned r;
    asm("v_cvt_pkrtz_f16_f32 %0, %1, %2" : "=v"(r) : "v"(a), "v"(b));
    return r;
}
__device__ inline unsigned pk_max(unsigned a, unsigned b) {
    unsigned r;
    asm("v_pk_max_f16 %0, %1, %2" : "=v"(r) : "v"(a), "v"(b));
    return r;
}
__device__ inline float f16_lo(unsigned h) {
    float f; asm("v_cvt_f32_f16 %0, %1" : "=v"(f) : "v"(h)); return f;
}
__device__ inline float f16_hi(unsigned h) {
    float f; unsigned t = h >> 16;
    asm("v_cvt_f32_f16 %0, %1" : "=v"(f) : "v"(t)); return f;
}

// ====== Weight prep (fp32 [K][N] -> bf16 Wt [N][K]) + q_all prep (last block) =
struct TEnt { const float* src; int dstOff; int K; int N; int tile0; };
struct TTab { TEnt e[19]; };

__global__ __launch_bounds__(256) void prep_weights_kernel(
    TTab tab, int ntile, unsigned short* __restrict__ wt,
    const float* __restrict__ te_w, const float* __restrict__ te_b,
    const float* __restrict__ wq, float* __restrict__ q_allG)
{
    __shared__ unsigned short lds[64][72];
    __shared__ float qte[AL_ * 68];
    int tid = threadIdx.x;
    if ((int)blockIdx.x >= ntile) {
        // q_all = time_embed(arange(48)) @ wq
        for (int i = tid; i < AL_ * 64; i += 256) {
            int a = i >> 6, j = i & 63;
            float lin = fmaf((float)a, te_w[j], te_b[j]);
            qte[a * 68 + j] = (j == 0) ? lin : __sinf(lin);
        }
        __syncthreads();
        for (int i = tid; i < AL_ * 64; i += 256) {
            int a = i >> 6, d = i & 63;
            float s0 = 0.f, s1 = 0.f, s2 = 0.f, s3 = 0.f;
            for (int j = 0; j < 64; j += 4) {
                s0 = fmaf(qte[a * 68 + j],     wq[j * 64 + d],       s0);
                s1 = fmaf(qte[a * 68 + j + 1], wq[(j + 1) * 64 + d], s1);
                s2 = fmaf(qte[a * 68 + j + 2], wq[(j + 2) * 64 + d], s2);
                s3 = fmaf(qte[a * 68 + j + 3], wq[(j + 3) * 64 + d], s3);
            }
            q_allG[i] = (s0 + s1) + (s2 + s3);
        }
        return;
    }
    int ei = 0;
    #pragma unroll
    for (int j = 1; j < 19; ++j) if ((int)blockIdx.x >= tab.e[j].tile0) ei = j;
    TEnt e = tab.e[ei];
    int t = blockIdx.x - e.tile0;
    int tilesK = e.K >> 6;
    int tk = t % tilesK, tn = t / tilesK;
    #pragma unroll
    for (int p = 0; p < 16; ++p) {
        int kk = p * 4 + (tid >> 6);
        int n = tid & 63;
        float v = e.src[(size_t)(tk * 64 + kk) * e.N + tn * 64 + n];
        lds[n][kk] = f2bf(v);
    }
    __syncthreads();
    #pragma unroll
    for (int p = 0; p < 2; ++p) {
        int c = p * 256 + tid;
        int n = c >> 3, q = c & 7;
        u32x4 v = *(const u32x4*)(&lds[n][q * 8]);
        *(u32x4*)(&wt[(size_t)e.dstOff + (size_t)(tn * 64 + n) * e.K + tk * 64 + q * 8]) = v;
    }
}

// ================= bf16 MFMA GEMM (proj): C = A(fp32 MxK) @ Wt^T -> bf16 ======
__global__ __launch_bounds__(256) void gemm_proj_kernel(
    const float* __restrict__ A, const unsigned short* __restrict__ Wt,
    const float* __restrict__ bias, unsigned short* __restrict__ C,
    int M, int N, int K)
{
    __shared__ unsigned short As[32 * 64];
    __shared__ unsigned short Bs[128 * 64];
    int tid = threadIdx.x;
    int bm = blockIdx.x * 32;
    int wave = tid >> 6, lane = tid & 63;
    int wm = wave >> 1, wn = wave & 1;
    int g = lane >> 4, r16 = lane & 15;

    f32x4 acc[4] = {};

    for (int k0 = 0; k0 < K; k0 += 64) {
        #pragma unroll
        for (int p = 0; p < 2; ++p) {
            int row = p * 16 + (tid >> 4);
            int c4 = tid & 15;
            f32x4 v = *(const f32x4*)(&A[(size_t)(bm + row) * K + k0 + c4 * 4]);
            u32x2 w;
            w[0] = f2bf2(v[0], v[1]);
            w[1] = f2bf2(v[2], v[3]);
            *(u32x2*)(&As[row * 64 + ((c4 * 4) ^ ((row & 7) << 3))]) = w;
        }
        #pragma unroll
        for (int p = 0; p < 4; ++p) {
            int c = p * 256 + tid;
            int n = c >> 3, q = c & 7;
            u32x4 v = *(const u32x4*)(&Wt[(size_t)n * K + k0 + q * 8]);
            *(u32x4*)(&Bs[n * 64 + ((q * 8) ^ ((n & 7) << 3))]) = v;
        }
        __syncthreads();
        #pragma unroll
        for (int kk = 0; kk < 2; ++kk) {
            short8 af, bf[4];
            int co = kk * 32 + g * 8;
            {
                int row = wm * 16 + r16;
                af = *(const short8*)(&As[row * 64 + (co ^ ((row & 7) << 3))]);
            }
            #pragma unroll
            for (int ni = 0; ni < 4; ++ni) {
                int row = wn * 64 + ni * 16 + r16;
                bf[ni] = *(const short8*)(&Bs[row * 64 + (co ^ ((row & 7) << 3))]);
            }
            #pragma unroll
            for (int ni = 0; ni < 4; ++ni)
                acc[ni] = __builtin_amdgcn_mfma_f32_16x16x32_bf16(af, bf[ni], acc[ni], 0, 0, 0);
        }
        __syncthreads();
    }
    #pragma unroll
    for (int ni = 0; ni < 4; ++ni) {
        int col = wn * 64 + ni * 16 + r16;
        float bv = bias[col];
        #pragma unroll
        for (int r = 0; r < 4; ++r) {
            int row = bm + wm * 16 + g * 4 + r;
            C[(size_t)row * N + col] = f2bf(acc[ni][r] + bv);
        }
    }
}

// ================= First attention: block = (b, half of 48 alpha rows) ========
__global__ __launch_bounds__(256) void first_attn_kernel(
    const float* __restrict__ note_times, const int* __restrict__ note_counts,
    const float* __restrict__ te_w, const float* __restrict__ te_b,
    const float* __restrict__ wk, const float* __restrict__ q_all,
    const unsigned short* __restrict__ note_emb,
    float* __restrict__ x_out, unsigned short* __restrict__ xbf_out)
{
    __shared__ union RU {
        float kkL[64 * 68];
        unsigned short E[32 * 256];
        struct { unsigned short As[32 * 64]; unsigned short Bs[128 * 64]; } mm;
    } ru;
    __shared__ float rsL[32][8];

    const int bx = blockIdx.x;
    const int b = bx >> 1, a0 = (bx & 1) * 24;
    const int tid = threadIdx.x, lane = tid & 63;
    const int wv = __builtin_amdgcn_readfirstlane(tid >> 6);
    const int g = lane >> 4, r16 = lane & 15;
    const int nc = note_counts[b];

    float kte[64];
    {
        float t = note_times[b * 64 + lane];
        #pragma unroll
        for (int j = 0; j < 64; ++j) {
            float lin = fmaf(t, te_w[j], te_b[j]);
            kte[j] = (j == 0) ? lin : __sinf(lin);
        }
    }
    {
        float kvp[16] = {};
        #pragma unroll
        for (int j = 0; j < 64; ++j) {
            #pragma unroll
            for (int dd = 0; dd < 16; ++dd)
                kvp[dd] = fmaf(kte[j], wk[j * 64 + wv * 16 + dd], kvp[dd]);
        }
        #pragma unroll
        for (int q4 = 0; q4 < 4; ++q4)
            *(f32x4*)(&ru.kkL[lane * 68 + wv * 16 + q4 * 4]) = *(const f32x4*)(&kvp[q4 * 4]);
    }
    __syncthreads();
    float kv[64];
    #pragma unroll
    for (int q4 = 0; q4 < 16; ++q4)
        *(f32x4*)(&kv[q4 * 4]) = *(const f32x4*)(&ru.kkL[lane * 68 + q4 * 4]);
    __syncthreads();

    float abar[6] = {};
    const float scale = 0.35355339059327373f; // 1/sqrt(8)
    #pragma unroll
    for (int p = 0; p < 2; ++p) {
        float e_reg[6][4];
        #pragma unroll
        for (int i = 0; i < 6; ++i) {
            int a = wv * 6 + i;
            float s[4];
            #pragma unroll
            for (int h = 0; h < 4; ++h) {
                float acc = 0.f;
                #pragma unroll
                for (int d = 0; d < 8; ++d)
                    acc = fmaf(q_all[(a0 + a) * 64 + p * 32 + h * 8 + d],
                               kv[p * 32 + h * 8 + d], acc);
                s[h] = (lane < nc) ? acc * scale : -1e9f;
            }
            unsigned m0 = pk_f16(s[0], s[1]);
            unsigned m1 = pk_f16(s[2], s[3]);
            #pragma unroll
            for (int st = 32; st >= 1; st >>= 1) {
                m0 = pk_max(m0, (unsigned)__shfl_xor((int)m0, st));
                m1 = pk_max(m1, (unsigned)__shfl_xor((int)m1, st));
            }
            float mm[4] = { f16_lo(m0), f16_hi(m0), f16_lo(m1), f16_hi(m1) };
            #pragma unroll
            for (int h = 0; h < 4; ++h) {
                float e = __expf(s[h] - mm[h]);
                e_reg[i][h] = e;
                int k = h * 64 + lane;
                ru.E[a * 256 + (k ^ ((a & 7) << 3))] = f2bf(e);
            }
        }
        __syncthreads();
        if (wv < 2) {
            f32x4 acc = {0.f, 0.f, 0.f, 0.f};
            #pragma unroll
            for (int ks = 0; ks < 8; ++ks) {
                int row = wv * 16 + r16;
                short8 af = *(const short8*)(&ru.E[row * 256 + ((ks * 32 + g * 8) ^ ((row & 7) << 3))]);
                short bb = (r16 == (ks >> 1)) ? (short)0x3F80 : (short)0;
                short8 bf = { bb, bb, bb, bb, bb, bb, bb, bb };
                acc = __builtin_amdgcn_mfma_f32_16x16x32_bf16(af, bf, acc, 0, 0, 0);
            }
            if (r16 < 4) {
                #pragma unroll
                for (int r = 0; r < 4; ++r)
                    rsL[wv * 16 + g * 4 + r][p * 4 + r16] = 0.125f / fmaxf(acc[r], 1e-20f);
            }
        }
        __syncthreads();
        #pragma unroll
        for (int i = 0; i < 6; ++i) {
            int a = wv * 6 + i;
            f32x4 rv = *(const f32x4*)(&rsL[a][p * 4]);
            abar[i] = fmaf(e_reg[i][0], rv[0], abar[i]);
            abar[i] = fmaf(e_reg[i][1], rv[1], abar[i]);
            abar[i] = fmaf(e_reg[i][2], rv[2], abar[i]);
            abar[i] = fmaf(e_reg[i][3], rv[3], abar[i]);
        }
    }
    {
        int l = tid & 63;
        #pragma unroll
        for (int pp = 0; pp < 4; ++pp) {
            int c = pp * 4 + (tid >> 6);
            u32x4 v = *(const u32x4*)(&note_emb[((size_t)b * 64 + l) * 128 + c * 8]);
            #pragma unroll
            for (int j = 0; j < 8; ++j) {
                unsigned short h16 = (unsigned short)((j & 1) ? (v[j >> 1] >> 16) : (v[j >> 1] & 0xffff));
                int f = c * 8 + j;
                ru.mm.Bs[f * 64 + (l ^ ((f & 7) << 3))] = h16;
            }
        }
    }
    #pragma unroll
    for (int i = 0; i < 6; ++i) {
        int a = wv * 6 + i;
        ru.mm.As[a * 64 + (lane ^ ((a & 7) << 3))] = f2bf(abar[i]);
    }
    __syncthreads();

    f32x4 pv[4] = {};
    #pragma unroll
    for (int q = 0; q < 4; ++q) {
        int f = wv * 4 + q, mi = f >> 3, ni = f & 7;
        #pragma unroll
        for (int ks = 0; ks < 2; ++ks) {
            int co = ks * 32 + g * 8;
            int raw = mi * 16 + r16, rb = ni * 16 + r16;
            short8 af = *(const short8*)(&ru.mm.As[raw * 64 + (co ^ ((raw & 7) << 3))]);
            short8 bf = *(const short8*)(&ru.mm.Bs[rb * 64 + (co ^ ((rb & 7) << 3))]);
            pv[q] = __builtin_amdgcn_mfma_f32_16x16x32_bf16(af, bf, pv[q], 0, 0, 0);
        }
    }
    #pragma unroll
    for (int q = 0; q < 4; ++q) {
        int f = wv * 4 + q, mi = f >> 3, ni = f & 7;
        #pragma unroll
        for (int r = 0; r < 4; ++r) {
            int row = mi * 16 + g * 4 + r;
            if (row < 24) {
                float v = (nc > 0) ? pv[q][r] : 0.f;
                size_t o = ((size_t)b * AL_ + a0 + row) * 128 + ni * 16 + r16;
                x_out[o] = v;
                xbf_out[o] = f2bf(v);
            }
        }
    }
}

// ====== Transformer self-attn per (b,h): 192 threads, distributed softmax =====
__global__ __launch_bounds__(192) void attn2_kernel(
    const unsigned short* __restrict__ xbf, const unsigned short* __restrict__ WtL,
    unsigned short* __restrict__ o)
{
    __shared__ unsigned short Xs[AL_ * 128];    // swizzled
    __shared__ unsigned short qM[AL_ * 40];     // [a][k]: 0..15 data, 16..31 zero
    __shared__ unsigned short kM[AL_ * 40];
    __shared__ unsigned short vT[16 * 72];      // [d][k=a']: 48..63 zero
    __shared__ float sL[AL_ * 52];
    __shared__ unsigned short P[AL_ * 64];      // swizzled bf16 probs
    int bid = blockIdx.x;
    int b = bid >> 3, h = bid & 7;
    int tid = threadIdx.x, lane = tid & 63;
    int wv = __builtin_amdgcn_readfirstlane(tid >> 6);
    int g = lane >> 4, r16 = lane & 15;

    #pragma unroll
    for (int p = 0; p < 4; ++p) {
        int i = p * 192 + tid;
        int a = i >> 4, c = (i & 15) * 8;
        u32x4 v = *(const u32x4*)(&xbf[((size_t)b * AL_ + a) * 128 + c]);
        *(u32x4*)(&Xs[a * 128 + (c & 64) + ((c & 63) ^ ((a & 7) << 3))]) = v;
    }
    // zero pads: qM/kM cols 16..31, vT cols 48..63, P cols 48..63
    for (int i = tid; i < 768; i += 192) {
        int a = i >> 4, k2 = 16 + (i & 15);
        qM[a * 40 + k2] = 0;
        kM[a * 40 + k2] = 0;
    }
    for (int i = tid; i < 256; i += 192) {
        int d = i >> 4, k2 = 48 + (i & 15);
        vT[d * 72 + k2] = 0;
    }
    for (int i = tid; i < 768; i += 192) {
        int a = i >> 4, c = 48 + (i & 15);
        P[a * 64 + (c ^ ((a & 7) << 3))] = 0;
    }
    __syncthreads();

    // qkv: 3 waves, one matrix each (M=48, N=16, K=128)
    {
        f32x4 acc[3] = {};
        const unsigned short* Wm = WtL + wv * 16384 + (size_t)(h * 16) * 128;
        #pragma unroll
        for (int kq = 0; kq < 4; ++kq) {
            short8 bf = ldg8(&Wm[(size_t)r16 * 128 + kq * 32 + g * 8]);
            #pragma unroll
            for (int mi = 0; mi < 3; ++mi) {
                int row = mi * 16 + r16;
                int c = kq * 32 + g * 8;
                short8 af = *(const short8*)(&Xs[row * 128 + (c & 64) + ((c & 63) ^ ((row & 7) << 3))]);
                acc[mi] = __builtin_amdgcn_mfma_f32_16x16x32_bf16(af, bf, acc[mi], 0, 0, 0);
            }
        }
        #pragma unroll
        for (int mi = 0; mi < 3; ++mi) {
            #pragma unroll
            for (int r = 0; r < 4; ++r) {
                int a = mi * 16 + g * 4 + r;
                unsigned short hv = f2bf(acc[mi][r]);
                if (wv == 0) qM[a * 40 + r16] = hv;
                else if (wv == 1) kM[a * 40 + r16] = hv;
                else vT[r16 * 72 + a] = hv;
            }
        }
    }
    __syncthreads();

    // scores: 9 frags (3m x 3n); this wave does m = wv
    {
        #pragma unroll
        for (int ni = 0; ni < 3; ++ni) {
            f32x4 acc = {0.f, 0.f, 0.f, 0.f};
            short8 af = *(const short8*)(&qM[(wv * 16 + r16) * 40 + g * 8]);
            short8 bf = *(const short8*)(&kM[(ni * 16 + r16) * 40 + g * 8]);
            acc = __builtin_amdgcn_mfma_f32_16x16x32_bf16(af, bf, acc, 0, 0, 0);
            #pragma unroll
            for (int r = 0; r < 4; ++r)
                sL[(wv * 16 + g * 4 + r) * 52 + ni * 16 + r16] = acc[r] * 0.25f;
        }
    }
    __syncthreads();

    // distributed softmax: 4-lane group per row (48 rows over 3 waves)
    {
        int row = wv * 16 + (lane >> 2), sub = lane & 3;
        f32x4 v0 = *(const f32x4*)(&sL[row * 52 + sub * 4]);
        f32x4 v1 = *(const f32x4*)(&sL[row * 52 + 16 + sub * 4]);
        f32x4 v2 = *(const f32x4*)(&sL[row * 52 + 32 + sub * 4]);
        float m = fmaxf(fmaxf(fmaxf(v0[0], v0[1]), fmaxf(v0[2], v0[3])),
                        fmaxf(fmaxf(v1[0], v1[1]), fmaxf(v1[2], v1[3])));
        m = fmaxf(m, fmaxf(fmaxf(v2[0], v2[1]), fmaxf(v2[2], v2[3])));
        m = fmaxf(m, __shfl_xor(m, 1));
        m = fmaxf(m, __shfl_xor(m, 2));
        float e[12];
        #pragma unroll
        for (int j = 0; j < 4; ++j) {
            e[j]     = __expf(v0[j] - m);
            e[4 + j] = __expf(v1[j] - m);
            e[8 + j] = __expf(v2[j] - m);
        }
        float sum = 0.f;
        #pragma unroll
        for (int j = 0; j < 12; ++j) sum += e[j];
        sum += __shfl_xor(sum, 1);
        sum += __shfl_xor(sum, 2);
        float inv = __fdividef(1.f, sum);
        #pragma unroll
        for (int c = 0; c < 3; ++c) {
            u32x2 w;
            w[0] = f2bf2(e[c * 4 + 0] * inv, e[c * 4 + 1] * inv);
            w[1] = f2bf2(e[c * 4 + 2] * inv, e[c * 4 + 3] * inv);
            int col = c * 16 + sub * 4;
            *(u32x2*)(&P[row * 64 + (col ^ ((row & 7) << 3))]) = w;
        }
    }
    __syncthreads();

    // PV: out[a][d] = sum_a' P[a][a'] v[a'][d]; m-frag = wv, K=64 (padded)
    {
        f32x4 acc = {0.f, 0.f, 0.f, 0.f};
        #pragma unroll
        for (int ks = 0; ks < 2; ++ks) {
            int co = ks * 32 + g * 8;
            int rp = wv * 16 + r16;
            short8 af = *(const short8*)(&P[rp * 64 + (co ^ ((rp & 7) << 3))]);
            short8 bf = *(const short8*)(&vT[r16 * 72 + co]);
            acc = __builtin_amdgcn_mfma_f32_16x16x32_bf16(af, bf, acc, 0, 0, 0);
        }
        #pragma unroll
        for (int r = 0; r < 4; ++r) {
            int a = wv * 16 + g * 4 + r;
            o[((size_t)b * AL_ + a) * 128 + h * 16 + r16] = f2bf(acc[r]);
        }
    }
}

// ====== Layer tail (16 rows/block): wo-GEMM + LN1 + FFN + LN2 (+head if last) =
__global__ __launch_bounds__(256) void layer_tail_kernel(
    const unsigned short* __restrict__ obuf, const unsigned short* __restrict__ Wl,
    const float* __restrict__ b1, const float* __restrict__ b2,
    const float* __restrict__ g1, const float* __restrict__ be1,
    const float* __restrict__ g2, const float* __restrict__ be2,
    float* __restrict__ x, unsigned short* __restrict__ xbf,
    int last, const float* __restrict__ cw1, const float* __restrict__ cb1,
    const float* __restrict__ cw2, const float* __restrict__ cb2,
    float* __restrict__ outp)
{
    __shared__ unsigned short OX[16 * 128];
    __shared__ union { unsigned short hid[16 * 512]; float Cs[16 * 132]; } u2;
    __shared__ float xr[16 * 132];
    const int tid = threadIdx.x, lane = tid & 63;
    const int wv = __builtin_amdgcn_readfirstlane(tid >> 6);
    const int g = lane >> 4, r16 = lane & 15;
    const int row0 = last ? ((int)blockIdx.x * 48 + 32) : ((int)blockIdx.x * 16);

    {
        int a = tid >> 4, c = (tid & 15) * 8;
        u32x4 v = *(const u32x4*)(&obuf[(size_t)(row0 + a) * 128 + c]);
        *(u32x4*)(&OX[a * 128 + (c & 64) + ((c & 63) ^ ((a & 7) << 3))]) = v;
    }
    __syncthreads();

    // wo GEMM: 8 frags (1m x 8n), wave does ni = wv*2 + {0,1}
    {
        f32x4 wacc[2] = {};
        #pragma unroll
        for (int q = 0; q < 2; ++q) {
            int ni = wv * 2 + q;
            const unsigned short* Wm = Wl + 49152 + (size_t)(ni * 16 + r16) * 128;
            #pragma unroll
            for (int kq = 0; kq < 4; ++kq) {
                int co = kq * 32 + g * 8;
                short8 af = *(const short8*)(&OX[r16 * 128 + (co & 64) + ((co & 63) ^ ((r16 & 7) << 3))]);
                short8 bf = ldg8(Wm + co);
                wacc[q] = __builtin_amdgcn_mfma_f32_16x16x32_bf16(af, bf, wacc[q], 0, 0, 0);
            }
        }
        #pragma unroll
        for (int q = 0; q < 2; ++q) {
            int ni = wv * 2 + q;
            #pragma unroll
            for (int r = 0; r < 4; ++r)
                u2.Cs[(g * 4 + r) * 132 + ni * 16 + r16] = wacc[q][r];
        }
    }
    __syncthreads();

    // LN1 (+residual)
    #pragma unroll
    for (int rr = 0; rr < 4; ++rr) {
        int row = wv * 4 + rr;
        size_t go = (size_t)(row0 + row) * 128;
        float v0 = u2.Cs[row * 132 + lane] + x[go + lane];
        float v1 = u2.Cs[row * 132 + 64 + lane] + x[go + 64 + lane];
        float sum = v0 + v1, sq = v0 * v0 + v1 * v1;
        #pragma unroll
        for (int o2 = 32; o2 >= 1; o2 >>= 1) {
            sum += __shfl_xor(sum, o2);
            sq  += __shfl_xor(sq, o2);
        }
        float mu = sum * (1.f / 128.f);
        float var = sq * (1.f / 128.f) - mu * mu;
        float rs = rsqrtf(var + 1e-5f);
        float o0 = (v0 - mu) * rs * g1[lane] + be1[lane];
        float o1 = (v1 - mu) * rs * g1[lane + 64] + be1[lane + 64];
        xr[row * 132 + lane] = o0;
        xr[row * 132 + 64 + lane] = o1;
        OX[row * 128 + (lane ^ ((row & 7) << 3))] = f2bf(o0);
        OX[row * 128 + 64 + (lane ^ ((row & 7) << 3))] = f2bf(o1);
    }
    __syncthreads();

    // hidden = relu(Xs @ w1 + b1): wave owns cols [wv*128, +128)
    {
        f32x4 hacc[8] = {};
        #pragma unroll
        for (int nf = 0; nf < 8; ++nf) {
            int col = wv * 128 + nf * 16 + r16;
            const unsigned short* Wm = Wl + 65536 + (size_t)col * 128;
            #pragma unroll
            for (int kq = 0; kq < 4; ++kq) {
                int co = kq * 32 + g * 8;
                short8 bf = ldg8(Wm + co);
                short8 af = *(const short8*)(&OX[r16 * 128 + (co & 64) + ((co & 63) ^ ((r16 & 7) << 3))]);
                hacc[nf] = __builtin_amdgcn_mfma_f32_16x16x32_bf16(af, bf, hacc[nf], 0, 0, 0);
            }
        }
        #pragma unroll
        for (int nf = 0; nf < 8; ++nf) {
            int col = wv * 128 + nf * 16 + r16;
            float bv = b1[col];
            #pragma unroll
            for (int r = 0; r < 4; ++r) {
                int rowa = g * 4 + r;
                u2.hid[rowa * 512 + (col & 448) + ((col & 63) ^ ((rowa & 7) << 3))] =
                    f2bf(fmaxf(hacc[nf][r] + bv, 0.f));
            }
        }
    }
    __syncthreads();

    // y = hid @ w2 (K=512)
    f32x4 yacc[2] = {};
    #pragma unroll
    for (int q = 0; q < 2; ++q) {
        int ni = wv * 2 + q;
        const unsigned short* Wm = Wl + 131072 + (size_t)(ni * 16 + r16) * 512;
        #pragma unroll
        for (int kq = 0; kq < 16; ++kq) {
            int co = kq * 32 + g * 8;
            short8 af = *(const short8*)(&u2.hid[r16 * 512 + (co & 448) + ((co & 63) ^ ((r16 & 7) << 3))]);
            short8 bf = ldg8(Wm + co);
            yacc[q] = __builtin_amdgcn_mfma_f32_16x16x32_bf16(af, bf, yacc[q], 0, 0, 0);
        }
    }
    __syncthreads();
    #pragma unroll
    for (int q = 0; q < 2; ++q) {
        int ni = wv * 2 + q;
        float bv = b2[ni * 16 + r16];
        #pragma unroll
        for (int r = 0; r < 4; ++r)
            u2.Cs[(g * 4 + r) * 132 + ni * 16 + r16] = yacc[q][r] + bv;
    }
    __syncthreads();

    // LN2 (+residual xr); write LN2 output back into xr (for head)
    #pragma unroll
    for (int rr = 0; rr < 4; ++rr) {
        int row = wv * 4 + rr;
        size_t go = (size_t)(row0 + row) * 128;
        float v0 = u2.Cs[row * 132 + lane] + xr[row * 132 + lane];
        float v1 = u2.Cs[row * 132 + 64 + lane] + xr[row * 132 + 64 + lane];
        float sum = v0 + v1, sq = v0 * v0 + v1 * v1;
        #pragma unroll
        for (int o2 = 32; o2 >= 1; o2 >>= 1) {
            sum += __shfl_xor(sum, o2);
            sq  += __shfl_xor(sq, o2);
        }
        float mu = sum * (1.f / 128.f);
        float var = sq * (1.f / 128.f) - mu * mu;
        float rs = rsqrtf(var + 1e-5f);
        float o0 = (v0 - mu) * rs * g2[lane] + be2[lane];
        float o1 = (v1 - mu) * rs * g2[lane + 64] + be2[lane + 64];
        if (!last) {
            x[go + lane] = o0;
            x[go + 64 + lane] = o1;
            xbf[go + lane] = f2bf(o0);
            xbf[go + 64 + lane] = f2bf(o1);
        } else {
            xr[row * 132 + lane] = o0;
            xr[row * 132 + 64 + lane] = o1;
        }
    }
    if (last) {
        __syncthreads();
        if (wv == 0) {
            // classifier head for batch b = blockIdx.x, from xr row 15 (= row 47)
            float hj = cb1[lane];
            #pragma unroll 8
            for (int d = 0; d < 128; ++d)
                hj = fmaf(xr[15 * 132 + d], cw1[d * 64 + lane], hj);
            hj = fmaxf(hj, 0.f);
            float acc = hj * cw2[lane];
            #pragma unroll
            for (int o2 = 32; o2 >= 1; o2 >>= 1) acc += __shfl_xor(acc, o2);
            if (lane == 0) outp[blockIdx.x] = acc + cb2[0];
        }
    }
}

// ================= Launch =====================================================
extern "C" void kernel_launch(void* const* d_in, const int* in_sizes, int n_in,
                              void* d_out, int out_size, void* d_ws, size_t ws_size,
                              hipStream_t stream) {
    (void)in_sizes; (void)n_in; (void)out_size; (void)ws_size;
    const float* cls_emb    = (const float*)d_in[0];
    const float* note_times = (const float*)d_in[1];
    const int*   note_counts= (const int*)d_in[2];
    const float* proj_w     = (const float*)d_in[3];
    const float* proj_b     = (const float*)d_in[4];
    const float* te_w       = (const float*)d_in[5];
    const float* te_b       = (const float*)d_in[6];
    const float* wq         = (const float*)d_in[7];
    const float* wk         = (const float*)d_in[8];
    const float* tf_wq      = (const float*)d_in[9];
    const float* tf_wk      = (const float*)d_in[10];
    const float* tf_wv      = (const float*)d_in[11];
    const float* tf_wo      = (const float*)d_in[12];
    const float* tf_ln1_g   = (const float*)d_in[13];
    const float* tf_ln1_b   = (const float*)d_in[14];
    const float* tf_w1      = (const float*)d_in[15];
    const float* tf_b1      = (const float*)d_in[16];
    const float* tf_w2      = (const float*)d_in[17];
    const float* tf_b2      = (const float*)d_in[18];
    const float* tf_ln2_g   = (const float*)d_in[19];
    const float* tf_ln2_b   = (const float*)d_in[20];
    const float* cls_w1     = (const float*)d_in[21];
    const float* cls_b1     = (const float*)d_in[22];
    const float* cls_w2     = (const float*)d_in[23];
    const float* cls_b2     = (const float*)d_in[24];
    float* out = (float*)d_out;
    float* ws = (float*)d_ws;

    // workspace layout (float units)
    unsigned short* note_emb16 = (unsigned short*)(ws + 0);       // 1,048,576 f
    float* x        = ws + 1048576;                                // 1,572,864 f
    unsigned short* obuf16 = (unsigned short*)(ws + 2621440);      // 786,432 f
    unsigned short* xbf    = (unsigned short*)(ws + 3407872);      // 786,432 f
    float* q_all    = ws + 4194304;                                // 3,072 f
    unsigned short* wt     = (unsigned short*)(ws + 4197376);      // 344,064 f

    TTab tab;
    int tile = 0, idx = 0;
    auto add = [&](const float* src, int dstOff, int K, int N) {
        tab.e[idx].src = src; tab.e[idx].dstOff = dstOff;
        tab.e[idx].K = K; tab.e[idx].N = N; tab.e[idx].tile0 = tile;
        tile += (K / 64) * (N / 64); ++idx;
    };
    add(proj_w, 0, DT_, DH_);
    int layerBase[NL_];
    for (int i = 0; i < NL_; ++i) {
        int base = 98304 + i * 196608;
        layerBase[i] = base;
        add(tf_wq + (size_t)i * DH_ * DH_, base,           DH_, DH_);
        add(tf_wk + (size_t)i * DH_ * DH_, base + 16384,   DH_, DH_);
        add(tf_wv + (size_t)i * DH_ * DH_, base + 32768,   DH_, DH_);
        add(tf_wo + (size_t)i * DH_ * DH_, base + 49152,   DH_, DH_);
        add(tf_w1 + (size_t)i * DH_ * DFF_, base + 65536,  DH_, DFF_);
        add(tf_w2 + (size_t)i * DFF_ * DH_, base + 131072, DFF_, DH_);
    }
    prep_weights_kernel<<<tile + 1, 256, 0, stream>>>(tab, tile, wt, te_w, te_b, wq, q_all);

    const int Mx = B_ * AL_; // 12288

    gemm_proj_kernel<<<(B_ * L_) / 32, 256, 0, stream>>>(
        cls_emb, wt, proj_b, note_emb16, B_ * L_, DH_, DT_);

    first_attn_kernel<<<B_ * 2, 256, 0, stream>>>(
        note_times, note_counts, te_w, te_b, wk, q_all, note_emb16, x, xbf);

    for (int i = 0; i < NL_; ++i) {
        int base = layerBase[i];
        int last = (i == NL_ - 1);
        attn2_kernel<<<B_ * H_, 192, 0, stream>>>(xbf, wt + base, obuf16);
        layer_tail_kernel<<<last ? B_ : (Mx / 16), 256, 0, stream>>>(
            obuf16, wt + base,
            tf_b1 + i * DFF_, tf_b2 + i * DH_,
            tf_ln1_g + i * DH_, tf_ln1_b + i * DH_,
            tf_ln2_g + i * DH_, tf_ln2_b + i * DH_,
            x, xbf,
            last, cls_w1, cls_b1, cls_w2, cls_b2, out);
    }
}

// Round 9
// 173.959 us; speedup vs baseline: 1.7410x; 1.0780x over previous
//
#include <hip/hip_runtime.h>
#include <hip/hip_bf16.h>

// Problem constants
#define B_   256
#define L_   64
#define DT_  768
#define DH_  128
#define AL_  48
#define DTE_ 64
#define H_   8
#define NL_  3
#define DFF_ 512

typedef __attribute__((ext_vector_type(4))) float f32x4;
typedef __attribute__((ext_vector_type(4))) unsigned int u32x4;
typedef __attribute__((ext_vector_type(2))) unsigned int u32x2;
typedef __attribute__((ext_vector_type(8))) short short8;

__device__ inline unsigned short f2bf(float f) {
    union { float f; unsigned u; } v; v.f = f;
    unsigned r = (v.u + 0x7FFFu + ((v.u >> 16) & 1u)) >> 16;
    return (unsigned short)r;
}
__device__ inline unsigned f2bf2(float a, float b) {
    return (unsigned)f2bf(a) | ((unsigned)f2bf(b) << 16);
}
__device__ inline float bf2f(unsigned short u) {
    union { unsigned u; float f; } v; v.u = ((unsigned)u) << 16; return v.f;
}
__device__ inline short8 ldg8(const unsigned short* p) {
    union { short8 s; u32x4 v; } r;
    r.v = *(const u32x4*)p;
    return r.s;
}
// packed f16 helpers
__device__ inline unsigned pk_f16(float a, float b) {
    unsigned r;
    asm("v_cvt_pkrtz_f16_f32 %0, %1, %2" : "=v"(r) : "v"(a), "v"(b));
    return r;
}
__device__ inline unsigned pk_max(unsigned a, unsigned b) {
    unsigned r;
    asm("v_pk_max_f16 %0, %1, %2" : "=v"(r) : "v"(a), "v"(b));
    return r;
}
__device__ inline float f16_lo(unsigned h) {
    float f; asm("v_cvt_f32_f16 %0, %1" : "=v"(f) : "v"(h)); return f;
}
__device__ inline float f16_hi(unsigned h) {
    float f; unsigned t = h >> 16;
    asm("v_cvt_f32_f16 %0, %1" : "=v"(f) : "v"(t)); return f;
}

// ====== Weight prep (fp32 [K][N] -> bf16 Wt [N][K]) + q_all prep (last block) =
struct TEnt { const float* src; int dstOff; int K; int N; int tile0; };
struct TTab { TEnt e[19]; };

__global__ __launch_bounds__(256) void prep_weights_kernel(
    TTab tab, int ntile, unsigned short* __restrict__ wt,
    const float* __restrict__ te_w, const float* __restrict__ te_b,
    const float* __restrict__ wq, float* __restrict__ q_allG)
{
    __shared__ unsigned short lds[64][72];
    __shared__ float qte[AL_ * 68];
    int tid = threadIdx.x;
    if ((int)blockIdx.x >= ntile) {
        for (int i = tid; i < AL_ * 64; i += 256) {
            int a = i >> 6, j = i & 63;
            float lin = fmaf((float)a, te_w[j], te_b[j]);
            qte[a * 68 + j] = (j == 0) ? lin : __sinf(lin);
        }
        __syncthreads();
        for (int i = tid; i < AL_ * 64; i += 256) {
            int a = i >> 6, d = i & 63;
            float s0 = 0.f, s1 = 0.f, s2 = 0.f, s3 = 0.f;
            for (int j = 0; j < 64; j += 4) {
                s0 = fmaf(qte[a * 68 + j],     wq[j * 64 + d],       s0);
                s1 = fmaf(qte[a * 68 + j + 1], wq[(j + 1) * 64 + d], s1);
                s2 = fmaf(qte[a * 68 + j + 2], wq[(j + 2) * 64 + d], s2);
                s3 = fmaf(qte[a * 68 + j + 3], wq[(j + 3) * 64 + d], s3);
            }
            q_allG[i] = (s0 + s1) + (s2 + s3);
        }
        return;
    }
    int ei = 0;
    #pragma unroll
    for (int j = 1; j < 19; ++j) if ((int)blockIdx.x >= tab.e[j].tile0) ei = j;
    TEnt e = tab.e[ei];
    int t = blockIdx.x - e.tile0;
    int tilesK = e.K >> 6;
    int tk = t % tilesK, tn = t / tilesK;
    #pragma unroll
    for (int p = 0; p < 16; ++p) {
        int kk = p * 4 + (tid >> 6);
        int n = tid & 63;
        float v = e.src[(size_t)(tk * 64 + kk) * e.N + tn * 64 + n];
        lds[n][kk] = f2bf(v);
    }
    __syncthreads();
    #pragma unroll
    for (int p = 0; p < 2; ++p) {
        int c = p * 256 + tid;
        int n = c >> 3, q = c & 7;
        u32x4 v = *(const u32x4*)(&lds[n][q * 8]);
        *(u32x4*)(&wt[(size_t)e.dstOff + (size_t)(tn * 64 + n) * e.K + tk * 64 + q * 8]) = v;
    }
}

// ================= bf16 MFMA GEMM (proj): C = A(fp32 MxK) @ Wt^T -> bf16 ======
__global__ __launch_bounds__(256) void gemm_proj_kernel(
    const float* __restrict__ A, const unsigned short* __restrict__ Wt,
    const float* __restrict__ bias, unsigned short* __restrict__ C,
    int M, int N, int K)
{
    __shared__ unsigned short As[32 * 64];
    __shared__ unsigned short Bs[128 * 64];
    int tid = threadIdx.x;
    int bm = blockIdx.x * 32;
    int wave = tid >> 6, lane = tid & 63;
    int wm = wave >> 1, wn = wave & 1;
    int g = lane >> 4, r16 = lane & 15;

    f32x4 acc[4] = {};

    for (int k0 = 0; k0 < K; k0 += 64) {
        #pragma unroll
        for (int p = 0; p < 2; ++p) {
            int row = p * 16 + (tid >> 4);
            int c4 = tid & 15;
            f32x4 v = *(const f32x4*)(&A[(size_t)(bm + row) * K + k0 + c4 * 4]);
            u32x2 w;
            w[0] = f2bf2(v[0], v[1]);
            w[1] = f2bf2(v[2], v[3]);
            *(u32x2*)(&As[row * 64 + ((c4 * 4) ^ ((row & 7) << 3))]) = w;
        }
        #pragma unroll
        for (int p = 0; p < 4; ++p) {
            int c = p * 256 + tid;
            int n = c >> 3, q = c & 7;
            u32x4 v = *(const u32x4*)(&Wt[(size_t)n * K + k0 + q * 8]);
            *(u32x4*)(&Bs[n * 64 + ((q * 8) ^ ((n & 7) << 3))]) = v;
        }
        __syncthreads();
        #pragma unroll
        for (int kk = 0; kk < 2; ++kk) {
            short8 af, bf[4];
            int co = kk * 32 + g * 8;
            {
                int row = wm * 16 + r16;
                af = *(const short8*)(&As[row * 64 + (co ^ ((row & 7) << 3))]);
            }
            #pragma unroll
            for (int ni = 0; ni < 4; ++ni) {
                int row = wn * 64 + ni * 16 + r16;
                bf[ni] = *(const short8*)(&Bs[row * 64 + (co ^ ((row & 7) << 3))]);
            }
            #pragma unroll
            for (int ni = 0; ni < 4; ++ni)
                acc[ni] = __builtin_amdgcn_mfma_f32_16x16x32_bf16(af, bf[ni], acc[ni], 0, 0, 0);
        }
        __syncthreads();
    }
    #pragma unroll
    for (int ni = 0; ni < 4; ++ni) {
        int col = wn * 64 + ni * 16 + r16;
        float bv = bias[col];
        #pragma unroll
        for (int r = 0; r < 4; ++r) {
            int row = bm + wm * 16 + g * 4 + r;
            C[(size_t)row * N + col] = f2bf(acc[ni][r] + bv);
        }
    }
}

// ================= First attention: block = (b, half of 48 alpha rows) ========
__global__ __launch_bounds__(256) void first_attn_kernel(
    const float* __restrict__ note_times, const int* __restrict__ note_counts,
    const float* __restrict__ te_w, const float* __restrict__ te_b,
    const float* __restrict__ wk, const float* __restrict__ q_all,
    const unsigned short* __restrict__ note_emb,
    float* __restrict__ x_out, unsigned short* __restrict__ xbf_out)
{
    __shared__ union RU {
        float kkL[64 * 68];
        unsigned short E[32 * 256];
        struct { unsigned short As[32 * 64]; unsigned short Bs[128 * 64]; } mm;
    } ru;
    __shared__ float rsL[32][8];

    const int bx = blockIdx.x;
    const int b = bx >> 1, a0 = (bx & 1) * 24;
    const int tid = threadIdx.x, lane = tid & 63;
    const int wv = __builtin_amdgcn_readfirstlane(tid >> 6);
    const int g = lane >> 4, r16 = lane & 15;
    const int nc = note_counts[b];

    float kte[64];
    {
        float t = note_times[b * 64 + lane];
        #pragma unroll
        for (int j = 0; j < 64; ++j) {
            float lin = fmaf(t, te_w[j], te_b[j]);
            kte[j] = (j == 0) ? lin : __sinf(lin);
        }
    }
    {
        float kvp[16] = {};
        #pragma unroll
        for (int j = 0; j < 64; ++j) {
            #pragma unroll
            for (int dd = 0; dd < 16; ++dd)
                kvp[dd] = fmaf(kte[j], wk[j * 64 + wv * 16 + dd], kvp[dd]);
        }
        #pragma unroll
        for (int q4 = 0; q4 < 4; ++q4)
            *(f32x4*)(&ru.kkL[lane * 68 + wv * 16 + q4 * 4]) = *(const f32x4*)(&kvp[q4 * 4]);
    }
    __syncthreads();
    float kv[64];
    #pragma unroll
    for (int q4 = 0; q4 < 16; ++q4)
        *(f32x4*)(&kv[q4 * 4]) = *(const f32x4*)(&ru.kkL[lane * 68 + q4 * 4]);
    __syncthreads();

    float abar[6] = {};
    const float scale = 0.35355339059327373f; // 1/sqrt(8)
    #pragma unroll
    for (int p = 0; p < 2; ++p) {
        float e_reg[6][4];
        #pragma unroll
        for (int i = 0; i < 6; ++i) {
            int a = wv * 6 + i;
            float s[4];
            #pragma unroll
            for (int h = 0; h < 4; ++h) {
                float acc = 0.f;
                #pragma unroll
                for (int d = 0; d < 8; ++d)
                    acc = fmaf(q_all[(a0 + a) * 64 + p * 32 + h * 8 + d],
                               kv[p * 32 + h * 8 + d], acc);
                s[h] = (lane < nc) ? acc * scale : -1e9f;
            }
            unsigned m0 = pk_f16(s[0], s[1]);
            unsigned m1 = pk_f16(s[2], s[3]);
            #pragma unroll
            for (int st = 32; st >= 1; st >>= 1) {
                m0 = pk_max(m0, (unsigned)__shfl_xor((int)m0, st));
                m1 = pk_max(m1, (unsigned)__shfl_xor((int)m1, st));
            }
            float mm[4] = { f16_lo(m0), f16_hi(m0), f16_lo(m1), f16_hi(m1) };
            #pragma unroll
            for (int h = 0; h < 4; ++h) {
                float e = __expf(s[h] - mm[h]);
                e_reg[i][h] = e;
                int k = h * 64 + lane;
                ru.E[a * 256 + (k ^ ((a & 7) << 3))] = f2bf(e);
            }
        }
        __syncthreads();
        if (wv < 2) {
            f32x4 acc = {0.f, 0.f, 0.f, 0.f};
            #pragma unroll
            for (int ks = 0; ks < 8; ++ks) {
                int row = wv * 16 + r16;
                short8 af = *(const short8*)(&ru.E[row * 256 + ((ks * 32 + g * 8) ^ ((row & 7) << 3))]);
                short bb = (r16 == (ks >> 1)) ? (short)0x3F80 : (short)0;
                short8 bf = { bb, bb, bb, bb, bb, bb, bb, bb };
                acc = __builtin_amdgcn_mfma_f32_16x16x32_bf16(af, bf, acc, 0, 0, 0);
            }
            if (r16 < 4) {
                #pragma unroll
                for (int r = 0; r < 4; ++r)
                    rsL[wv * 16 + g * 4 + r][p * 4 + r16] = 0.125f / fmaxf(acc[r], 1e-20f);
            }
        }
        __syncthreads();
        #pragma unroll
        for (int i = 0; i < 6; ++i) {
            int a = wv * 6 + i;
            f32x4 rv = *(const f32x4*)(&rsL[a][p * 4]);
            abar[i] = fmaf(e_reg[i][0], rv[0], abar[i]);
            abar[i] = fmaf(e_reg[i][1], rv[1], abar[i]);
            abar[i] = fmaf(e_reg[i][2], rv[2], abar[i]);
            abar[i] = fmaf(e_reg[i][3], rv[3], abar[i]);
        }
    }
    {
        int l = tid & 63;
        #pragma unroll
        for (int pp = 0; pp < 4; ++pp) {
            int c = pp * 4 + (tid >> 6);
            u32x4 v = *(const u32x4*)(&note_emb[((size_t)b * 64 + l) * 128 + c * 8]);
            #pragma unroll
            for (int j = 0; j < 8; ++j) {
                unsigned short h16 = (unsigned short)((j & 1) ? (v[j >> 1] >> 16) : (v[j >> 1] & 0xffff));
                int f = c * 8 + j;
                ru.mm.Bs[f * 64 + (l ^ ((f & 7) << 3))] = h16;
            }
        }
    }
    #pragma unroll
    for (int i = 0; i < 6; ++i) {
        int a = wv * 6 + i;
        ru.mm.As[a * 64 + (lane ^ ((a & 7) << 3))] = f2bf(abar[i]);
    }
    __syncthreads();

    f32x4 pv[4] = {};
    #pragma unroll
    for (int q = 0; q < 4; ++q) {
        int f = wv * 4 + q, mi = f >> 3, ni = f & 7;
        #pragma unroll
        for (int ks = 0; ks < 2; ++ks) {
            int co = ks * 32 + g * 8;
            int raw = mi * 16 + r16, rb = ni * 16 + r16;
            short8 af = *(const short8*)(&ru.mm.As[raw * 64 + (co ^ ((raw & 7) << 3))]);
            short8 bf = *(const short8*)(&ru.mm.Bs[rb * 64 + (co ^ ((rb & 7) << 3))]);
            pv[q] = __builtin_amdgcn_mfma_f32_16x16x32_bf16(af, bf, pv[q], 0, 0, 0);
        }
    }
    #pragma unroll
    for (int q = 0; q < 4; ++q) {
        int f = wv * 4 + q, mi = f >> 3, ni = f & 7;
        #pragma unroll
        for (int r = 0; r < 4; ++r) {
            int row = mi * 16 + g * 4 + r;
            if (row < 24) {
                float v = (nc > 0) ? pv[q][r] : 0.f;
                size_t o = ((size_t)b * AL_ + a0 + row) * 128 + ni * 16 + r16;
                x_out[o] = v;
                xbf_out[o] = f2bf(v);
            }
        }
    }
}

// ====== Transformer self-attn per (b,h): 192 threads, LDS-unioned =============
__global__ __launch_bounds__(192) void attn2_kernel(
    const unsigned short* __restrict__ xbf, const unsigned short* __restrict__ WtL,
    unsigned short* __restrict__ o)
{
    __shared__ union UA {
        unsigned short Xs[AL_ * 128];   // phase: stage + qkv
        float sL[AL_ * 52];             // phase: scores (Xs dead)
    } ua;
    __shared__ union UB {
        struct { unsigned short qM[AL_ * 40]; unsigned short kM[AL_ * 40]; } qk;
        unsigned short P[AL_ * 64];     // phase: softmax+PV (qM/kM dead)
    } ub;
    __shared__ unsigned short vT[16 * 72];
    int bid = blockIdx.x;
    int b = bid >> 3, h = bid & 7;
    int tid = threadIdx.x, lane = tid & 63;
    int wv = __builtin_amdgcn_readfirstlane(tid >> 6);
    int g = lane >> 4, r16 = lane & 15;

    #pragma unroll
    for (int p = 0; p < 4; ++p) {
        int i = p * 192 + tid;
        int a = i >> 4, c = (i & 15) * 8;
        u32x4 v = *(const u32x4*)(&xbf[((size_t)b * AL_ + a) * 128 + c]);
        *(u32x4*)(&ua.Xs[a * 128 + (c & 64) + ((c & 63) ^ ((a & 7) << 3))]) = v;
    }
    // zero pads: qM/kM cols 16..31, vT cols 48..63
    for (int i = tid; i < 768; i += 192) {
        int a = i >> 4, k2 = 16 + (i & 15);
        ub.qk.qM[a * 40 + k2] = 0;
        ub.qk.kM[a * 40 + k2] = 0;
    }
    for (int i = tid; i < 256; i += 192) {
        int d = i >> 4, k2 = 48 + (i & 15);
        vT[d * 72 + k2] = 0;
    }
    __syncthreads();

    // qkv: 3 waves, one matrix each (M=48, N=16, K=128)
    {
        f32x4 acc[3] = {};
        const unsigned short* Wm = WtL + wv * 16384 + (size_t)(h * 16) * 128;
        #pragma unroll
        for (int kq = 0; kq < 4; ++kq) {
            short8 bf = ldg8(&Wm[(size_t)r16 * 128 + kq * 32 + g * 8]);
            #pragma unroll
            for (int mi = 0; mi < 3; ++mi) {
                int row = mi * 16 + r16;
                int c = kq * 32 + g * 8;
                short8 af = *(const short8*)(&ua.Xs[row * 128 + (c & 64) + ((c & 63) ^ ((row & 7) << 3))]);
                acc[mi] = __builtin_amdgcn_mfma_f32_16x16x32_bf16(af, bf, acc[mi], 0, 0, 0);
            }
        }
        #pragma unroll
        for (int mi = 0; mi < 3; ++mi) {
            #pragma unroll
            for (int r = 0; r < 4; ++r) {
                int a = mi * 16 + g * 4 + r;
                unsigned short hv = f2bf(acc[mi][r]);
                if (wv == 0) ub.qk.qM[a * 40 + r16] = hv;
                else if (wv == 1) ub.qk.kM[a * 40 + r16] = hv;
                else vT[r16 * 72 + a] = hv;
            }
        }
    }
    __syncthreads();

    // scores: 9 frags (3m x 3n); writes sL over dead Xs
    {
        #pragma unroll
        for (int ni = 0; ni < 3; ++ni) {
            f32x4 acc = {0.f, 0.f, 0.f, 0.f};
            short8 af = *(const short8*)(&ub.qk.qM[(wv * 16 + r16) * 40 + g * 8]);
            short8 bf = *(const short8*)(&ub.qk.kM[(ni * 16 + r16) * 40 + g * 8]);
            acc = __builtin_amdgcn_mfma_f32_16x16x32_bf16(af, bf, acc, 0, 0, 0);
            #pragma unroll
            for (int r = 0; r < 4; ++r)
                ua.sL[(wv * 16 + g * 4 + r) * 52 + ni * 16 + r16] = acc[r] * 0.25f;
        }
    }
    __syncthreads();

    // distributed softmax: 4-lane group per row; P overlays dead qM/kM
    {
        int row = wv * 16 + (lane >> 2), sub = lane & 3;
        f32x4 v0 = *(const f32x4*)(&ua.sL[row * 52 + sub * 4]);
        f32x4 v1 = *(const f32x4*)(&ua.sL[row * 52 + 16 + sub * 4]);
        f32x4 v2 = *(const f32x4*)(&ua.sL[row * 52 + 32 + sub * 4]);
        float m = fmaxf(fmaxf(fmaxf(v0[0], v0[1]), fmaxf(v0[2], v0[3])),
                        fmaxf(fmaxf(v1[0], v1[1]), fmaxf(v1[2], v1[3])));
        m = fmaxf(m, fmaxf(fmaxf(v2[0], v2[1]), fmaxf(v2[2], v2[3])));
        m = fmaxf(m, __shfl_xor(m, 1));
        m = fmaxf(m, __shfl_xor(m, 2));
        float e[12];
        #pragma unroll
        for (int j = 0; j < 4; ++j) {
            e[j]     = __expf(v0[j] - m);
            e[4 + j] = __expf(v1[j] - m);
            e[8 + j] = __expf(v2[j] - m);
        }
        float sum = 0.f;
        #pragma unroll
        for (int j = 0; j < 12; ++j) sum += e[j];
        sum += __shfl_xor(sum, 1);
        sum += __shfl_xor(sum, 2);
        float inv = __fdividef(1.f, sum);
        #pragma unroll
        for (int c = 0; c < 3; ++c) {
            u32x2 w;
            w[0] = f2bf2(e[c * 4 + 0] * inv, e[c * 4 + 1] * inv);
            w[1] = f2bf2(e[c * 4 + 2] * inv, e[c * 4 + 3] * inv);
            int col = c * 16 + sub * 4;
            *(u32x2*)(&ub.P[row * 64 + (col ^ ((row & 7) << 3))]) = w;
        }
        // P zero-pad cols 48..63 (after qM/kM reads are done)
        for (int i = tid; i < 768; i += 192) {
            int a = i >> 4, c = 48 + (i & 15);
            ub.P[a * 64 + (c ^ ((a & 7) << 3))] = 0;
        }
    }
    __syncthreads();

    // PV: out[a][d] = sum_a' P[a][a'] v[a'][d]; m-frag = wv, K=64 (padded)
    {
        f32x4 acc = {0.f, 0.f, 0.f, 0.f};
        #pragma unroll
        for (int ks = 0; ks < 2; ++ks) {
            int co = ks * 32 + g * 8;
            int rp = wv * 16 + r16;
            short8 af = *(const short8*)(&ub.P[rp * 64 + (co ^ ((rp & 7) << 3))]);
            short8 bf = *(const short8*)(&vT[r16 * 72 + co]);
            acc = __builtin_amdgcn_mfma_f32_16x16x32_bf16(af, bf, acc, 0, 0, 0);
        }
        #pragma unroll
        for (int r = 0; r < 4; ++r) {
            int a = wv * 16 + g * 4 + r;
            o[((size_t)b * AL_ + a) * 128 + h * 16 + r16] = f2bf(acc[r]);
        }
    }
}

// ====== Layer tail (ROWS rows/block): wo-GEMM + LN1 + FFN + LN2 (+head) =======
template<int ROWS>
__global__ __launch_bounds__(256) void layer_tail_kernel(
    const unsigned short* __restrict__ obuf, const unsigned short* __restrict__ Wl,
    const float* __restrict__ b1, const float* __restrict__ b2,
    const float* __restrict__ g1, const float* __restrict__ be1,
    const float* __restrict__ g2, const float* __restrict__ be2,
    float* __restrict__ x, unsigned short* __restrict__ xbf,
    int last, const float* __restrict__ cw1, const float* __restrict__ cb1,
    const float* __restrict__ cw2, const float* __restrict__ cb2,
    float* __restrict__ outp)
{
    constexpr int MR = ROWS / 16;
    __shared__ unsigned short OX[ROWS * 128];
    __shared__ union { unsigned short hid[ROWS * 512]; float Cs[ROWS * 132]; } u2;
    __shared__ float xr[ROWS * 132];
    const int tid = threadIdx.x, lane = tid & 63;
    const int wv = __builtin_amdgcn_readfirstlane(tid >> 6);
    const int g = lane >> 4, r16 = lane & 15;
    const int row0 = last ? ((int)blockIdx.x * 48 + 32) : ((int)blockIdx.x * ROWS);

    #pragma unroll
    for (int p = 0; p < MR; ++p) {
        int i = p * 256 + tid;
        int a = i >> 4, c = (i & 15) * 8;
        u32x4 v = *(const u32x4*)(&obuf[(size_t)(row0 + a) * 128 + c]);
        *(u32x4*)(&OX[a * 128 + (c & 64) + ((c & 63) ^ ((a & 7) << 3))]) = v;
    }
    __syncthreads();

    // wo GEMM: 8*MR frags, wave does ni = wv*2 + {0,1}, mi < MR
    {
        f32x4 wacc[MR][2] = {};
        #pragma unroll
        for (int q = 0; q < 2; ++q) {
            int ni = wv * 2 + q;
            const unsigned short* Wm = Wl + 49152 + (size_t)(ni * 16 + r16) * 128;
            #pragma unroll
            for (int kq = 0; kq < 4; ++kq) {
                int co = kq * 32 + g * 8;
                short8 bf = ldg8(Wm + co);
                #pragma unroll
                for (int mi = 0; mi < MR; ++mi) {
                    int ra = mi * 16 + r16;
                    short8 af = *(const short8*)(&OX[ra * 128 + (co & 64) + ((co & 63) ^ ((ra & 7) << 3))]);
                    wacc[mi][q] = __builtin_amdgcn_mfma_f32_16x16x32_bf16(af, bf, wacc[mi][q], 0, 0, 0);
                }
            }
        }
        #pragma unroll
        for (int mi = 0; mi < MR; ++mi)
            #pragma unroll
            for (int q = 0; q < 2; ++q) {
                int ni = wv * 2 + q;
                #pragma unroll
                for (int r = 0; r < 4; ++r)
                    u2.Cs[(mi * 16 + g * 4 + r) * 132 + ni * 16 + r16] = wacc[mi][q][r];
            }
    }
    __syncthreads();

    // LN1 (+residual)
    #pragma unroll
    for (int rr = 0; rr < ROWS / 4; ++rr) {
        int row = wv * (ROWS / 4) + rr;
        size_t go = (size_t)(row0 + row) * 128;
        float v0 = u2.Cs[row * 132 + lane] + x[go + lane];
        float v1 = u2.Cs[row * 132 + 64 + lane] + x[go + 64 + lane];
        float sum = v0 + v1, sq = v0 * v0 + v1 * v1;
        #pragma unroll
        for (int o2 = 32; o2 >= 1; o2 >>= 1) {
            sum += __shfl_xor(sum, o2);
            sq  += __shfl_xor(sq, o2);
        }
        float mu = sum * (1.f / 128.f);
        float var = sq * (1.f / 128.f) - mu * mu;
        float rs = rsqrtf(var + 1e-5f);
        float o0 = (v0 - mu) * rs * g1[lane] + be1[lane];
        float o1 = (v1 - mu) * rs * g1[lane + 64] + be1[lane + 64];
        xr[row * 132 + lane] = o0;
        xr[row * 132 + 64 + lane] = o1;
        OX[row * 128 + (lane ^ ((row & 7) << 3))] = f2bf(o0);
        OX[row * 128 + 64 + (lane ^ ((row & 7) << 3))] = f2bf(o1);
    }
    __syncthreads();

    // hidden = relu(Xs @ w1 + b1): wave owns cols [wv*128, +128)
    {
        f32x4 hacc[MR][8] = {};
        #pragma unroll
        for (int nf = 0; nf < 8; ++nf) {
            int col = wv * 128 + nf * 16 + r16;
            const unsigned short* Wm = Wl + 65536 + (size_t)col * 128;
            #pragma unroll
            for (int kq = 0; kq < 4; ++kq) {
                int co = kq * 32 + g * 8;
                short8 bf = ldg8(Wm + co);
                #pragma unroll
                for (int mi = 0; mi < MR; ++mi) {
                    int ra = mi * 16 + r16;
                    short8 af = *(const short8*)(&OX[ra * 128 + (co & 64) + ((co & 63) ^ ((ra & 7) << 3))]);
                    hacc[mi][nf] = __builtin_amdgcn_mfma_f32_16x16x32_bf16(af, bf, hacc[mi][nf], 0, 0, 0);
                }
            }
        }
        #pragma unroll
        for (int nf = 0; nf < 8; ++nf) {
            int col = wv * 128 + nf * 16 + r16;
            float bv = b1[col];
            #pragma unroll
            for (int mi = 0; mi < MR; ++mi)
                #pragma unroll
                for (int r = 0; r < 4; ++r) {
                    int rowa = mi * 16 + g * 4 + r;
                    u2.hid[rowa * 512 + (col & 448) + ((col & 63) ^ ((rowa & 7) << 3))] =
                        f2bf(fmaxf(hacc[mi][nf][r] + bv, 0.f));
                }
        }
    }
    __syncthreads();

    // y = hid @ w2 (K=512)
    f32x4 yacc[MR][2] = {};
    #pragma unroll
    for (int q = 0; q < 2; ++q) {
        int ni = wv * 2 + q;
        const unsigned short* Wm = Wl + 131072 + (size_t)(ni * 16 + r16) * 512;
        #pragma unroll
        for (int kq = 0; kq < 16; ++kq) {
            int co = kq * 32 + g * 8;
            short8 bf = ldg8(Wm + co);
            #pragma unroll
            for (int mi = 0; mi < MR; ++mi) {
                int ra = mi * 16 + r16;
                short8 af = *(const short8*)(&u2.hid[ra * 512 + (co & 448) + ((co & 63) ^ ((ra & 7) << 3))]);
                yacc[mi][q] = __builtin_amdgcn_mfma_f32_16x16x32_bf16(af, bf, yacc[mi][q], 0, 0, 0);
            }
        }
    }
    __syncthreads();
    #pragma unroll
    for (int mi = 0; mi < MR; ++mi)
        #pragma unroll
        for (int q = 0; q < 2; ++q) {
            int ni = wv * 2 + q;
            float bv = b2[ni * 16 + r16];
            #pragma unroll
            for (int r = 0; r < 4; ++r)
                u2.Cs[(mi * 16 + g * 4 + r) * 132 + ni * 16 + r16] = yacc[mi][q][r] + bv;
        }
    __syncthreads();

    // LN2 (+residual xr)
    #pragma unroll
    for (int rr = 0; rr < ROWS / 4; ++rr) {
        int row = wv * (ROWS / 4) + rr;
        size_t go = (size_t)(row0 + row) * 128;
        float v0 = u2.Cs[row * 132 + lane] + xr[row * 132 + lane];
        float v1 = u2.Cs[row * 132 + 64 + lane] + xr[row * 132 + 64 + lane];
        float sum = v0 + v1, sq = v0 * v0 + v1 * v1;
        #pragma unroll
        for (int o2 = 32; o2 >= 1; o2 >>= 1) {
            sum += __shfl_xor(sum, o2);
            sq  += __shfl_xor(sq, o2);
        }
        float mu = sum * (1.f / 128.f);
        float var = sq * (1.f / 128.f) - mu * mu;
        float rs = rsqrtf(var + 1e-5f);
        float o0 = (v0 - mu) * rs * g2[lane] + be2[lane];
        float o1 = (v1 - mu) * rs * g2[lane + 64] + be2[lane + 64];
        if (!last) {
            x[go + lane] = o0;
            x[go + 64 + lane] = o1;
            xbf[go + lane] = f2bf(o0);
            xbf[go + 64 + lane] = f2bf(o1);
        } else {
            xr[row * 132 + lane] = o0;
            xr[row * 132 + 64 + lane] = o1;
        }
    }
    if (last) {
        __syncthreads();
        if (wv == 0) {
            float hj = cb1[lane];
            #pragma unroll 8
            for (int d = 0; d < 128; ++d)
                hj = fmaf(xr[(ROWS - 1) * 132 + d], cw1[d * 64 + lane], hj);
            hj = fmaxf(hj, 0.f);
            float acc = hj * cw2[lane];
            #pragma unroll
            for (int o2 = 32; o2 >= 1; o2 >>= 1) acc += __shfl_xor(acc, o2);
            if (lane == 0) outp[blockIdx.x] = acc + cb2[0];
        }
    }
}

// ================= Launch =====================================================
extern "C" void kernel_launch(void* const* d_in, const int* in_sizes, int n_in,
                              void* d_out, int out_size, void* d_ws, size_t ws_size,
                              hipStream_t stream) {
    (void)in_sizes; (void)n_in; (void)out_size; (void)ws_size;
    const float* cls_emb    = (const float*)d_in[0];
    const float* note_times = (const float*)d_in[1];
    const int*   note_counts= (const int*)d_in[2];
    const float* proj_w     = (const float*)d_in[3];
    const float* proj_b     = (const float*)d_in[4];
    const float* te_w       = (const float*)d_in[5];
    const float* te_b       = (const float*)d_in[6];
    const float* wq         = (const float*)d_in[7];
    const float* wk         = (const float*)d_in[8];
    const float* tf_wq      = (const float*)d_in[9];
    const float* tf_wk      = (const float*)d_in[10];
    const float* tf_wv      = (const float*)d_in[11];
    const float* tf_wo      = (const float*)d_in[12];
    const float* tf_ln1_g   = (const float*)d_in[13];
    const float* tf_ln1_b   = (const float*)d_in[14];
    const float* tf_w1      = (const float*)d_in[15];
    const float* tf_b1      = (const float*)d_in[16];
    const float* tf_w2      = (const float*)d_in[17];
    const float* tf_b2      = (const float*)d_in[18];
    const float* tf_ln2_g   = (const float*)d_in[19];
    const float* tf_ln2_b   = (const float*)d_in[20];
    const float* cls_w1     = (const float*)d_in[21];
    const float* cls_b1     = (const float*)d_in[22];
    const float* cls_w2     = (const float*)d_in[23];
    const float* cls_b2     = (const float*)d_in[24];
    float* out = (float*)d_out;
    float* ws = (float*)d_ws;

    // workspace layout (float units)
    unsigned short* note_emb16 = (unsigned short*)(ws + 0);       // 1,048,576 f
    float* x        = ws + 1048576;                                // 1,572,864 f
    unsigned short* obuf16 = (unsigned short*)(ws + 2621440);      // 786,432 f
    unsigned short* xbf    = (unsigned short*)(ws + 3407872);      // 786,432 f
    float* q_all    = ws + 4194304;                                // 3,072 f
    unsigned short* wt     = (unsigned short*)(ws + 4197376);      // 344,064 f

    TTab tab;
    int tile = 0, idx = 0;
    auto add = [&](const float* src, int dstOff, int K, int N) {
        tab.e[idx].src = src; tab.e[idx].dstOff = dstOff;
        tab.e[idx].K = K; tab.e[idx].N = N; tab.e[idx].tile0 = tile;
        tile += (K / 64) * (N / 64); ++idx;
    };
    add(proj_w, 0, DT_, DH_);
    int layerBase[NL_];
    for (int i = 0; i < NL_; ++i) {
        int base = 98304 + i * 196608;
        layerBase[i] = base;
        add(tf_wq + (size_t)i * DH_ * DH_, base,           DH_, DH_);
        add(tf_wk + (size_t)i * DH_ * DH_, base + 16384,   DH_, DH_);
        add(tf_wv + (size_t)i * DH_ * DH_, base + 32768,   DH_, DH_);
        add(tf_wo + (size_t)i * DH_ * DH_, base + 49152,   DH_, DH_);
        add(tf_w1 + (size_t)i * DH_ * DFF_, base + 65536,  DH_, DFF_);
        add(tf_w2 + (size_t)i * DFF_ * DH_, base + 131072, DFF_, DH_);
    }
    prep_weights_kernel<<<tile + 1, 256, 0, stream>>>(tab, tile, wt, te_w, te_b, wq, q_all);

    const int Mx = B_ * AL_; // 12288

    gemm_proj_kernel<<<(B_ * L_) / 32, 256, 0, stream>>>(
        cls_emb, wt, proj_b, note_emb16, B_ * L_, DH_, DT_);

    first_attn_kernel<<<B_ * 2, 256, 0, stream>>>(
        note_times, note_counts, te_w, te_b, wk, q_all, note_emb16, x, xbf);

    for (int i = 0; i < NL_; ++i) {
        int base = layerBase[i];
        int last = (i == NL_ - 1);
        attn2_kernel<<<B_ * H_, 192, 0, stream>>>(xbf, wt + base, obuf16);
        if (!last) {
            layer_tail_kernel<32><<<Mx / 32, 256, 0, stream>>>(
                obuf16, wt + base,
                tf_b1 + i * DFF_, tf_b2 + i * DH_,
                tf_ln1_g + i * DH_, tf_ln1_b + i * DH_,
                tf_ln2_g + i * DH_, tf_ln2_b + i * DH_,
                x, xbf,
                0, cls_w1, cls_b1, cls_w2, cls_b2, out);
        } else {
            layer_tail_kernel<16><<<B_, 256, 0, stream>>>(
                obuf16, wt + base,
                tf_b1 + i * DFF_, tf_b2 + i * DH_,
                tf_ln1_g + i * DH_, tf_ln1_b + i * DH_,
                tf_ln2_g + i * DH_, tf_ln2_b + i * DH_,
                x, xbf,
                1, cls_w1, cls_b1, cls_w2, cls_b2, out);
        }
    }
}

// Round 10
// 169.194 us; speedup vs baseline: 1.7900x; 1.0282x over previous
//
#include <hip/hip_runtime.h>
#include <hip/hip_bf16.h>

// Problem constants
#define B_   256
#define L_   64
#define DT_  768
#define DH_  128
#define AL_  48
#define DTE_ 64
#define H_   8
#define NL_  3
#define DFF_ 512

typedef __attribute__((ext_vector_type(4))) float f32x4;
typedef __attribute__((ext_vector_type(4))) unsigned int u32x4;
typedef __attribute__((ext_vector_type(2))) unsigned int u32x2;
typedef __attribute__((ext_vector_type(8))) short short8;

__device__ inline unsigned short f2bf(float f) {
    union { float f; unsigned u; } v; v.f = f;
    unsigned r = (v.u + 0x7FFFu + ((v.u >> 16) & 1u)) >> 16;
    return (unsigned short)r;
}
__device__ inline unsigned f2bf2(float a, float b) {
    return (unsigned)f2bf(a) | ((unsigned)f2bf(b) << 16);
}
__device__ inline float bf2f(unsigned short u) {
    union { unsigned u; float f; } v; v.u = ((unsigned)u) << 16; return v.f;
}
__device__ inline short8 ldg8(const unsigned short* p) {
    union { short8 s; u32x4 v; } r;
    r.v = *(const u32x4*)p;
    return r.s;
}
// packed f16 helpers
__device__ inline unsigned pk_f16(float a, float b) {
    unsigned r;
    asm("v_cvt_pkrtz_f16_f32 %0, %1, %2" : "=v"(r) : "v"(a), "v"(b));
    return r;
}
__device__ inline unsigned pk_max(unsigned a, unsigned b) {
    unsigned r;
    asm("v_pk_max_f16 %0, %1, %2" : "=v"(r) : "v"(a), "v"(b));
    return r;
}
__device__ inline float f16_lo(unsigned h) {
    float f; asm("v_cvt_f32_f16 %0, %1" : "=v"(f) : "v"(h)); return f;
}
__device__ inline float f16_hi(unsigned h) {
    float f; unsigned t = h >> 16;
    asm("v_cvt_f32_f16 %0, %1" : "=v"(f) : "v"(t)); return f;
}

// ====== Weight prep (fp32 [K][N] -> bf16 Wt [N][K]) + q_all prep (last block) =
struct TEnt { const float* src; int dstOff; int K; int N; int tile0; };
struct TTab { TEnt e[19]; };

__global__ __launch_bounds__(256) void prep_weights_kernel(
    TTab tab, int ntile, unsigned short* __restrict__ wt,
    const float* __restrict__ te_w, const float* __restrict__ te_b,
    const float* __restrict__ wq, float* __restrict__ q_allG)
{
    __shared__ unsigned short lds[64][72];
    __shared__ float qte[AL_ * 68];
    int tid = threadIdx.x;
    if ((int)blockIdx.x >= ntile) {
        for (int i = tid; i < AL_ * 64; i += 256) {
            int a = i >> 6, j = i & 63;
            float lin = fmaf((float)a, te_w[j], te_b[j]);
            qte[a * 68 + j] = (j == 0) ? lin : __sinf(lin);
        }
        __syncthreads();
        for (int i = tid; i < AL_ * 64; i += 256) {
            int a = i >> 6, d = i & 63;
            float s0 = 0.f, s1 = 0.f, s2 = 0.f, s3 = 0.f;
            for (int j = 0; j < 64; j += 4) {
                s0 = fmaf(qte[a * 68 + j],     wq[j * 64 + d],       s0);
                s1 = fmaf(qte[a * 68 + j + 1], wq[(j + 1) * 64 + d], s1);
                s2 = fmaf(qte[a * 68 + j + 2], wq[(j + 2) * 64 + d], s2);
                s3 = fmaf(qte[a * 68 + j + 3], wq[(j + 3) * 64 + d], s3);
            }
            q_allG[i] = (s0 + s1) + (s2 + s3);
        }
        return;
    }
    int ei = 0;
    #pragma unroll
    for (int j = 1; j < 19; ++j) if ((int)blockIdx.x >= tab.e[j].tile0) ei = j;
    TEnt e = tab.e[ei];
    int t = blockIdx.x - e.tile0;
    int tilesK = e.K >> 6;
    int tk = t % tilesK, tn = t / tilesK;
    #pragma unroll
    for (int p = 0; p < 16; ++p) {
        int kk = p * 4 + (tid >> 6);
        int n = tid & 63;
        float v = e.src[(size_t)(tk * 64 + kk) * e.N + tn * 64 + n];
        lds[n][kk] = f2bf(v);
    }
    __syncthreads();
    #pragma unroll
    for (int p = 0; p < 2; ++p) {
        int c = p * 256 + tid;
        int n = c >> 3, q = c & 7;
        u32x4 v = *(const u32x4*)(&lds[n][q * 8]);
        *(u32x4*)(&wt[(size_t)e.dstOff + (size_t)(tn * 64 + n) * e.K + tk * 64 + q * 8]) = v;
    }
}

// ====== bf16 MFMA GEMM (proj): B-frags direct from L2, BK=128, BM=32 =========
__global__ __launch_bounds__(256) void gemm_proj_kernel(
    const float* __restrict__ A, const unsigned short* __restrict__ Wt,
    const float* __restrict__ bias, unsigned short* __restrict__ C,
    int M, int N, int K)
{
    __shared__ unsigned short As[32 * 128];
    int tid = threadIdx.x;
    int bm = blockIdx.x * 32;
    int wave = tid >> 6, lane = tid & 63;
    int g = lane >> 4, r16 = lane & 15;

    f32x4 acc[2][2] = {};

    for (int k0 = 0; k0 < K; k0 += 128) {
        {
            int row = tid >> 3, c16 = (tid & 7) * 16;
            const float* Ap = &A[(size_t)(bm + row) * K + k0 + c16];
            f32x4 v0 = *(const f32x4*)(Ap);
            f32x4 v1 = *(const f32x4*)(Ap + 4);
            f32x4 v2 = *(const f32x4*)(Ap + 8);
            f32x4 v3 = *(const f32x4*)(Ap + 12);
            u32x4 w0, w1;
            w0[0] = f2bf2(v0[0], v0[1]); w0[1] = f2bf2(v0[2], v0[3]);
            w0[2] = f2bf2(v1[0], v1[1]); w0[3] = f2bf2(v1[2], v1[3]);
            w1[0] = f2bf2(v2[0], v2[1]); w1[1] = f2bf2(v2[2], v2[3]);
            w1[2] = f2bf2(v3[0], v3[1]); w1[3] = f2bf2(v3[2], v3[3]);
            int cA = c16, cB = c16 + 8;
            *(u32x4*)(&As[row * 128 + (cA & 64) + ((cA & 63) ^ ((row & 7) << 3))]) = w0;
            *(u32x4*)(&As[row * 128 + (cB & 64) + ((cB & 63) ^ ((row & 7) << 3))]) = w1;
        }
        __syncthreads();
        #pragma unroll
        for (int kk = 0; kk < 4; ++kk) {
            int co = kk * 32 + g * 8;
            short8 af[2];
            #pragma unroll
            for (int mi = 0; mi < 2; ++mi) {
                int rr = mi * 16 + r16;
                af[mi] = *(const short8*)(&As[rr * 128 + (co & 64) + ((co & 63) ^ ((rr & 7) << 3))]);
            }
            #pragma unroll
            for (int q = 0; q < 2; ++q) {
                int ni = wave * 2 + q;
                short8 bf = ldg8(&Wt[(size_t)(ni * 16 + r16) * K + k0 + co]);
                acc[0][q] = __builtin_amdgcn_mfma_f32_16x16x32_bf16(af[0], bf, acc[0][q], 0, 0, 0);
                acc[1][q] = __builtin_amdgcn_mfma_f32_16x16x32_bf16(af[1], bf, acc[1][q], 0, 0, 0);
            }
        }
        __syncthreads();
    }
    #pragma unroll
    for (int q = 0; q < 2; ++q) {
        int col = (wave * 2 + q) * 16 + r16;
        float bv = bias[col];
        #pragma unroll
        for (int mi = 0; mi < 2; ++mi) {
            #pragma unroll
            for (int r = 0; r < 4; ++r) {
                int row = bm + mi * 16 + g * 4 + r;
                C[(size_t)row * N + col] = f2bf(acc[mi][q][r] + bv);
            }
        }
    }
}

// ================= First attention: block = (b, half of 48 alpha rows) ========
__global__ __launch_bounds__(256) void first_attn_kernel(
    const float* __restrict__ note_times, const int* __restrict__ note_counts,
    const float* __restrict__ te_w, const float* __restrict__ te_b,
    const float* __restrict__ wk, const float* __restrict__ q_all,
    const unsigned short* __restrict__ note_emb,
    float* __restrict__ x_out, unsigned short* __restrict__ xbf_out)
{
    __shared__ union RU {
        float kkL[64 * 68];
        unsigned short E[32 * 256];
        struct { unsigned short As[32 * 64]; unsigned short Bs[128 * 64]; } mm;
    } ru;
    __shared__ float rsL[32][8];

    const int bx = blockIdx.x;
    const int b = bx >> 1, a0 = (bx & 1) * 24;
    const int tid = threadIdx.x, lane = tid & 63;
    const int wv = __builtin_amdgcn_readfirstlane(tid >> 6);
    const int g = lane >> 4, r16 = lane & 15;
    const int nc = note_counts[b];

    float kte[64];
    {
        float t = note_times[b * 64 + lane];
        #pragma unroll
        for (int j = 0; j < 64; ++j) {
            float lin = fmaf(t, te_w[j], te_b[j]);
            kte[j] = (j == 0) ? lin : __sinf(lin);
        }
    }
    {
        float kvp[16] = {};
        #pragma unroll
        for (int j = 0; j < 64; ++j) {
            #pragma unroll
            for (int dd = 0; dd < 16; ++dd)
                kvp[dd] = fmaf(kte[j], wk[j * 64 + wv * 16 + dd], kvp[dd]);
        }
        #pragma unroll
        for (int q4 = 0; q4 < 4; ++q4)
            *(f32x4*)(&ru.kkL[lane * 68 + wv * 16 + q4 * 4]) = *(const f32x4*)(&kvp[q4 * 4]);
    }
    __syncthreads();
    float kv[64];
    #pragma unroll
    for (int q4 = 0; q4 < 16; ++q4)
        *(f32x4*)(&kv[q4 * 4]) = *(const f32x4*)(&ru.kkL[lane * 68 + q4 * 4]);
    __syncthreads();

    float abar[6] = {};
    const float scale = 0.35355339059327373f; // 1/sqrt(8)
    #pragma unroll
    for (int p = 0; p < 2; ++p) {
        float e_reg[6][4];
        #pragma unroll
        for (int i = 0; i < 6; ++i) {
            int a = wv * 6 + i;
            float s[4];
            #pragma unroll
            for (int h = 0; h < 4; ++h) {
                float acc = 0.f;
                #pragma unroll
                for (int d = 0; d < 8; ++d)
                    acc = fmaf(q_all[(a0 + a) * 64 + p * 32 + h * 8 + d],
                               kv[p * 32 + h * 8 + d], acc);
                s[h] = (lane < nc) ? acc * scale : -1e9f;
            }
            unsigned m0 = pk_f16(s[0], s[1]);
            unsigned m1 = pk_f16(s[2], s[3]);
            #pragma unroll
            for (int st = 32; st >= 1; st >>= 1) {
                m0 = pk_max(m0, (unsigned)__shfl_xor((int)m0, st));
                m1 = pk_max(m1, (unsigned)__shfl_xor((int)m1, st));
            }
            float mm[4] = { f16_lo(m0), f16_hi(m0), f16_lo(m1), f16_hi(m1) };
            #pragma unroll
            for (int h = 0; h < 4; ++h) {
                float e = __expf(s[h] - mm[h]);
                e_reg[i][h] = e;
                int k = h * 64 + lane;
                ru.E[a * 256 + (k ^ ((a & 7) << 3))] = f2bf(e);
            }
        }
        __syncthreads();
        if (wv < 2) {
            f32x4 acc = {0.f, 0.f, 0.f, 0.f};
            #pragma unroll
            for (int ks = 0; ks < 8; ++ks) {
                int row = wv * 16 + r16;
                short8 af = *(const short8*)(&ru.E[row * 256 + ((ks * 32 + g * 8) ^ ((row & 7) << 3))]);
                short bb = (r16 == (ks >> 1)) ? (short)0x3F80 : (short)0;
                short8 bf = { bb, bb, bb, bb, bb, bb, bb, bb };
                acc = __builtin_amdgcn_mfma_f32_16x16x32_bf16(af, bf, acc, 0, 0, 0);
            }
            if (r16 < 4) {
                #pragma unroll
                for (int r = 0; r < 4; ++r)
                    rsL[wv * 16 + g * 4 + r][p * 4 + r16] = 0.125f / fmaxf(acc[r], 1e-20f);
            }
        }
        __syncthreads();
        #pragma unroll
        for (int i = 0; i < 6; ++i) {
            int a = wv * 6 + i;
            f32x4 rv = *(const f32x4*)(&rsL[a][p * 4]);
            abar[i] = fmaf(e_reg[i][0], rv[0], abar[i]);
            abar[i] = fmaf(e_reg[i][1], rv[1], abar[i]);
            abar[i] = fmaf(e_reg[i][2], rv[2], abar[i]);
            abar[i] = fmaf(e_reg[i][3], rv[3], abar[i]);
        }
    }
    {
        int l = tid & 63;
        #pragma unroll
        for (int pp = 0; pp < 4; ++pp) {
            int c = pp * 4 + (tid >> 6);
            u32x4 v = *(const u32x4*)(&note_emb[((size_t)b * 64 + l) * 128 + c * 8]);
            #pragma unroll
            for (int j = 0; j < 8; ++j) {
                unsigned short h16 = (unsigned short)((j & 1) ? (v[j >> 1] >> 16) : (v[j >> 1] & 0xffff));
                int f = c * 8 + j;
                ru.mm.Bs[f * 64 + (l ^ ((f & 7) << 3))] = h16;
            }
        }
    }
    #pragma unroll
    for (int i = 0; i < 6; ++i) {
        int a = wv * 6 + i;
        ru.mm.As[a * 64 + (lane ^ ((a & 7) << 3))] = f2bf(abar[i]);
    }
    __syncthreads();

    f32x4 pv[4] = {};
    #pragma unroll
    for (int q = 0; q < 4; ++q) {
        int f = wv * 4 + q, mi = f >> 3, ni = f & 7;
        #pragma unroll
        for (int ks = 0; ks < 2; ++ks) {
            int co = ks * 32 + g * 8;
            int raw = mi * 16 + r16, rb = ni * 16 + r16;
            short8 af = *(const short8*)(&ru.mm.As[raw * 64 + (co ^ ((raw & 7) << 3))]);
            short8 bf = *(const short8*)(&ru.mm.Bs[rb * 64 + (co ^ ((rb & 7) << 3))]);
            pv[q] = __builtin_amdgcn_mfma_f32_16x16x32_bf16(af, bf, pv[q], 0, 0, 0);
        }
    }
    #pragma unroll
    for (int q = 0; q < 4; ++q) {
        int f = wv * 4 + q, mi = f >> 3, ni = f & 7;
        #pragma unroll
        for (int r = 0; r < 4; ++r) {
            int row = mi * 16 + g * 4 + r;
            if (row < 24) {
                float v = (nc > 0) ? pv[q][r] : 0.f;
                size_t o = ((size_t)b * AL_ + a0 + row) * 128 + ni * 16 + r16;
                x_out[o] = v;
                xbf_out[o] = f2bf(v);
            }
        }
    }
}

// ====== Transformer self-attn: block = (b, 2 heads), 192 threads ==============
__global__ __launch_bounds__(192) void attn2_kernel(
    const unsigned short* __restrict__ xbf, const unsigned short* __restrict__ WtL,
    unsigned short* __restrict__ o)
{
    __shared__ unsigned short Xs[AL_ * 128];    // alive across both heads
    __shared__ float sL[AL_ * 52];
    __shared__ union UB {
        struct { unsigned short qM[AL_ * 40]; unsigned short kM[AL_ * 40]; } qk;
        unsigned short P[AL_ * 64];
    } ub;
    __shared__ unsigned short vT[16 * 72];
    int bid = blockIdx.x;
    int b = bid >> 2, h0 = (bid & 3) << 1;
    int tid = threadIdx.x, lane = tid & 63;
    int wv = __builtin_amdgcn_readfirstlane(tid >> 6);
    int g = lane >> 4, r16 = lane & 15;

    #pragma unroll
    for (int p = 0; p < 4; ++p) {
        int i = p * 192 + tid;
        int a = i >> 4, c = (i & 15) * 8;
        u32x4 v = *(const u32x4*)(&xbf[((size_t)b * AL_ + a) * 128 + c]);
        *(u32x4*)(&Xs[a * 128 + (c & 64) + ((c & 63) ^ ((a & 7) << 3))]) = v;
    }
    for (int i = tid; i < 256; i += 192) {
        int d = i >> 4, k2 = 48 + (i & 15);
        vT[d * 72 + k2] = 0;
    }
    __syncthreads();

    for (int hh = 0; hh < 2; ++hh) {
        int h = h0 + hh;
        // re-zero qM/kM pads (P overlay corrupted them last iteration)
        for (int i = tid; i < 768; i += 192) {
            int a = i >> 4, k2 = 16 + (i & 15);
            ub.qk.qM[a * 40 + k2] = 0;
            ub.qk.kM[a * 40 + k2] = 0;
        }
        // qkv: 3 waves, one matrix each (M=48, N=16, K=128)
        {
            f32x4 acc[3] = {};
            const unsigned short* Wm = WtL + wv * 16384 + (size_t)(h * 16) * 128;
            #pragma unroll
            for (int kq = 0; kq < 4; ++kq) {
                short8 bf = ldg8(&Wm[(size_t)r16 * 128 + kq * 32 + g * 8]);
                #pragma unroll
                for (int mi = 0; mi < 3; ++mi) {
                    int row = mi * 16 + r16;
                    int c = kq * 32 + g * 8;
                    short8 af = *(const short8*)(&Xs[row * 128 + (c & 64) + ((c & 63) ^ ((row & 7) << 3))]);
                    acc[mi] = __builtin_amdgcn_mfma_f32_16x16x32_bf16(af, bf, acc[mi], 0, 0, 0);
                }
            }
            #pragma unroll
            for (int mi = 0; mi < 3; ++mi) {
                #pragma unroll
                for (int r = 0; r < 4; ++r) {
                    int a = mi * 16 + g * 4 + r;
                    unsigned short hv = f2bf(acc[mi][r]);
                    if (wv == 0) ub.qk.qM[a * 40 + r16] = hv;
                    else if (wv == 1) ub.qk.kM[a * 40 + r16] = hv;
                    else vT[r16 * 72 + a] = hv;
                }
            }
        }
        __syncthreads();

        // scores: 9 frags (3m x 3n); this wave does m = wv
        {
            #pragma unroll
            for (int ni = 0; ni < 3; ++ni) {
                f32x4 acc = {0.f, 0.f, 0.f, 0.f};
                short8 af = *(const short8*)(&ub.qk.qM[(wv * 16 + r16) * 40 + g * 8]);
                short8 bf = *(const short8*)(&ub.qk.kM[(ni * 16 + r16) * 40 + g * 8]);
                acc = __builtin_amdgcn_mfma_f32_16x16x32_bf16(af, bf, acc, 0, 0, 0);
                #pragma unroll
                for (int r = 0; r < 4; ++r)
                    sL[(wv * 16 + g * 4 + r) * 52 + ni * 16 + r16] = acc[r] * 0.25f;
            }
        }
        __syncthreads();

        // distributed softmax: 4-lane group per row; P overlays dead qM/kM
        {
            int row = wv * 16 + (lane >> 2), sub = lane & 3;
            f32x4 v0 = *(const f32x4*)(&sL[row * 52 + sub * 4]);
            f32x4 v1 = *(const f32x4*)(&sL[row * 52 + 16 + sub * 4]);
            f32x4 v2 = *(const f32x4*)(&sL[row * 52 + 32 + sub * 4]);
            float m = fmaxf(fmaxf(fmaxf(v0[0], v0[1]), fmaxf(v0[2], v0[3])),
                            fmaxf(fmaxf(v1[0], v1[1]), fmaxf(v1[2], v1[3])));
            m = fmaxf(m, fmaxf(fmaxf(v2[0], v2[1]), fmaxf(v2[2], v2[3])));
            m = fmaxf(m, __shfl_xor(m, 1));
            m = fmaxf(m, __shfl_xor(m, 2));
            float e[12];
            #pragma unroll
            for (int j = 0; j < 4; ++j) {
                e[j]     = __expf(v0[j] - m);
                e[4 + j] = __expf(v1[j] - m);
                e[8 + j] = __expf(v2[j] - m);
            }
            float sum = 0.f;
            #pragma unroll
            for (int j = 0; j < 12; ++j) sum += e[j];
            sum += __shfl_xor(sum, 1);
            sum += __shfl_xor(sum, 2);
            float inv = __fdividef(1.f, sum);
            #pragma unroll
            for (int c = 0; c < 3; ++c) {
                u32x2 w;
                w[0] = f2bf2(e[c * 4 + 0] * inv, e[c * 4 + 1] * inv);
                w[1] = f2bf2(e[c * 4 + 2] * inv, e[c * 4 + 3] * inv);
                int col = c * 16 + sub * 4;
                *(u32x2*)(&ub.P[row * 64 + (col ^ ((row & 7) << 3))]) = w;
            }
            for (int i = tid; i < 768; i += 192) {
                int a = i >> 4, c = 48 + (i & 15);
                ub.P[a * 64 + (c ^ ((a & 7) << 3))] = 0;
            }
        }
        __syncthreads();

        // PV: out[a][d] = sum_a' P[a][a'] v[a'][d]; m-frag = wv, K=64 (padded)
        {
            f32x4 acc = {0.f, 0.f, 0.f, 0.f};
            #pragma unroll
            for (int ks = 0; ks < 2; ++ks) {
                int co = ks * 32 + g * 8;
                int rp = wv * 16 + r16;
                short8 af = *(const short8*)(&ub.P[rp * 64 + (co ^ ((rp & 7) << 3))]);
                short8 bf = *(const short8*)(&vT[r16 * 72 + co]);
                acc = __builtin_amdgcn_mfma_f32_16x16x32_bf16(af, bf, acc, 0, 0, 0);
            }
            #pragma unroll
            for (int r = 0; r < 4; ++r) {
                int a = wv * 16 + g * 4 + r;
                o[((size_t)b * AL_ + a) * 128 + h * 16 + r16] = f2bf(acc[r]);
            }
        }
        __syncthreads();
    }
}

// ====== Layer tail (ROWS rows/block): wo-GEMM + LN1 + FFN + LN2 (+head) =======
template<int ROWS>
__global__ __launch_bounds__(256) void layer_tail_kernel(
    const unsigned short* __restrict__ obuf, const unsigned short* __restrict__ Wl,
    const float* __restrict__ b1, const float* __restrict__ b2,
    const float* __restrict__ g1, const float* __restrict__ be1,
    const float* __restrict__ g2, const float* __restrict__ be2,
    float* __restrict__ x, unsigned short* __restrict__ xbf,
    int last, const float* __restrict__ cw1, const float* __restrict__ cb1,
    const float* __restrict__ cw2, const float* __restrict__ cb2,
    float* __restrict__ outp)
{
    constexpr int MR = ROWS / 16;
    __shared__ unsigned short OX[ROWS * 128];
    __shared__ union { unsigned short hid[ROWS * 512]; float Cs[ROWS * 132]; } u2;
    __shared__ float xr[ROWS * 132];
    const int tid = threadIdx.x, lane = tid & 63;
    const int wv = __builtin_amdgcn_readfirstlane(tid >> 6);
    const int g = lane >> 4, r16 = lane & 15;
    const int row0 = last ? ((int)blockIdx.x * 48 + 32) : ((int)blockIdx.x * ROWS);

    #pragma unroll
    for (int p = 0; p < MR; ++p) {
        int i = p * 256 + tid;
        int a = i >> 4, c = (i & 15) * 8;
        u32x4 v = *(const u32x4*)(&obuf[(size_t)(row0 + a) * 128 + c]);
        *(u32x4*)(&OX[a * 128 + (c & 64) + ((c & 63) ^ ((a & 7) << 3))]) = v;
    }
    __syncthreads();

    // wo GEMM: 8*MR frags, wave does ni = wv*2 + {0,1}, mi < MR
    {
        f32x4 wacc[MR][2] = {};
        #pragma unroll
        for (int q = 0; q < 2; ++q) {
            int ni = wv * 2 + q;
            const unsigned short* Wm = Wl + 49152 + (size_t)(ni * 16 + r16) * 128;
            #pragma unroll
            for (int kq = 0; kq < 4; ++kq) {
                int co = kq * 32 + g * 8;
                short8 bf = ldg8(Wm + co);
                #pragma unroll
                for (int mi = 0; mi < MR; ++mi) {
                    int ra = mi * 16 + r16;
                    short8 af = *(const short8*)(&OX[ra * 128 + (co & 64) + ((co & 63) ^ ((ra & 7) << 3))]);
                    wacc[mi][q] = __builtin_amdgcn_mfma_f32_16x16x32_bf16(af, bf, wacc[mi][q], 0, 0, 0);
                }
            }
        }
        #pragma unroll
        for (int mi = 0; mi < MR; ++mi)
            #pragma unroll
            for (int q = 0; q < 2; ++q) {
                int ni = wv * 2 + q;
                #pragma unroll
                for (int r = 0; r < 4; ++r)
                    u2.Cs[(mi * 16 + g * 4 + r) * 132 + ni * 16 + r16] = wacc[mi][q][r];
            }
    }
    __syncthreads();

    // LN1 (+residual)
    #pragma unroll
    for (int rr = 0; rr < ROWS / 4; ++rr) {
        int row = wv * (ROWS / 4) + rr;
        size_t go = (size_t)(row0 + row) * 128;
        float v0 = u2.Cs[row * 132 + lane] + x[go + lane];
        float v1 = u2.Cs[row * 132 + 64 + lane] + x[go + 64 + lane];
        float sum = v0 + v1, sq = v0 * v0 + v1 * v1;
        #pragma unroll
        for (int o2 = 32; o2 >= 1; o2 >>= 1) {
            sum += __shfl_xor(sum, o2);
            sq  += __shfl_xor(sq, o2);
        }
        float mu = sum * (1.f / 128.f);
        float var = sq * (1.f / 128.f) - mu * mu;
        float rs = rsqrtf(var + 1e-5f);
        float o0 = (v0 - mu) * rs * g1[lane] + be1[lane];
        float o1 = (v1 - mu) * rs * g1[lane + 64] + be1[lane + 64];
        xr[row * 132 + lane] = o0;
        xr[row * 132 + 64 + lane] = o1;
        OX[row * 128 + (lane ^ ((row & 7) << 3))] = f2bf(o0);
        OX[row * 128 + 64 + (lane ^ ((row & 7) << 3))] = f2bf(o1);
    }
    __syncthreads();

    // hidden = relu(Xs @ w1 + b1): wave owns cols [wv*128, +128)
    {
        f32x4 hacc[MR][8] = {};
        #pragma unroll
        for (int nf = 0; nf < 8; ++nf) {
            int col = wv * 128 + nf * 16 + r16;
            const unsigned short* Wm = Wl + 65536 + (size_t)col * 128;
            #pragma unroll
            for (int kq = 0; kq < 4; ++kq) {
                int co = kq * 32 + g * 8;
                short8 bf = ldg8(Wm + co);
                #pragma unroll
                for (int mi = 0; mi < MR; ++mi) {
                    int ra = mi * 16 + r16;
                    short8 af = *(const short8*)(&OX[ra * 128 + (co & 64) + ((co & 63) ^ ((ra & 7) << 3))]);
                    hacc[mi][nf] = __builtin_amdgcn_mfma_f32_16x16x32_bf16(af, bf, hacc[mi][nf], 0, 0, 0);
                }
            }
        }
        #pragma unroll
        for (int nf = 0; nf < 8; ++nf) {
            int col = wv * 128 + nf * 16 + r16;
            float bv = b1[col];
            #pragma unroll
            for (int mi = 0; mi < MR; ++mi)
                #pragma unroll
                for (int r = 0; r < 4; ++r) {
                    int rowa = mi * 16 + g * 4 + r;
                    u2.hid[rowa * 512 + (col & 448) + ((col & 63) ^ ((rowa & 7) << 3))] =
                        f2bf(fmaxf(hacc[mi][nf][r] + bv, 0.f));
                }
        }
    }
    __syncthreads();

    // y = hid @ w2 (K=512)
    f32x4 yacc[MR][2] = {};
    #pragma unroll
    for (int q = 0; q < 2; ++q) {
        int ni = wv * 2 + q;
        const unsigned short* Wm = Wl + 131072 + (size_t)(ni * 16 + r16) * 512;
        #pragma unroll
        for (int kq = 0; kq < 16; ++kq) {
            int co = kq * 32 + g * 8;
            short8 bf = ldg8(Wm + co);
            #pragma unroll
            for (int mi = 0; mi < MR; ++mi) {
                int ra = mi * 16 + r16;
                short8 af = *(const short8*)(&u2.hid[ra * 512 + (co & 448) + ((co & 63) ^ ((ra & 7) << 3))]);
                yacc[mi][q] = __builtin_amdgcn_mfma_f32_16x16x32_bf16(af, bf, yacc[mi][q], 0, 0, 0);
            }
        }
    }
    __syncthreads();
    #pragma unroll
    for (int mi = 0; mi < MR; ++mi)
        #pragma unroll
        for (int q = 0; q < 2; ++q) {
            int ni = wv * 2 + q;
            float bv = b2[ni * 16 + r16];
            #pragma unroll
            for (int r = 0; r < 4; ++r)
                u2.Cs[(mi * 16 + g * 4 + r) * 132 + ni * 16 + r16] = yacc[mi][q][r] + bv;
        }
    __syncthreads();

    // LN2 (+residual xr)
    #pragma unroll
    for (int rr = 0; rr < ROWS / 4; ++rr) {
        int row = wv * (ROWS / 4) + rr;
        size_t go = (size_t)(row0 + row) * 128;
        float v0 = u2.Cs[row * 132 + lane] + xr[row * 132 + lane];
        float v1 = u2.Cs[row * 132 + 64 + lane] + xr[row * 132 + 64 + lane];
        float sum = v0 + v1, sq = v0 * v0 + v1 * v1;
        #pragma unroll
        for (int o2 = 32; o2 >= 1; o2 >>= 1) {
            sum += __shfl_xor(sum, o2);
            sq  += __shfl_xor(sq, o2);
        }
        float mu = sum * (1.f / 128.f);
        float var = sq * (1.f / 128.f) - mu * mu;
        float rs = rsqrtf(var + 1e-5f);
        float o0 = (v0 - mu) * rs * g2[lane] + be2[lane];
        float o1 = (v1 - mu) * rs * g2[lane + 64] + be2[lane + 64];
        if (!last) {
            x[go + lane] = o0;
            x[go + 64 + lane] = o1;
            xbf[go + lane] = f2bf(o0);
            xbf[go + 64 + lane] = f2bf(o1);
        } else {
            xr[row * 132 + lane] = o0;
            xr[row * 132 + 64 + lane] = o1;
        }
    }
    if (last) {
        __syncthreads();
        if (wv == 0) {
            float hj = cb1[lane];
            #pragma unroll 8
            for (int d = 0; d < 128; ++d)
                hj = fmaf(xr[(ROWS - 1) * 132 + d], cw1[d * 64 + lane], hj);
            hj = fmaxf(hj, 0.f);
            float acc = hj * cw2[lane];
            #pragma unroll
            for (int o2 = 32; o2 >= 1; o2 >>= 1) acc += __shfl_xor(acc, o2);
            if (lane == 0) outp[blockIdx.x] = acc + cb2[0];
        }
    }
}

// ================= Launch =====================================================
extern "C" void kernel_launch(void* const* d_in, const int* in_sizes, int n_in,
                              void* d_out, int out_size, void* d_ws, size_t ws_size,
                              hipStream_t stream) {
    (void)in_sizes; (void)n_in; (void)out_size; (void)ws_size;
    const float* cls_emb    = (const float*)d_in[0];
    const float* note_times = (const float*)d_in[1];
    const int*   note_counts= (const int*)d_in[2];
    const float* proj_w     = (const float*)d_in[3];
    const float* proj_b     = (const float*)d_in[4];
    const float* te_w       = (const float*)d_in[5];
    const float* te_b       = (const float*)d_in[6];
    const float* wq         = (const float*)d_in[7];
    const float* wk         = (const float*)d_in[8];
    const float* tf_wq      = (const float*)d_in[9];
    const float* tf_wk      = (const float*)d_in[10];
    const float* tf_wv      = (const float*)d_in[11];
    const float* tf_wo      = (const float*)d_in[12];
    const float* tf_ln1_g   = (const float*)d_in[13];
    const float* tf_ln1_b   = (const float*)d_in[14];
    const float* tf_w1      = (const float*)d_in[15];
    const float* tf_b1      = (const float*)d_in[16];
    const float* tf_w2      = (const float*)d_in[17];
    const float* tf_b2      = (const float*)d_in[18];
    const float* tf_ln2_g   = (const float*)d_in[19];
    const float* tf_ln2_b   = (const float*)d_in[20];
    const float* cls_w1     = (const float*)d_in[21];
    const float* cls_b1     = (const float*)d_in[22];
    const float* cls_w2     = (const float*)d_in[23];
    const float* cls_b2     = (const float*)d_in[24];
    float* out = (float*)d_out;
    float* ws = (float*)d_ws;

    // workspace layout (float units)
    unsigned short* note_emb16 = (unsigned short*)(ws + 0);       // 1,048,576 f
    float* x        = ws + 1048576;                                // 1,572,864 f
    unsigned short* obuf16 = (unsigned short*)(ws + 2621440);      // 786,432 f
    unsigned short* xbf    = (unsigned short*)(ws + 3407872);      // 786,432 f
    float* q_all    = ws + 4194304;                                // 3,072 f
    unsigned short* wt     = (unsigned short*)(ws + 4197376);      // 344,064 f

    TTab tab;
    int tile = 0, idx = 0;
    auto add = [&](const float* src, int dstOff, int K, int N) {
        tab.e[idx].src = src; tab.e[idx].dstOff = dstOff;
        tab.e[idx].K = K; tab.e[idx].N = N; tab.e[idx].tile0 = tile;
        tile += (K / 64) * (N / 64); ++idx;
    };
    add(proj_w, 0, DT_, DH_);
    int layerBase[NL_];
    for (int i = 0; i < NL_; ++i) {
        int base = 98304 + i * 196608;
        layerBase[i] = base;
        add(tf_wq + (size_t)i * DH_ * DH_, base,           DH_, DH_);
        add(tf_wk + (size_t)i * DH_ * DH_, base + 16384,   DH_, DH_);
        add(tf_wv + (size_t)i * DH_ * DH_, base + 32768,   DH_, DH_);
        add(tf_wo + (size_t)i * DH_ * DH_, base + 49152,   DH_, DH_);
        add(tf_w1 + (size_t)i * DH_ * DFF_, base + 65536,  DH_, DFF_);
        add(tf_w2 + (size_t)i * DFF_ * DH_, base + 131072, DFF_, DH_);
    }
    prep_weights_kernel<<<tile + 1, 256, 0, stream>>>(tab, tile, wt, te_w, te_b, wq, q_all);

    const int Mx = B_ * AL_; // 12288

    gemm_proj_kernel<<<(B_ * L_) / 32, 256, 0, stream>>>(
        cls_emb, wt, proj_b, note_emb16, B_ * L_, DH_, DT_);

    first_attn_kernel<<<B_ * 2, 256, 0, stream>>>(
        note_times, note_counts, te_w, te_b, wk, q_all, note_emb16, x, xbf);

    for (int i = 0; i < NL_; ++i) {
        int base = layerBase[i];
        int last = (i == NL_ - 1);
        attn2_kernel<<<B_ * 4, 192, 0, stream>>>(xbf, wt + base, obuf16);
        if (!last) {
            layer_tail_kernel<32><<<Mx / 32, 256, 0, stream>>>(
                obuf16, wt + base,
                tf_b1 + i * DFF_, tf_b2 + i * DH_,
                tf_ln1_g + i * DH_, tf_ln1_b + i * DH_,
                tf_ln2_g + i * DH_, tf_ln2_b + i * DH_,
                x, xbf,
                0, cls_w1, cls_b1, cls_w2, cls_b2, out);
        } else {
            layer_tail_kernel<16><<<B_, 256, 0, stream>>>(
                obuf16, wt + base,
                tf_b1 + i * DFF_, tf_b2 + i * DH_,
                tf_ln1_g + i * DH_, tf_ln1_b + i * DH_,
                tf_ln2_g + i * DH_, tf_ln2_b + i * DH_,
                x, xbf,
                1, cls_w1, cls_b1, cls_w2, cls_b2, out);
        }
    }
}